// Round 8
// baseline (289.416 us; speedup 1.0000x reference)
//
#include <hip/hip_runtime.h>
#include <hip/hip_bf16.h>

#define D_MODEL 1024
#define NHEADS 16
#define HDIM 64
#define BATCH 8
#define SEQ 512
#define NROWS 4096          // BATCH*SEQ
#define SCALE 0.125f
#define LN_EPS 1e-5f

typedef __attribute__((ext_vector_type(8))) short bf16x8;      // 8 bf16 (4 VGPRs)
typedef __attribute__((ext_vector_type(4))) float f32x4;
typedef __attribute__((ext_vector_type(8))) unsigned short u16x8;

static __device__ __forceinline__ float bf2f(unsigned short u) {
    return __uint_as_float(((unsigned int)u) << 16);
}
static __device__ __forceinline__ unsigned short f2bf(float f) {
    unsigned int x = __float_as_uint(f);
    unsigned int r = (x + 0x7fffu + ((x >> 16) & 1u)) >> 16;   // RNE
    return (unsigned short)r;
}

// ---------------------------------------------------------------------------
// Bias helper: jax.image.resize(bias128, (512,512), 'bilinear')
// ---------------------------------------------------------------------------
static __device__ __forceinline__ float bias128(int a, int b) {
    float d = fabsf((float)(a - b));
    return expf(-d * 0.1f) - d * 0.05f;
}

// ---------------------------------------------------------------------------
// prep_kernel: fused LN (blocks 0..8191) + bias table (8192..9215) +
// Wqkv fp32->bf16 convert (9216..12287).  Saves 2 launches.
// ---------------------------------------------------------------------------
__global__ void prep_kernel(const float* __restrict__ dec, const float* __restrict__ enc,
                            const float* __restrict__ gamma, const float* __restrict__ beta,
                            const float* __restrict__ Wqkv,
                            unsigned short* __restrict__ q_ln, unsigned short* __restrict__ kv_ln,
                            float* __restrict__ bias, unsigned short* __restrict__ Wqkv_bf) {
    int blk = blockIdx.x;
    int t = threadIdx.x;
    if (blk >= 9216) {          // Wqkv convert: 3072 blocks x 256 thr of float4
        int idx = (blk - 9216) * 256 + t;
        float4 v = ((const float4*)Wqkv)[idx];
        ushort4 u;
        u.x = f2bf(v.x); u.y = f2bf(v.y); u.z = f2bf(v.z); u.w = f2bf(v.w);
        ((ushort4*)Wqkv_bf)[idx] = u;
        return;
    }
    if (blk >= 8192) {          // bias: 1024 blocks
        int idx = (blk - 8192) * 256 + t;
        int qi = idx >> 9, kj = idx & 511;
        float fq = (qi + 0.5f) * 0.25f - 0.5f;
        float fk = (kj + 0.5f) * 0.25f - 0.5f;
        int iq = (int)floorf(fq); float tq = fq - (float)iq;
        int ik = (int)floorf(fk); float tk = fk - (float)ik;
        int iq0 = min(max(iq, 0), 127), iq1 = min(max(iq + 1, 0), 127);
        int ik0 = min(max(ik, 0), 127), ik1 = min(max(ik + 1, 0), 127);
        float v = (1.f - tq) * ((1.f - tk) * bias128(iq0, ik0) + tk * bias128(iq0, ik1))
                +        tq  * ((1.f - tk) * bias128(iq1, ik0) + tk * bias128(iq1, ik1));
        bias[idx] = v;
        return;
    }
    // LayerNorm: one block per row
    int row = blk;
    const float* src = (row < NROWS) ? dec + (size_t)row * D_MODEL
                                     : enc + (size_t)(row - NROWS) * D_MODEL;
    unsigned short* dst = (row < NROWS) ? q_ln + (size_t)row * D_MODEL
                                        : kv_ln + (size_t)(row - NROWS) * D_MODEL;
    float4 x = ((const float4*)src)[t];
    float s  = x.x + x.y + x.z + x.w;
    float ss = x.x * x.x + x.y * x.y + x.z * x.z + x.w * x.w;
    #pragma unroll
    for (int off = 32; off > 0; off >>= 1) {
        s  += __shfl_down(s, off);
        ss += __shfl_down(ss, off);
    }
    __shared__ float red_s[4], red_ss[4];
    int wid = t >> 6, lane = t & 63;
    if (lane == 0) { red_s[wid] = s; red_ss[wid] = ss; }
    __syncthreads();
    if (t == 0) {
        float S = red_s[0] + red_s[1] + red_s[2] + red_s[3];
        float SS = red_ss[0] + red_ss[1] + red_ss[2] + red_ss[3];
        red_s[0] = S; red_ss[0] = SS;
    }
    __syncthreads();
    float mu  = red_s[0] * (1.0f / 1024.0f);
    float var = red_ss[0] * (1.0f / 1024.0f) - mu * mu;
    float rstd = rsqrtf(var + LN_EPS);
    float4 g = ((const float4*)gamma)[t];
    float4 bb = ((const float4*)beta)[t];
    ushort4 u;
    u.x = f2bf((x.x - mu) * rstd * g.x + bb.x);
    u.y = f2bf((x.y - mu) * rstd * g.y + bb.y);
    u.z = f2bf((x.z - mu) * rstd * g.z + bb.z);
    u.w = f2bf((x.w - mu) * rstd * g.w + bb.w);
    ((ushort4*)dst)[t] = u;
}

// ---------------------------------------------------------------------------
// Wout + Wgate fp32 -> bf16 (one launch, 2048 blocks)
// ---------------------------------------------------------------------------
__global__ void convert_og(const float* __restrict__ Wout, const float* __restrict__ Wgate,
                           unsigned short* __restrict__ Wout_bf, unsigned short* __restrict__ Wgate_bf) {
    int idx = blockIdx.x * 256 + threadIdx.x;   // float4 units, 0..524287
    const float* src; unsigned short* dst; int off;
    if (idx < 262144) { src = (const float*)Wout; dst = Wout_bf; off = idx; }
    else              { src = (const float*)Wgate; dst = Wgate_bf; off = idx - 262144; }
    float4 v = ((const float4*)src)[off];
    ushort4 u;
    u.x = f2bf(v.x); u.y = f2bf(v.y); u.z = f2bf(v.z); u.w = f2bf(v.w);
    ((ushort4*)dst)[off] = u;
}

// ===========================================================================
// Shared MFMA GEMM pattern: C(128x128) = A(128xK) @ W^T(128xK), bf16 in.
// 256 thr = 4 waves (2x2); wave does 64x64 as 4x4 MFMA 16x16 tiles.
//
// R7 lesson (permanent): accumulators and prefetch buffers must be NAMED
// scalars — array-indexed locals get lowered to scratch (signature:
// VGPR~68 + GB-scale WRITE_SIZE + MfmaUtil ~3%).
//
// R8: software-pipelined prefetch — tile kt+1 is loaded into registers
// before the MFMA block of tile kt; the vmcnt wait lands at the next
// iteration's LDS store, hiding global/L2 latency behind 32 MFMAs.
// ===========================================================================
#define GSTR 72
#define CSTR 136   // multiple of 8 (16B-aligned rows for u16x8 epilogue reads)

union alignas(16) GemmSmem {
    struct { unsigned short A[128 * GSTR]; unsigned short B[128 * GSTR]; } ab;
    unsigned short C[128 * CSTR];   // 34816 shorts <= 36864
};

#define MF(a, b, d) __builtin_amdgcn_mfma_f32_16x16x32_bf16((a), (b), (d), 0, 0, 0)

#define GEMM_KH(kh)                                                            \
    {                                                                          \
        const unsigned short* Arow_ = &As[(wr * 64 + c) * GSTR + (kh) * 32 + quad * 8]; \
        const unsigned short* Brow_ = &Bs[(wc * 64 + c) * GSTR + (kh) * 32 + quad * 8]; \
        bf16x8 f0 = *(const bf16x8*)(Arow_);                                   \
        bf16x8 f1 = *(const bf16x8*)(Arow_ + 16 * GSTR);                       \
        bf16x8 f2 = *(const bf16x8*)(Arow_ + 32 * GSTR);                       \
        bf16x8 f3 = *(const bf16x8*)(Arow_ + 48 * GSTR);                       \
        bf16x8 g0 = *(const bf16x8*)(Brow_);                                   \
        bf16x8 g1 = *(const bf16x8*)(Brow_ + 16 * GSTR);                       \
        bf16x8 g2 = *(const bf16x8*)(Brow_ + 32 * GSTR);                       \
        bf16x8 g3 = *(const bf16x8*)(Brow_ + 48 * GSTR);                       \
        a00 = MF(f0, g0, a00); a01 = MF(f0, g1, a01); a02 = MF(f0, g2, a02); a03 = MF(f0, g3, a03); \
        a10 = MF(f1, g0, a10); a11 = MF(f1, g1, a11); a12 = MF(f1, g2, a12); a13 = MF(f1, g3, a13); \
        a20 = MF(f2, g0, a20); a21 = MF(f2, g1, a21); a22 = MF(f2, g2, a22); a23 = MF(f2, g3, a23); \
        a30 = MF(f3, g0, a30); a31 = MF(f3, g1, a31); a32 = MF(f3, g2, a32); a33 = MF(f3, g3, a33); \
    }

#define GEMM_MAIN_LOOP(Aptr, Bptr)                                             \
    __shared__ GemmSmem smem;                                                  \
    unsigned short* As = smem.ab.A;                                            \
    unsigned short* Bs = smem.ab.B;                                            \
    int tid = threadIdx.x;                                                     \
    int wave = tid >> 6, lane = tid & 63, quad = lane >> 4, c = lane & 15;     \
    int wr = wave >> 1, wc = wave & 1;                                         \
    int colg = tid & 7, r0 = tid >> 3;                                         \
    const unsigned short* Ab = (Aptr) + (size_t)(rt * 128 + r0) * 1024 + colg * 8; \
    const unsigned short* Bb = (Bptr) + (size_t)(ct * 128 + r0) * 1024 + colg * 8; \
    f32x4 a00 = (f32x4)0.f, a01 = (f32x4)0.f, a02 = (f32x4)0.f, a03 = (f32x4)0.f; \
    f32x4 a10 = (f32x4)0.f, a11 = (f32x4)0.f, a12 = (f32x4)0.f, a13 = (f32x4)0.f; \
    f32x4 a20 = (f32x4)0.f, a21 = (f32x4)0.f, a22 = (f32x4)0.f, a23 = (f32x4)0.f; \
    f32x4 a30 = (f32x4)0.f, a31 = (f32x4)0.f, a32 = (f32x4)0.f, a33 = (f32x4)0.f; \
    u16x8 pa0 = *(const u16x8*)(Ab);                                           \
    u16x8 pa1 = *(const u16x8*)(Ab + 32768);                                   \
    u16x8 pa2 = *(const u16x8*)(Ab + 65536);                                   \
    u16x8 pa3 = *(const u16x8*)(Ab + 98304);                                   \
    u16x8 pb0 = *(const u16x8*)(Bb);                                           \
    u16x8 pb1 = *(const u16x8*)(Bb + 32768);                                   \
    u16x8 pb2 = *(const u16x8*)(Bb + 65536);                                   \
    u16x8 pb3 = *(const u16x8*)(Bb + 98304);                                   \
    for (int kt = 0; kt < 16; ++kt) {                                          \
        __syncthreads();                                                       \
        *(u16x8*)&As[(r0 +  0) * GSTR + colg * 8] = pa0;                       \
        *(u16x8*)&As[(r0 + 32) * GSTR + colg * 8] = pa1;                       \
        *(u16x8*)&As[(r0 + 64) * GSTR + colg * 8] = pa2;                       \
        *(u16x8*)&As[(r0 + 96) * GSTR + colg * 8] = pa3;                       \
        *(u16x8*)&Bs[(r0 +  0) * GSTR + colg * 8] = pb0;                       \
        *(u16x8*)&Bs[(r0 + 32) * GSTR + colg * 8] = pb1;                       \
        *(u16x8*)&Bs[(r0 + 64) * GSTR + colg * 8] = pb2;                       \
        *(u16x8*)&Bs[(r0 + 96) * GSTR + colg * 8] = pb3;                       \
        __syncthreads();                                                       \
        if (kt < 15) {                                                         \
            int k1 = (kt + 1) * 64;                                            \
            pa0 = *(const u16x8*)(Ab + k1);                                    \
            pa1 = *(const u16x8*)(Ab + 32768 + k1);                            \
            pa2 = *(const u16x8*)(Ab + 65536 + k1);                            \
            pa3 = *(const u16x8*)(Ab + 98304 + k1);                            \
            pb0 = *(const u16x8*)(Bb + k1);                                    \
            pb1 = *(const u16x8*)(Bb + 32768 + k1);                            \
            pb2 = *(const u16x8*)(Bb + 65536 + k1);                            \
            pb3 = *(const u16x8*)(Bb + 98304 + k1);                            \
        }                                                                      \
        GEMM_KH(0)                                                             \
        GEMM_KH(1)                                                             \
    }

// ---------------------------------------------------------------------------
// QKV GEMM (MFMA) + fused RoPE, LDS-bounce epilogue with wide stores.
// 1-D grid of 768, swizzled into 8(ct)x4(rt) super-tiles for L2 locality.
// ---------------------------------------------------------------------------
#define ROPE_REG(i, reg, A0, A1, A2, A3)                                       \
    {                                                                          \
        int mloc = wr * 64 + (i) * 16 + quad * 4 + (reg);                      \
        int crow = mloc * CSTR + wc * 64;                                      \
        float fl = (float)((rt * 128 + mloc) & 511);                           \
        float aa0 = fl * inv0, aa1 = fl * inv1;                                \
        float c0 = cosf(aa0), s0 = sinf(aa0);                                  \
        float c1 = cosf(aa1), s1 = sinf(aa1);                                  \
        float e0 = A0[(reg)], o0 = A2[(reg)];                                  \
        float e1 = A1[(reg)], o1 = A3[(reg)];                                  \
        smem.C[crow + c]      = f2bf(e0 * c0 - o0 * s0);                       \
        smem.C[crow + 32 + c] = f2bf(e0 * s0 + o0 * c0);                       \
        smem.C[crow + 16 + c] = f2bf(e1 * c1 - o1 * s1);                       \
        smem.C[crow + 48 + c] = f2bf(e1 * s1 + o1 * c1);                       \
    }
#define ROPE_ROW(i, A0, A1, A2, A3)                                            \
    ROPE_REG(i, 0, A0, A1, A2, A3) ROPE_REG(i, 1, A0, A1, A2, A3)              \
    ROPE_REG(i, 2, A0, A1, A2, A3) ROPE_REG(i, 3, A0, A1, A2, A3)

#define VSEC_REG(i, reg, A0, A1, A2, A3)                                       \
    {                                                                          \
        int crow = (wr * 64 + (i) * 16 + quad * 4 + (reg)) * CSTR + wc * 64;   \
        smem.C[crow + c]      = f2bf(A0[(reg)]);                               \
        smem.C[crow + 16 + c] = f2bf(A1[(reg)]);                               \
        smem.C[crow + 32 + c] = f2bf(A2[(reg)]);                               \
        smem.C[crow + 48 + c] = f2bf(A3[(reg)]);                               \
    }
#define VSEC_ROW(i, A0, A1, A2, A3)                                            \
    VSEC_REG(i, 0, A0, A1, A2, A3) VSEC_REG(i, 1, A0, A1, A2, A3)              \
    VSEC_REG(i, 2, A0, A1, A2, A3) VSEC_REG(i, 3, A0, A1, A2, A3)

__global__ __launch_bounds__(256, 1)
void qkv_gemm_mfma(const unsigned short* __restrict__ q_ln,
                   const unsigned short* __restrict__ kv_ln,
                   const unsigned short* __restrict__ Wb,
                   unsigned short* __restrict__ qo,
                   unsigned short* __restrict__ ko,
                   unsigned short* __restrict__ vo) {
    int bid = blockIdx.x;               // 0..767
    int st = bid >> 5, in = bid & 31;   // 24 super-tiles of 32 blocks
    int stc = st % 3, str = st / 3;
    int ct = stc * 8 + (in & 7);        // 0..23
    int rt = str * 4 + (in >> 3);       // 0..31
    int n0 = ct * 128;
    int section = n0 >> 10;             // 0=q 1=k 2=v (uniform per block)
    const unsigned short* A = (section == 0) ? q_ln : kv_ln;

    GEMM_MAIN_LOOP(A, Wb)

    // ---- epilogue: RoPE in-register, bounce through LDS, wide stores ----
    __syncthreads();                    // all waves done reading As/Bs
    if (section == 2) {
        VSEC_ROW(0, a00, a01, a02, a03)
        VSEC_ROW(1, a10, a11, a12, a13)
        VSEC_ROW(2, a20, a21, a22, a23)
        VSEC_ROW(3, a30, a31, a32, a33)
    } else {
        float inv0 = expf(-0.2878231366f * (float)c);          // 10000^(-c/32)
        float inv1 = expf(-0.2878231366f * (float)(16 + c));
        ROPE_ROW(0, a00, a01, a02, a03)
        ROPE_ROW(1, a10, a11, a12, a13)
        ROPE_ROW(2, a20, a21, a22, a23)
        ROPE_ROW(3, a30, a31, a32, a33)
    }
    __syncthreads();

    unsigned short* outp = (section == 0) ? qo : (section == 1) ? ko : vo;
    int rr = tid >> 1, ch = tid & 1;    // row 0..127, head-half 0/1
    int mm = rt * 128 + rr;
    int bb = mm >> 9, ll = mm & 511;
    int h = ((n0 & 1023) >> 6) + ch;
    unsigned short* orow = outp + (((size_t)bb * NHEADS + h) * SEQ + ll) * HDIM;
    const unsigned short* csrc = &smem.C[rr * CSTR + ch * 64];
    #pragma unroll
    for (int kc = 0; kc < 8; ++kc)
        *(u16x8*)(orow + kc * 8) = *(const u16x8*)(csrc + kc * 8);
}

// ---------------------------------------------------------------------------
// Projection 1 (MFMA): t = att @ Wout^T + b_out -> fp32 t_proj + bf16 t_bf
// grid (8, 32)
// ---------------------------------------------------------------------------
#define OUT1_REG(mb, reg, n, Aij)                                              \
    {                                                                          \
        float v = Aij[(reg)] + bo;                                             \
        t_proj[(size_t)((mb) + (reg)) * 1024 + (n)] = v;                       \
        t_bf[(size_t)((mb) + (reg)) * 1024 + (n)] = f2bf(v);                   \
    }
#define OUT1_TILE(i, j, Aij)                                                   \
    {                                                                          \
        int n = ct * 128 + wc * 64 + (j) * 16 + c;                             \
        float bo = b_out[n];                                                   \
        int mb = rt * 128 + wr * 64 + (i) * 16 + quad * 4;                     \
        OUT1_REG(mb, 0, n, Aij) OUT1_REG(mb, 1, n, Aij)                        \
        OUT1_REG(mb, 2, n, Aij) OUT1_REG(mb, 3, n, Aij)                        \
    }

__global__ __launch_bounds__(256, 1)
void out_gemm1_mfma(const unsigned short* __restrict__ att,
                    const unsigned short* __restrict__ Wob,
                    const float* __restrict__ b_out,
                    float* __restrict__ t_proj,
                    unsigned short* __restrict__ t_bf) {
    int ct = blockIdx.x, rt = blockIdx.y;

    GEMM_MAIN_LOOP(att, Wob)

    OUT1_TILE(0, 0, a00) OUT1_TILE(0, 1, a01) OUT1_TILE(0, 2, a02) OUT1_TILE(0, 3, a03)
    OUT1_TILE(1, 0, a10) OUT1_TILE(1, 1, a11) OUT1_TILE(1, 2, a12) OUT1_TILE(1, 3, a13)
    OUT1_TILE(2, 0, a20) OUT1_TILE(2, 1, a21) OUT1_TILE(2, 2, a22) OUT1_TILE(2, 3, a23)
    OUT1_TILE(3, 0, a30) OUT1_TILE(3, 1, a31) OUT1_TILE(3, 2, a32) OUT1_TILE(3, 3, a33)
}

// ---------------------------------------------------------------------------
// Projection 2 (MFMA): gz = t_bf @ Wgate^T + b_gate;
// out = sigmoid(gz)*t + (1-sigmoid)*residual
// grid (8, 32)
// ---------------------------------------------------------------------------
#define OUT2_REG(mb, reg, n, Aij)                                              \
    {                                                                          \
        float gz = Aij[(reg)] + bg;                                            \
        float g = 1.0f / (1.0f + expf(-gz));                                   \
        size_t idx = (size_t)((mb) + (reg)) * 1024 + (n);                      \
        float tv = t_proj[idx];                                                \
        float rv = residual[idx];                                              \
        out[idx] = g * tv + (1.0f - g) * rv;                                   \
    }
#define OUT2_TILE(i, j, Aij)                                                   \
    {                                                                          \
        int n = ct * 128 + wc * 64 + (j) * 16 + c;                             \
        float bg = b_gate[n];                                                  \
        int mb = rt * 128 + wr * 64 + (i) * 16 + quad * 4;                     \
        OUT2_REG(mb, 0, n, Aij) OUT2_REG(mb, 1, n, Aij)                        \
        OUT2_REG(mb, 2, n, Aij) OUT2_REG(mb, 3, n, Aij)                        \
    }

__global__ __launch_bounds__(256, 1)
void out_gemm2_mfma(const unsigned short* __restrict__ t_bf,
                    const unsigned short* __restrict__ Wgb,
                    const float* __restrict__ b_gate,
                    const float* __restrict__ t_proj,
                    const float* __restrict__ residual,
                    float* __restrict__ out) {
    int ct = blockIdx.x, rt = blockIdx.y;

    GEMM_MAIN_LOOP(t_bf, Wgb)

    OUT2_TILE(0, 0, a00) OUT2_TILE(0, 1, a01) OUT2_TILE(0, 2, a02) OUT2_TILE(0, 3, a03)
    OUT2_TILE(1, 0, a10) OUT2_TILE(1, 1, a11) OUT2_TILE(1, 2, a12) OUT2_TILE(1, 3, a13)
    OUT2_TILE(2, 0, a20) OUT2_TILE(2, 1, a21) OUT2_TILE(2, 2, a22) OUT2_TILE(2, 3, a23)
    OUT2_TILE(3, 0, a30) OUT2_TILE(3, 1, a31) OUT2_TILE(3, 2, a32) OUT2_TILE(3, 3, a33)
}

// ---------------------------------------------------------------------------
// Flash attention, bf16 MFMA (16x16x32) — unchanged (verified)
// ---------------------------------------------------------------------------
#define KSTR 72

__global__ __launch_bounds__(256)
void attn_kernel(const unsigned short* __restrict__ q,
                 const unsigned short* __restrict__ k,
                 const unsigned short* __restrict__ v,
                 const float* __restrict__ bias,
                 unsigned short* __restrict__ attended) {
    int qt = blockIdx.x, h = blockIdx.y, b = blockIdx.z;
    __shared__ unsigned short Ks[64 * KSTR];
    __shared__ unsigned short Vt[64 * KSTR];
    __shared__ unsigned short Ps[64 * KSTR];
    __shared__ float af[64];
    __shared__ float lf[64];

    int tid = threadIdx.x;
    int wave = tid >> 6, lane = tid & 63;
    int quad = lane >> 4, c = lane & 15;
    int wb = wave * 16;
    size_t headbase = (((size_t)b * NHEADS + h) * SEQ) * HDIM;
    int q0 = qt * 64;

    const unsigned short* qrow = q + headbase + (size_t)(q0 + wb + c) * HDIM;
    bf16x8 aq0 = *(const bf16x8*)(qrow + quad * 8);
    bf16x8 aq1 = *(const bf16x8*)(qrow + 32 + quad * 8);

    int sr = tid >> 2, sc0 = (tid & 3) * 16;

    f32x4 oacc[4];
    #pragma unroll
    for (int t = 0; t < 4; ++t) oacc[t] = (f32x4)0.f;
    float mrow[4], lrow[4];
    #pragma unroll
    for (int r = 0; r < 4; ++r) { mrow[r] = -1e30f; lrow[r] = 0.f; }

    for (int kt = 0; kt < 8; ++kt) {
        int kv0 = kt * 64;
        __syncthreads();
        {
            const unsigned short* krow = k + headbase + (size_t)(kv0 + sr) * HDIM + sc0;
            const unsigned short* vrow = v + headbase + (size_t)(kv0 + sr) * HDIM + sc0;
            u16x8 ka = *(const u16x8*)(krow);
            u16x8 kb2 = *(const u16x8*)(krow + 8);
            u16x8 va = *(const u16x8*)(vrow);
            u16x8 vb2 = *(const u16x8*)(vrow + 8);
            *(u16x8*)&Ks[sr * KSTR + sc0] = ka;
            *(u16x8*)&Ks[sr * KSTR + sc0 + 8] = kb2;
            #pragma unroll
            for (int j = 0; j < 8; ++j) Vt[(sc0 + j) * KSTR + sr] = va[j];
            #pragma unroll
            for (int j = 0; j < 8; ++j) Vt[(sc0 + 8 + j) * KSTR + sr] = vb2[j];
        }
        __syncthreads();

        f32x4 sacc[4];
        #pragma unroll
        for (int nt = 0; nt < 4; ++nt) {
            const unsigned short* kbase = &Ks[(nt * 16 + c) * KSTR];
            bf16x8 b0 = *(const bf16x8*)(kbase + quad * 8);
            bf16x8 b1 = *(const bf16x8*)(kbase + 32 + quad * 8);
            f32x4 a = (f32x4)0.f;
            a = __builtin_amdgcn_mfma_f32_16x16x32_bf16(aq0, b0, a, 0, 0, 0);
            a = __builtin_amdgcn_mfma_f32_16x16x32_bf16(aq1, b1, a, 0, 0, 0);
            sacc[nt] = a;
        }

        const float* bbase = bias + (size_t)(q0 + wb + quad * 4) * 512 + kv0 + c;
        float tmax[4];
        #pragma unroll
        for (int r = 0; r < 4; ++r) tmax[r] = -1e30f;
        #pragma unroll
        for (int nt = 0; nt < 4; ++nt)
            #pragma unroll
            for (int r = 0; r < 4; ++r) {
                float s = sacc[nt][r] * SCALE + bbase[(size_t)r * 512 + nt * 16];
                sacc[nt][r] = s;
                tmax[r] = fmaxf(tmax[r], s);
            }
        #pragma unroll
        for (int r = 0; r < 4; ++r) {
            float t = tmax[r];
            t = fmaxf(t, __shfl_xor(t, 1));
            t = fmaxf(t, __shfl_xor(t, 2));
            t = fmaxf(t, __shfl_xor(t, 4));
            t = fmaxf(t, __shfl_xor(t, 8));
            tmax[r] = t;
        }
        float alpha[4];
        #pragma unroll
        for (int r = 0; r < 4; ++r) {
            float mnew = fmaxf(mrow[r], tmax[r]);
            alpha[r] = __expf(mrow[r] - mnew);
            mrow[r] = mnew;
        }
        float tsum[4];
        #pragma unroll
        for (int r = 0; r < 4; ++r) tsum[r] = 0.f;
        #pragma unroll
        for (int nt = 0; nt < 4; ++nt)
            #pragma unroll
            for (int r = 0; r < 4; ++r) {
                float p = __expf(sacc[nt][r] - mrow[r]);
                tsum[r] += p;
                Ps[(wb + quad * 4 + r) * KSTR + nt * 16 + c] = f2bf(p);
            }
        #pragma unroll
        for (int r = 0; r < 4; ++r) {
            float t = tsum[r];
            t += __shfl_xor(t, 1);
            t += __shfl_xor(t, 2);
            t += __shfl_xor(t, 4);
            t += __shfl_xor(t, 8);
            lrow[r] = lrow[r] * alpha[r] + t;
        }
        if (c == 0) {
            f32x4 av;
            av[0] = alpha[0]; av[1] = alpha[1]; av[2] = alpha[2]; av[3] = alpha[3];
            *(f32x4*)&af[wb + quad * 4] = av;
        }
        float myalpha = af[wb + c];
        #pragma unroll
        for (int t = 0; t < 4; ++t) oacc[t] *= myalpha;

        bf16x8 pb0 = *(const bf16x8*)&Ps[(wb + c) * KSTR + quad * 8];
        bf16x8 pb1 = *(const bf16x8*)&Ps[(wb + c) * KSTR + 32 + quad * 8];
        #pragma unroll
        for (int t = 0; t < 4; ++t) {
            const unsigned short* vbase = &Vt[(t * 16 + c) * KSTR];
            bf16x8 a0 = *(const bf16x8*)(vbase + quad * 8);
            bf16x8 a1 = *(const bf16x8*)(vbase + 32 + quad * 8);
            oacc[t] = __builtin_amdgcn_mfma_f32_16x16x32_bf16(a0, pb0, oacc[t], 0, 0, 0);
            oacc[t] = __builtin_amdgcn_mfma_f32_16x16x32_bf16(a1, pb1, oacc[t], 0, 0, 0);
        }
    }

    if (c == 0) {
        f32x4 lv;
        lv[0] = lrow[0]; lv[1] = lrow[1]; lv[2] = lrow[2]; lv[3] = lrow[3];
        *(f32x4*)&lf[wb + quad * 4] = lv;
    }
    float invl = 1.0f / lf[wb + c];
    unsigned short* drow = attended + ((size_t)b * SEQ + (q0 + wb + c)) * D_MODEL + h * HDIM;
    #pragma unroll
    for (int t = 0; t < 4; ++t) {
        ushort4 o;
        o.x = f2bf(oacc[t][0] * invl);
        o.y = f2bf(oacc[t][1] * invl);
        o.z = f2bf(oacc[t][2] * invl);
        o.w = f2bf(oacc[t][3] * invl);
        *(ushort4*)(drow + t * 16 + quad * 4) = o;
    }
}

extern "C" void kernel_launch(void* const* d_in, const int* in_sizes, int n_in,
                              void* d_out, int out_size, void* d_ws, size_t ws_size,
                              hipStream_t stream) {
    const float* dec    = (const float*)d_in[0];
    const float* enc    = (const float*)d_in[1];
    const float* Wqkv   = (const float*)d_in[2];
    const float* Wout   = (const float*)d_in[3];
    const float* b_out  = (const float*)d_in[4];
    const float* Wgate  = (const float*)d_in[5];
    const float* b_gate = (const float*)d_in[6];
    const float* gamma  = (const float*)d_in[7];
    const float* beta   = (const float*)d_in[8];
    float* out = (float*)d_out;

    char* ws = (char*)d_ws;
    const size_t MB = 1024 * 1024;
    unsigned short* q_ln    = (unsigned short*)(ws + 0 * MB);
    unsigned short* kv_ln   = (unsigned short*)(ws + 8 * MB);
    unsigned short* qb      = (unsigned short*)(ws + 16 * MB);
    unsigned short* kb      = (unsigned short*)(ws + 24 * MB);
    unsigned short* vb      = (unsigned short*)(ws + 32 * MB);
    unsigned short* Wqkv_bf = (unsigned short*)(ws + 40 * MB);
    float*          bias    = (float*)(ws + 46 * MB);
    unsigned short* att     = (unsigned short*)(ws + 0 * MB);
    float*          t_proj  = (float*)(ws + 8 * MB);
    unsigned short* t_bf    = (unsigned short*)(ws + 24 * MB);
    unsigned short* Wout_bf = (unsigned short*)(ws + 32 * MB);   // vb dead after attn
    unsigned short* Wgate_bf= (unsigned short*)(ws + 34 * MB);

    prep_kernel<<<12288, 256, 0, stream>>>(dec, enc, gamma, beta, Wqkv,
                                           q_ln, kv_ln, bias, Wqkv_bf);
    qkv_gemm_mfma<<<768, 256, 0, stream>>>(q_ln, kv_ln, Wqkv_bf, qb, kb, vb);
    attn_kernel<<<dim3(8, 16, 8), 256, 0, stream>>>(qb, kb, vb, bias, att);
    convert_og<<<2048, 256, 0, stream>>>(Wout, Wgate, Wout_bf, Wgate_bf);
    out_gemm1_mfma<<<dim3(8, 32), 256, 0, stream>>>(att, Wout_bf, b_out, t_proj, t_bf);
    out_gemm2_mfma<<<dim3(8, 32), 256, 0, stream>>>(t_bf, Wgate_bf, b_gate, t_proj, dec, out);
}

// Round 9
// 273.801 us; speedup vs baseline: 1.0570x; 1.0570x over previous
//
#include <hip/hip_runtime.h>
#include <hip/hip_bf16.h>

#define D_MODEL 1024
#define NHEADS 16
#define HDIM 64
#define BATCH 8
#define SEQ 512
#define NROWS 4096          // BATCH*SEQ
#define SCALE 0.125f
#define LN_EPS 1e-5f

typedef __attribute__((ext_vector_type(8))) short bf16x8;      // 8 bf16 (4 VGPRs)
typedef __attribute__((ext_vector_type(4))) float f32x4;
typedef __attribute__((ext_vector_type(8))) unsigned short u16x8;

static __device__ __forceinline__ float bf2f(unsigned short u) {
    return __uint_as_float(((unsigned int)u) << 16);
}
static __device__ __forceinline__ unsigned short f2bf(float f) {
    unsigned int x = __float_as_uint(f);
    unsigned int r = (x + 0x7fffu + ((x >> 16) & 1u)) >> 16;   // RNE
    return (unsigned short)r;
}

// async 16B/lane global->LDS DMA; LDS dest = wave-uniform base + lane*16
#define GLOAD16(gp, lp)                                                        \
    __builtin_amdgcn_global_load_lds(                                          \
        (const __attribute__((address_space(1))) void*)(gp),                   \
        (__attribute__((address_space(3))) void*)(lp), 16, 0, 0)

// ---------------------------------------------------------------------------
// Bias helper: jax.image.resize(bias128, (512,512), 'bilinear')
// ---------------------------------------------------------------------------
static __device__ __forceinline__ float bias128(int a, int b) {
    float d = fabsf((float)(a - b));
    return expf(-d * 0.1f) - d * 0.05f;
}

// ---------------------------------------------------------------------------
// prep_kernel: fused LN (blocks 0..8191) + bias table (8192..9215) +
// Wqkv fp32->bf16 convert (9216..12287)
// ---------------------------------------------------------------------------
__global__ void prep_kernel(const float* __restrict__ dec, const float* __restrict__ enc,
                            const float* __restrict__ gamma, const float* __restrict__ beta,
                            const float* __restrict__ Wqkv,
                            unsigned short* __restrict__ q_ln, unsigned short* __restrict__ kv_ln,
                            float* __restrict__ bias, unsigned short* __restrict__ Wqkv_bf) {
    int blk = blockIdx.x;
    int t = threadIdx.x;
    if (blk >= 9216) {          // Wqkv convert
        int idx = (blk - 9216) * 256 + t;
        float4 v = ((const float4*)Wqkv)[idx];
        ushort4 u;
        u.x = f2bf(v.x); u.y = f2bf(v.y); u.z = f2bf(v.z); u.w = f2bf(v.w);
        ((ushort4*)Wqkv_bf)[idx] = u;
        return;
    }
    if (blk >= 8192) {          // bias
        int idx = (blk - 8192) * 256 + t;
        int qi = idx >> 9, kj = idx & 511;
        float fq = (qi + 0.5f) * 0.25f - 0.5f;
        float fk = (kj + 0.5f) * 0.25f - 0.5f;
        int iq = (int)floorf(fq); float tq = fq - (float)iq;
        int ik = (int)floorf(fk); float tk = fk - (float)ik;
        int iq0 = min(max(iq, 0), 127), iq1 = min(max(iq + 1, 0), 127);
        int ik0 = min(max(ik, 0), 127), ik1 = min(max(ik + 1, 0), 127);
        float v = (1.f - tq) * ((1.f - tk) * bias128(iq0, ik0) + tk * bias128(iq0, ik1))
                +        tq  * ((1.f - tk) * bias128(iq1, ik0) + tk * bias128(iq1, ik1));
        bias[idx] = v;
        return;
    }
    int row = blk;
    const float* src = (row < NROWS) ? dec + (size_t)row * D_MODEL
                                     : enc + (size_t)(row - NROWS) * D_MODEL;
    unsigned short* dst = (row < NROWS) ? q_ln + (size_t)row * D_MODEL
                                        : kv_ln + (size_t)(row - NROWS) * D_MODEL;
    float4 x = ((const float4*)src)[t];
    float s  = x.x + x.y + x.z + x.w;
    float ss = x.x * x.x + x.y * x.y + x.z * x.z + x.w * x.w;
    #pragma unroll
    for (int off = 32; off > 0; off >>= 1) {
        s  += __shfl_down(s, off);
        ss += __shfl_down(ss, off);
    }
    __shared__ float red_s[4], red_ss[4];
    int wid = t >> 6, lane = t & 63;
    if (lane == 0) { red_s[wid] = s; red_ss[wid] = ss; }
    __syncthreads();
    if (t == 0) {
        float S = red_s[0] + red_s[1] + red_s[2] + red_s[3];
        float SS = red_ss[0] + red_ss[1] + red_ss[2] + red_ss[3];
        red_s[0] = S; red_ss[0] = SS;
    }
    __syncthreads();
    float mu  = red_s[0] * (1.0f / 1024.0f);
    float var = red_ss[0] * (1.0f / 1024.0f) - mu * mu;
    float rstd = rsqrtf(var + LN_EPS);
    float4 g = ((const float4*)gamma)[t];
    float4 bb = ((const float4*)beta)[t];
    ushort4 u;
    u.x = f2bf((x.x - mu) * rstd * g.x + bb.x);
    u.y = f2bf((x.y - mu) * rstd * g.y + bb.y);
    u.z = f2bf((x.z - mu) * rstd * g.z + bb.z);
    u.w = f2bf((x.w - mu) * rstd * g.w + bb.w);
    ((ushort4*)dst)[t] = u;
}

// ---------------------------------------------------------------------------
// Wout + Wgate fp32 -> bf16
// ---------------------------------------------------------------------------
__global__ void convert_og(const float* __restrict__ Wout, const float* __restrict__ Wgate,
                           unsigned short* __restrict__ Wout_bf, unsigned short* __restrict__ Wgate_bf) {
    int idx = blockIdx.x * 256 + threadIdx.x;
    const float* src; unsigned short* dst; int off;
    if (idx < 262144) { src = (const float*)Wout; dst = Wout_bf; off = idx; }
    else              { src = (const float*)Wgate; dst = Wgate_bf; off = idx - 262144; }
    float4 v = ((const float4*)src)[off];
    ushort4 u;
    u.x = f2bf(v.x); u.y = f2bf(v.y); u.z = f2bf(v.z); u.w = f2bf(v.w);
    ((ushort4*)dst)[off] = u;
}

// ===========================================================================
// Shared MFMA GEMM: C(128x128) = A(128xK) @ W^T(128xK), bf16.
// R7 lesson: accumulators must be NAMED scalars (arrays -> scratch:
//   VGPR~68 + GB WRITE_SIZE + MfmaUtil 3%).
// R8 lesson: register prefetch regresses (74->100us); per guide m131-m141
//   the fix for this structure is global_load_lds, not scheduling tweaks.
// R9: staging via global_load_lds width=16 (m93->m97 = 1.69x on the ladder).
//   Constraint: LDS dest = wave-uniform base + lane*16 -> unpadded stride-64
//   rows. Bank conflicts avoided via XOR chunk swizzle: row r slot p holds
//   global 16B-chunk (p ^ (r&7)); the permutation is applied on the per-lane
//   GLOBAL source address (free), reads recompute p = chunk ^ (row&7).
// ===========================================================================
#define CSTR 136   // C-bounce row stride (multiple of 8 -> 16B-aligned rows)

union alignas(16) GemmSmem {
    struct { unsigned short A[128 * 64]; unsigned short B[128 * 64]; } ab;  // 32 KB staging
    unsigned short C[128 * CSTR];                                           // 34816 B bounce
};

#define MF(a, b, d) __builtin_amdgcn_mfma_f32_16x16x32_bf16((a), (b), (d), 0, 0, 0)

#define GEMM_KH(kh)                                                            \
    {                                                                          \
        const unsigned short* Arow_ = &As[(wr * 64 + c) * 64 + pofs##kh];      \
        const unsigned short* Brow_ = &Bs[(wc * 64 + c) * 64 + pofs##kh];      \
        bf16x8 f0 = *(const bf16x8*)(Arow_);                                   \
        bf16x8 f1 = *(const bf16x8*)(Arow_ + 1024);                            \
        bf16x8 f2 = *(const bf16x8*)(Arow_ + 2048);                            \
        bf16x8 f3 = *(const bf16x8*)(Arow_ + 3072);                            \
        bf16x8 g0 = *(const bf16x8*)(Brow_);                                   \
        bf16x8 g1 = *(const bf16x8*)(Brow_ + 1024);                            \
        bf16x8 g2 = *(const bf16x8*)(Brow_ + 2048);                            \
        bf16x8 g3 = *(const bf16x8*)(Brow_ + 3072);                            \
        a00 = MF(f0, g0, a00); a01 = MF(f0, g1, a01); a02 = MF(f0, g2, a02); a03 = MF(f0, g3, a03); \
        a10 = MF(f1, g0, a10); a11 = MF(f1, g1, a11); a12 = MF(f1, g2, a12); a13 = MF(f1, g3, a13); \
        a20 = MF(f2, g0, a20); a21 = MF(f2, g1, a21); a22 = MF(f2, g2, a22); a23 = MF(f2, g3, a23); \
        a30 = MF(f3, g0, a30); a31 = MF(f3, g1, a31); a32 = MF(f3, g2, a32); a33 = MF(f3, g3, a33); \
    }

#define GEMM_MAIN_LOOP(Aptr, Bptr)                                             \
    __shared__ GemmSmem smem;                                                  \
    unsigned short* As = smem.ab.A;                                            \
    unsigned short* Bs = smem.ab.B;                                            \
    int tid = threadIdx.x;                                                     \
    int wave = tid >> 6, lane = tid & 63, quad = lane >> 4, c = lane & 15;     \
    int wr = wave >> 1, wc = wave & 1;                                         \
    int x7 = c & 7;                                                            \
    int pofs0 = (quad ^ x7) * 8;                                               \
    int pofs1 = ((4 + quad) ^ x7) * 8;                                         \
    int grow = lane >> 3;                                                      \
    int cg = ((lane & 7) ^ grow) * 8;                                          \
    const unsigned short* Ag = (Aptr) + (size_t)(rt * 128 + wave * 32 + grow) * 1024 + cg; \
    const unsigned short* Bg = (Bptr) + (size_t)(ct * 128 + wave * 32 + grow) * 1024 + cg; \
    unsigned short* AsW = As + wave * 2048;                                    \
    unsigned short* BsW = Bs + wave * 2048;                                    \
    f32x4 a00 = (f32x4)0.f, a01 = (f32x4)0.f, a02 = (f32x4)0.f, a03 = (f32x4)0.f; \
    f32x4 a10 = (f32x4)0.f, a11 = (f32x4)0.f, a12 = (f32x4)0.f, a13 = (f32x4)0.f; \
    f32x4 a20 = (f32x4)0.f, a21 = (f32x4)0.f, a22 = (f32x4)0.f, a23 = (f32x4)0.f; \
    f32x4 a30 = (f32x4)0.f, a31 = (f32x4)0.f, a32 = (f32x4)0.f, a33 = (f32x4)0.f; \
    for (int kt = 0; kt < 16; ++kt) {                                          \
        int k0 = kt * 64;                                                      \
        __syncthreads();                                                       \
        GLOAD16(Ag + k0,         AsW);                                         \
        GLOAD16(Ag + 8192 + k0,  AsW + 512);                                   \
        GLOAD16(Ag + 16384 + k0, AsW + 1024);                                  \
        GLOAD16(Ag + 24576 + k0, AsW + 1536);                                  \
        GLOAD16(Bg + k0,         BsW);                                         \
        GLOAD16(Bg + 8192 + k0,  BsW + 512);                                   \
        GLOAD16(Bg + 16384 + k0, BsW + 1024);                                  \
        GLOAD16(Bg + 24576 + k0, BsW + 1536);                                  \
        __syncthreads();                                                       \
        GEMM_KH(0)                                                             \
        GEMM_KH(1)                                                             \
    }

// ---------------------------------------------------------------------------
// QKV GEMM (MFMA) + fused RoPE, LDS-bounce epilogue with wide stores.
// 1-D grid of 768, swizzled into 8(ct)x4(rt) super-tiles for L2 locality.
// ---------------------------------------------------------------------------
#define ROPE_REG(i, reg, A0, A1, A2, A3)                                       \
    {                                                                          \
        int mloc = wr * 64 + (i) * 16 + quad * 4 + (reg);                      \
        int crow = mloc * CSTR + wc * 64;                                      \
        float fl = (float)((rt * 128 + mloc) & 511);                           \
        float aa0 = fl * inv0, aa1 = fl * inv1;                                \
        float c0 = cosf(aa0), s0 = sinf(aa0);                                  \
        float c1 = cosf(aa1), s1 = sinf(aa1);                                  \
        float e0 = A0[(reg)], o0 = A2[(reg)];                                  \
        float e1 = A1[(reg)], o1 = A3[(reg)];                                  \
        smem.C[crow + c]      = f2bf(e0 * c0 - o0 * s0);                       \
        smem.C[crow + 32 + c] = f2bf(e0 * s0 + o0 * c0);                       \
        smem.C[crow + 16 + c] = f2bf(e1 * c1 - o1 * s1);                       \
        smem.C[crow + 48 + c] = f2bf(e1 * s1 + o1 * c1);                       \
    }
#define ROPE_ROW(i, A0, A1, A2, A3)                                            \
    ROPE_REG(i, 0, A0, A1, A2, A3) ROPE_REG(i, 1, A0, A1, A2, A3)              \
    ROPE_REG(i, 2, A0, A1, A2, A3) ROPE_REG(i, 3, A0, A1, A2, A3)

#define VSEC_REG(i, reg, A0, A1, A2, A3)                                       \
    {                                                                          \
        int crow = (wr * 64 + (i) * 16 + quad * 4 + (reg)) * CSTR + wc * 64;   \
        smem.C[crow + c]      = f2bf(A0[(reg)]);                               \
        smem.C[crow + 16 + c] = f2bf(A1[(reg)]);                               \
        smem.C[crow + 32 + c] = f2bf(A2[(reg)]);                               \
        smem.C[crow + 48 + c] = f2bf(A3[(reg)]);                               \
    }
#define VSEC_ROW(i, A0, A1, A2, A3)                                            \
    VSEC_REG(i, 0, A0, A1, A2, A3) VSEC_REG(i, 1, A0, A1, A2, A3)              \
    VSEC_REG(i, 2, A0, A1, A2, A3) VSEC_REG(i, 3, A0, A1, A2, A3)

__global__ __launch_bounds__(256, 1)
void qkv_gemm_mfma(const unsigned short* __restrict__ q_ln,
                   const unsigned short* __restrict__ kv_ln,
                   const unsigned short* __restrict__ Wb,
                   unsigned short* __restrict__ qo,
                   unsigned short* __restrict__ ko,
                   unsigned short* __restrict__ vo) {
    int bid = blockIdx.x;               // 0..767
    int st = bid >> 5, in = bid & 31;   // 24 super-tiles of 32 blocks
    int stc = st % 3, str = st / 3;
    int ct = stc * 8 + (in & 7);        // 0..23
    int rt = str * 4 + (in >> 3);       // 0..31
    int n0 = ct * 128;
    int section = n0 >> 10;             // 0=q 1=k 2=v (uniform per block)
    const unsigned short* A = (section == 0) ? q_ln : kv_ln;

    GEMM_MAIN_LOOP(A, Wb)

    __syncthreads();                    // all waves done reading As/Bs
    if (section == 2) {
        VSEC_ROW(0, a00, a01, a02, a03)
        VSEC_ROW(1, a10, a11, a12, a13)
        VSEC_ROW(2, a20, a21, a22, a23)
        VSEC_ROW(3, a30, a31, a32, a33)
    } else {
        float inv0 = expf(-0.2878231366f * (float)c);          // 10000^(-c/32)
        float inv1 = expf(-0.2878231366f * (float)(16 + c));
        ROPE_ROW(0, a00, a01, a02, a03)
        ROPE_ROW(1, a10, a11, a12, a13)
        ROPE_ROW(2, a20, a21, a22, a23)
        ROPE_ROW(3, a30, a31, a32, a33)
    }
    __syncthreads();

    unsigned short* outp = (section == 0) ? qo : (section == 1) ? ko : vo;
    int rr = tid >> 1, ch = tid & 1;    // row 0..127, head-half 0/1
    int mm = rt * 128 + rr;
    int bb = mm >> 9, ll = mm & 511;
    int h = ((n0 & 1023) >> 6) + ch;
    unsigned short* orow = outp + (((size_t)bb * NHEADS + h) * SEQ + ll) * HDIM;
    const unsigned short* csrc = &smem.C[rr * CSTR + ch * 64];
    #pragma unroll
    for (int kc = 0; kc < 8; ++kc)
        *(u16x8*)(orow + kc * 8) = *(const u16x8*)(csrc + kc * 8);
}

// ---------------------------------------------------------------------------
// Projection 1 (MFMA): t = att @ Wout^T + b_out -> fp32 t_proj + bf16 t_bf
// ---------------------------------------------------------------------------
#define OUT1_REG(mb, reg, n, Aij)                                              \
    {                                                                          \
        float v = Aij[(reg)] + bo;                                             \
        t_proj[(size_t)((mb) + (reg)) * 1024 + (n)] = v;                       \
        t_bf[(size_t)((mb) + (reg)) * 1024 + (n)] = f2bf(v);                   \
    }
#define OUT1_TILE(i, j, Aij)                                                   \
    {                                                                          \
        int n = ct * 128 + wc * 64 + (j) * 16 + c;                             \
        float bo = b_out[n];                                                   \
        int mb = rt * 128 + wr * 64 + (i) * 16 + quad * 4;                     \
        OUT1_REG(mb, 0, n, Aij) OUT1_REG(mb, 1, n, Aij)                        \
        OUT1_REG(mb, 2, n, Aij) OUT1_REG(mb, 3, n, Aij)                        \
    }

__global__ __launch_bounds__(256, 1)
void out_gemm1_mfma(const unsigned short* __restrict__ att,
                    const unsigned short* __restrict__ Wob,
                    const float* __restrict__ b_out,
                    float* __restrict__ t_proj,
                    unsigned short* __restrict__ t_bf) {
    int ct = blockIdx.x, rt = blockIdx.y;

    GEMM_MAIN_LOOP(att, Wob)

    OUT1_TILE(0, 0, a00) OUT1_TILE(0, 1, a01) OUT1_TILE(0, 2, a02) OUT1_TILE(0, 3, a03)
    OUT1_TILE(1, 0, a10) OUT1_TILE(1, 1, a11) OUT1_TILE(1, 2, a12) OUT1_TILE(1, 3, a13)
    OUT1_TILE(2, 0, a20) OUT1_TILE(2, 1, a21) OUT1_TILE(2, 2, a22) OUT1_TILE(2, 3, a23)
    OUT1_TILE(3, 0, a30) OUT1_TILE(3, 1, a31) OUT1_TILE(3, 2, a32) OUT1_TILE(3, 3, a33)
}

// ---------------------------------------------------------------------------
// Projection 2 (MFMA): gz = t_bf @ Wgate^T + b_gate;
// out = sigmoid(gz)*t + (1-sigmoid)*residual
// ---------------------------------------------------------------------------
#define OUT2_REG(mb, reg, n, Aij)                                              \
    {                                                                          \
        float gz = Aij[(reg)] + bg;                                            \
        float g = 1.0f / (1.0f + expf(-gz));                                   \
        size_t idx = (size_t)((mb) + (reg)) * 1024 + (n);                      \
        float tv = t_proj[idx];                                                \
        float rv = residual[idx];                                              \
        out[idx] = g * tv + (1.0f - g) * rv;                                   \
    }
#define OUT2_TILE(i, j, Aij)                                                   \
    {                                                                          \
        int n = ct * 128 + wc * 64 + (j) * 16 + c;                             \
        float bg = b_gate[n];                                                  \
        int mb = rt * 128 + wr * 64 + (i) * 16 + quad * 4;                     \
        OUT2_REG(mb, 0, n, Aij) OUT2_REG(mb, 1, n, Aij)                        \
        OUT2_REG(mb, 2, n, Aij) OUT2_REG(mb, 3, n, Aij)                        \
    }

__global__ __launch_bounds__(256, 1)
void out_gemm2_mfma(const unsigned short* __restrict__ t_bf,
                    const unsigned short* __restrict__ Wgb,
                    const float* __restrict__ b_gate,
                    const float* __restrict__ t_proj,
                    const float* __restrict__ residual,
                    float* __restrict__ out) {
    int ct = blockIdx.x, rt = blockIdx.y;

    GEMM_MAIN_LOOP(t_bf, Wgb)

    OUT2_TILE(0, 0, a00) OUT2_TILE(0, 1, a01) OUT2_TILE(0, 2, a02) OUT2_TILE(0, 3, a03)
    OUT2_TILE(1, 0, a10) OUT2_TILE(1, 1, a11) OUT2_TILE(1, 2, a12) OUT2_TILE(1, 3, a13)
    OUT2_TILE(2, 0, a20) OUT2_TILE(2, 1, a21) OUT2_TILE(2, 2, a22) OUT2_TILE(2, 3, a23)
    OUT2_TILE(3, 0, a30) OUT2_TILE(3, 1, a31) OUT2_TILE(3, 2, a32) OUT2_TILE(3, 3, a33)
}

// ---------------------------------------------------------------------------
// Flash attention, bf16 MFMA (16x16x32) — unchanged (verified)
// ---------------------------------------------------------------------------
#define KSTR 72

__global__ __launch_bounds__(256)
void attn_kernel(const unsigned short* __restrict__ q,
                 const unsigned short* __restrict__ k,
                 const unsigned short* __restrict__ v,
                 const float* __restrict__ bias,
                 unsigned short* __restrict__ attended) {
    int qt = blockIdx.x, h = blockIdx.y, b = blockIdx.z;
    __shared__ unsigned short Ks[64 * KSTR];
    __shared__ unsigned short Vt[64 * KSTR];
    __shared__ unsigned short Ps[64 * KSTR];
    __shared__ float af[64];
    __shared__ float lf[64];

    int tid = threadIdx.x;
    int wave = tid >> 6, lane = tid & 63;
    int quad = lane >> 4, c = lane & 15;
    int wb = wave * 16;
    size_t headbase = (((size_t)b * NHEADS + h) * SEQ) * HDIM;
    int q0 = qt * 64;

    const unsigned short* qrow = q + headbase + (size_t)(q0 + wb + c) * HDIM;
    bf16x8 aq0 = *(const bf16x8*)(qrow + quad * 8);
    bf16x8 aq1 = *(const bf16x8*)(qrow + 32 + quad * 8);

    int sr = tid >> 2, sc0 = (tid & 3) * 16;

    f32x4 oacc[4];
    #pragma unroll
    for (int t = 0; t < 4; ++t) oacc[t] = (f32x4)0.f;
    float mrow[4], lrow[4];
    #pragma unroll
    for (int r = 0; r < 4; ++r) { mrow[r] = -1e30f; lrow[r] = 0.f; }

    for (int kt = 0; kt < 8; ++kt) {
        int kv0 = kt * 64;
        __syncthreads();
        {
            const unsigned short* krow = k + headbase + (size_t)(kv0 + sr) * HDIM + sc0;
            const unsigned short* vrow = v + headbase + (size_t)(kv0 + sr) * HDIM + sc0;
            u16x8 ka = *(const u16x8*)(krow);
            u16x8 kb2 = *(const u16x8*)(krow + 8);
            u16x8 va = *(const u16x8*)(vrow);
            u16x8 vb2 = *(const u16x8*)(vrow + 8);
            *(u16x8*)&Ks[sr * KSTR + sc0] = ka;
            *(u16x8*)&Ks[sr * KSTR + sc0 + 8] = kb2;
            #pragma unroll
            for (int j = 0; j < 8; ++j) Vt[(sc0 + j) * KSTR + sr] = va[j];
            #pragma unroll
            for (int j = 0; j < 8; ++j) Vt[(sc0 + 8 + j) * KSTR + sr] = vb2[j];
        }
        __syncthreads();

        f32x4 sacc[4];
        #pragma unroll
        for (int nt = 0; nt < 4; ++nt) {
            const unsigned short* kbase = &Ks[(nt * 16 + c) * KSTR];
            bf16x8 b0 = *(const bf16x8*)(kbase + quad * 8);
            bf16x8 b1 = *(const bf16x8*)(kbase + 32 + quad * 8);
            f32x4 a = (f32x4)0.f;
            a = __builtin_amdgcn_mfma_f32_16x16x32_bf16(aq0, b0, a, 0, 0, 0);
            a = __builtin_amdgcn_mfma_f32_16x16x32_bf16(aq1, b1, a, 0, 0, 0);
            sacc[nt] = a;
        }

        const float* bbase = bias + (size_t)(q0 + wb + quad * 4) * 512 + kv0 + c;
        float tmax[4];
        #pragma unroll
        for (int r = 0; r < 4; ++r) tmax[r] = -1e30f;
        #pragma unroll
        for (int nt = 0; nt < 4; ++nt)
            #pragma unroll
            for (int r = 0; r < 4; ++r) {
                float s = sacc[nt][r] * SCALE + bbase[(size_t)r * 512 + nt * 16];
                sacc[nt][r] = s;
                tmax[r] = fmaxf(tmax[r], s);
            }
        #pragma unroll
        for (int r = 0; r < 4; ++r) {
            float t = tmax[r];
            t = fmaxf(t, __shfl_xor(t, 1));
            t = fmaxf(t, __shfl_xor(t, 2));
            t = fmaxf(t, __shfl_xor(t, 4));
            t = fmaxf(t, __shfl_xor(t, 8));
            tmax[r] = t;
        }
        float alpha[4];
        #pragma unroll
        for (int r = 0; r < 4; ++r) {
            float mnew = fmaxf(mrow[r], tmax[r]);
            alpha[r] = __expf(mrow[r] - mnew);
            mrow[r] = mnew;
        }
        float tsum[4];
        #pragma unroll
        for (int r = 0; r < 4; ++r) tsum[r] = 0.f;
        #pragma unroll
        for (int nt = 0; nt < 4; ++nt)
            #pragma unroll
            for (int r = 0; r < 4; ++r) {
                float p = __expf(sacc[nt][r] - mrow[r]);
                tsum[r] += p;
                Ps[(wb + quad * 4 + r) * KSTR + nt * 16 + c] = f2bf(p);
            }
        #pragma unroll
        for (int r = 0; r < 4; ++r) {
            float t = tsum[r];
            t += __shfl_xor(t, 1);
            t += __shfl_xor(t, 2);
            t += __shfl_xor(t, 4);
            t += __shfl_xor(t, 8);
            lrow[r] = lrow[r] * alpha[r] + t;
        }
        if (c == 0) {
            f32x4 av;
            av[0] = alpha[0]; av[1] = alpha[1]; av[2] = alpha[2]; av[3] = alpha[3];
            *(f32x4*)&af[wb + quad * 4] = av;
        }
        float myalpha = af[wb + c];
        #pragma unroll
        for (int t = 0; t < 4; ++t) oacc[t] *= myalpha;

        bf16x8 pb0 = *(const bf16x8*)&Ps[(wb + c) * KSTR + quad * 8];
        bf16x8 pb1 = *(const bf16x8*)&Ps[(wb + c) * KSTR + 32 + quad * 8];
        #pragma unroll
        for (int t = 0; t < 4; ++t) {
            const unsigned short* vbase = &Vt[(t * 16 + c) * KSTR];
            bf16x8 a0 = *(const bf16x8*)(vbase + quad * 8);
            bf16x8 a1 = *(const bf16x8*)(vbase + 32 + quad * 8);
            oacc[t] = __builtin_amdgcn_mfma_f32_16x16x32_bf16(a0, pb0, oacc[t], 0, 0, 0);
            oacc[t] = __builtin_amdgcn_mfma_f32_16x16x32_bf16(a1, pb1, oacc[t], 0, 0, 0);
        }
    }

    if (c == 0) {
        f32x4 lv;
        lv[0] = lrow[0]; lv[1] = lrow[1]; lv[2] = lrow[2]; lv[3] = lrow[3];
        *(f32x4*)&lf[wb + quad * 4] = lv;
    }
    float invl = 1.0f / lf[wb + c];
    unsigned short* drow = attended + ((size_t)b * SEQ + (q0 + wb + c)) * D_MODEL + h * HDIM;
    #pragma unroll
    for (int t = 0; t < 4; ++t) {
        ushort4 o;
        o.x = f2bf(oacc[t][0] * invl);
        o.y = f2bf(oacc[t][1] * invl);
        o.z = f2bf(oacc[t][2] * invl);
        o.w = f2bf(oacc[t][3] * invl);
        *(ushort4*)(drow + t * 16 + quad * 4) = o;
    }
}

extern "C" void kernel_launch(void* const* d_in, const int* in_sizes, int n_in,
                              void* d_out, int out_size, void* d_ws, size_t ws_size,
                              hipStream_t stream) {
    const float* dec    = (const float*)d_in[0];
    const float* enc    = (const float*)d_in[1];
    const float* Wqkv   = (const float*)d_in[2];
    const float* Wout   = (const float*)d_in[3];
    const float* b_out  = (const float*)d_in[4];
    const float* Wgate  = (const float*)d_in[5];
    const float* b_gate = (const float*)d_in[6];
    const float* gamma  = (const float*)d_in[7];
    const float* beta   = (const float*)d_in[8];
    float* out = (float*)d_out;

    char* ws = (char*)d_ws;
    const size_t MB = 1024 * 1024;
    unsigned short* q_ln    = (unsigned short*)(ws + 0 * MB);
    unsigned short* kv_ln   = (unsigned short*)(ws + 8 * MB);
    unsigned short* qb      = (unsigned short*)(ws + 16 * MB);
    unsigned short* kb      = (unsigned short*)(ws + 24 * MB);
    unsigned short* vb      = (unsigned short*)(ws + 32 * MB);
    unsigned short* Wqkv_bf = (unsigned short*)(ws + 40 * MB);
    float*          bias    = (float*)(ws + 46 * MB);
    unsigned short* att     = (unsigned short*)(ws + 0 * MB);
    float*          t_proj  = (float*)(ws + 8 * MB);
    unsigned short* t_bf    = (unsigned short*)(ws + 24 * MB);
    unsigned short* Wout_bf = (unsigned short*)(ws + 32 * MB);   // vb dead after attn
    unsigned short* Wgate_bf= (unsigned short*)(ws + 34 * MB);

    prep_kernel<<<12288, 256, 0, stream>>>(dec, enc, gamma, beta, Wqkv,
                                           q_ln, kv_ln, bias, Wqkv_bf);
    qkv_gemm_mfma<<<768, 256, 0, stream>>>(q_ln, kv_ln, Wqkv_bf, qb, kb, vb);
    attn_kernel<<<dim3(8, 16, 8), 256, 0, stream>>>(qb, kb, vb, bias, att);
    convert_og<<<2048, 256, 0, stream>>>(Wout, Wgate, Wout_bf, Wgate_bf);
    out_gemm1_mfma<<<dim3(8, 32), 256, 0, stream>>>(att, Wout_bf, b_out, t_proj, t_bf);
    out_gemm2_mfma<<<dim3(8, 32), 256, 0, stream>>>(t_bf, Wgate_bf, b_gate, t_proj, dec, out);
}

// Round 10
// 268.174 us; speedup vs baseline: 1.0792x; 1.0210x over previous
//
#include <hip/hip_runtime.h>
#include <hip/hip_bf16.h>

#define D_MODEL 1024
#define NHEADS 16
#define HDIM 64
#define BATCH 8
#define SEQ 512
#define NROWS 4096          // BATCH*SEQ
#define SCALE 0.125f
#define LN_EPS 1e-5f

typedef __attribute__((ext_vector_type(8))) short bf16x8;      // 8 bf16 (4 VGPRs)
typedef __attribute__((ext_vector_type(4))) float f32x4;
typedef __attribute__((ext_vector_type(8))) unsigned short u16x8;

static __device__ __forceinline__ float bf2f(unsigned short u) {
    return __uint_as_float(((unsigned int)u) << 16);
}
static __device__ __forceinline__ unsigned short f2bf(float f) {
    unsigned int x = __float_as_uint(f);
    unsigned int r = (x + 0x7fffu + ((x >> 16) & 1u)) >> 16;   // RNE
    return (unsigned short)r;
}

// async 16B/lane global->LDS DMA; LDS dest = wave-uniform base + lane*16
#define GLOAD16(gp, lp)                                                        \
    __builtin_amdgcn_global_load_lds(                                          \
        (const __attribute__((address_space(1))) void*)(gp),                   \
        (__attribute__((address_space(3))) void*)(lp), 16, 0, 0)

// ---------------------------------------------------------------------------
// Bias helper: jax.image.resize(bias128, (512,512), 'bilinear')
// ---------------------------------------------------------------------------
static __device__ __forceinline__ float bias128(int a, int b) {
    float d = fabsf((float)(a - b));
    return expf(-d * 0.1f) - d * 0.05f;
}

// ---------------------------------------------------------------------------
// prep_kernel: fused LN (blocks 0..8191) + bias table (8192..9215) +
// Wqkv fp32->bf16 convert (9216..12287)
// ---------------------------------------------------------------------------
__global__ void prep_kernel(const float* __restrict__ dec, const float* __restrict__ enc,
                            const float* __restrict__ gamma, const float* __restrict__ beta,
                            const float* __restrict__ Wqkv,
                            unsigned short* __restrict__ q_ln, unsigned short* __restrict__ kv_ln,
                            float* __restrict__ bias, unsigned short* __restrict__ Wqkv_bf) {
    int blk = blockIdx.x;
    int t = threadIdx.x;
    if (blk >= 9216) {          // Wqkv convert
        int idx = (blk - 9216) * 256 + t;
        float4 v = ((const float4*)Wqkv)[idx];
        ushort4 u;
        u.x = f2bf(v.x); u.y = f2bf(v.y); u.z = f2bf(v.z); u.w = f2bf(v.w);
        ((ushort4*)Wqkv_bf)[idx] = u;
        return;
    }
    if (blk >= 8192) {          // bias
        int idx = (blk - 8192) * 256 + t;
        int qi = idx >> 9, kj = idx & 511;
        float fq = (qi + 0.5f) * 0.25f - 0.5f;
        float fk = (kj + 0.5f) * 0.25f - 0.5f;
        int iq = (int)floorf(fq); float tq = fq - (float)iq;
        int ik = (int)floorf(fk); float tk = fk - (float)ik;
        int iq0 = min(max(iq, 0), 127), iq1 = min(max(iq + 1, 0), 127);
        int ik0 = min(max(ik, 0), 127), ik1 = min(max(ik + 1, 0), 127);
        float v = (1.f - tq) * ((1.f - tk) * bias128(iq0, ik0) + tk * bias128(iq0, ik1))
                +        tq  * ((1.f - tk) * bias128(iq1, ik0) + tk * bias128(iq1, ik1));
        bias[idx] = v;
        return;
    }
    int row = blk;
    const float* src = (row < NROWS) ? dec + (size_t)row * D_MODEL
                                     : enc + (size_t)(row - NROWS) * D_MODEL;
    unsigned short* dst = (row < NROWS) ? q_ln + (size_t)row * D_MODEL
                                        : kv_ln + (size_t)(row - NROWS) * D_MODEL;
    float4 x = ((const float4*)src)[t];
    float s  = x.x + x.y + x.z + x.w;
    float ss = x.x * x.x + x.y * x.y + x.z * x.z + x.w * x.w;
    #pragma unroll
    for (int off = 32; off > 0; off >>= 1) {
        s  += __shfl_down(s, off);
        ss += __shfl_down(ss, off);
    }
    __shared__ float red_s[4], red_ss[4];
    int wid = t >> 6, lane = t & 63;
    if (lane == 0) { red_s[wid] = s; red_ss[wid] = ss; }
    __syncthreads();
    if (t == 0) {
        float S = red_s[0] + red_s[1] + red_s[2] + red_s[3];
        float SS = red_ss[0] + red_ss[1] + red_ss[2] + red_ss[3];
        red_s[0] = S; red_ss[0] = SS;
    }
    __syncthreads();
    float mu  = red_s[0] * (1.0f / 1024.0f);
    float var = red_ss[0] * (1.0f / 1024.0f) - mu * mu;
    float rstd = rsqrtf(var + LN_EPS);
    float4 g = ((const float4*)gamma)[t];
    float4 bb = ((const float4*)beta)[t];
    ushort4 u;
    u.x = f2bf((x.x - mu) * rstd * g.x + bb.x);
    u.y = f2bf((x.y - mu) * rstd * g.y + bb.y);
    u.z = f2bf((x.z - mu) * rstd * g.z + bb.z);
    u.w = f2bf((x.w - mu) * rstd * g.w + bb.w);
    ((ushort4*)dst)[t] = u;
}

// ---------------------------------------------------------------------------
// Wout + Wgate fp32 -> bf16 (runs after attn; targets freed vb region)
// ---------------------------------------------------------------------------
__global__ void convert_og(const float* __restrict__ Wout, const float* __restrict__ Wgate,
                           unsigned short* __restrict__ Wout_bf, unsigned short* __restrict__ Wgate_bf) {
    int idx = blockIdx.x * 256 + threadIdx.x;
    const float* src; unsigned short* dst; int off;
    if (idx < 262144) { src = (const float*)Wout; dst = Wout_bf; off = idx; }
    else              { src = (const float*)Wgate; dst = Wgate_bf; off = idx - 262144; }
    float4 v = ((const float4*)src)[off];
    ushort4 u;
    u.x = f2bf(v.x); u.y = f2bf(v.y); u.z = f2bf(v.z); u.w = f2bf(v.w);
    ((ushort4*)dst)[off] = u;
}

// ===========================================================================
// Shared MFMA GEMM: C(128x128) = A(128xK) @ W^T(128xK), bf16.
// R7 lesson: accumulators must be NAMED scalars (arrays -> scratch:
//   VGPR~68 + GB WRITE_SIZE + MfmaUtil 3%).
// R8 lesson: register prefetch regresses; scheduling tweaks on the 2-barrier
//   K-loop are neutral-to-negative (guide m131-m141).
// R9 (verified): global_load_lds width=16 staging + XOR chunk swizzle ->
//   SQ_LDS_BANK_CONFLICT = 0, 71 us @ 363 TF — the m97-structure plateau
//   for K=1024. Leave as-is.
// ===========================================================================
#define CSTR 136   // C-bounce row stride (multiple of 8 -> 16B-aligned rows)

union alignas(16) GemmSmem {
    struct { unsigned short A[128 * 64]; unsigned short B[128 * 64]; } ab;  // 32 KB staging
    unsigned short C[128 * CSTR];                                           // 34816 B bounce
};

#define MF(a, b, d) __builtin_amdgcn_mfma_f32_16x16x32_bf16((a), (b), (d), 0, 0, 0)

#define GEMM_KH(kh)                                                            \
    {                                                                          \
        const unsigned short* Arow_ = &As[(wr * 64 + c) * 64 + pofs##kh];      \
        const unsigned short* Brow_ = &Bs[(wc * 64 + c) * 64 + pofs##kh];      \
        bf16x8 f0 = *(const bf16x8*)(Arow_);                                   \
        bf16x8 f1 = *(const bf16x8*)(Arow_ + 1024);                            \
        bf16x8 f2 = *(const bf16x8*)(Arow_ + 2048);                            \
        bf16x8 f3 = *(const bf16x8*)(Arow_ + 3072);                            \
        bf16x8 g0 = *(const bf16x8*)(Brow_);                                   \
        bf16x8 g1 = *(const bf16x8*)(Brow_ + 1024);                            \
        bf16x8 g2 = *(const bf16x8*)(Brow_ + 2048);                            \
        bf16x8 g3 = *(const bf16x8*)(Brow_ + 3072);                            \
        a00 = MF(f0, g0, a00); a01 = MF(f0, g1, a01); a02 = MF(f0, g2, a02); a03 = MF(f0, g3, a03); \
        a10 = MF(f1, g0, a10); a11 = MF(f1, g1, a11); a12 = MF(f1, g2, a12); a13 = MF(f1, g3, a13); \
        a20 = MF(f2, g0, a20); a21 = MF(f2, g1, a21); a22 = MF(f2, g2, a22); a23 = MF(f2, g3, a23); \
        a30 = MF(f3, g0, a30); a31 = MF(f3, g1, a31); a32 = MF(f3, g2, a32); a33 = MF(f3, g3, a33); \
    }

#define GEMM_MAIN_LOOP(Aptr, Bptr)                                             \
    __shared__ GemmSmem smem;                                                  \
    unsigned short* As = smem.ab.A;                                            \
    unsigned short* Bs = smem.ab.B;                                            \
    int tid = threadIdx.x;                                                     \
    int wave = tid >> 6, lane = tid & 63, quad = lane >> 4, c = lane & 15;     \
    int wr = wave >> 1, wc = wave & 1;                                         \
    int x7 = c & 7;                                                            \
    int pofs0 = (quad ^ x7) * 8;                                               \
    int pofs1 = ((4 + quad) ^ x7) * 8;                                         \
    int grow = lane >> 3;                                                      \
    int cg = ((lane & 7) ^ grow) * 8;                                          \
    const unsigned short* Ag = (Aptr) + (size_t)(rt * 128 + wave * 32 + grow) * 1024 + cg; \
    const unsigned short* Bg = (Bptr) + (size_t)(ct * 128 + wave * 32 + grow) * 1024 + cg; \
    unsigned short* AsW = As + wave * 2048;                                    \
    unsigned short* BsW = Bs + wave * 2048;                                    \
    f32x4 a00 = (f32x4)0.f, a01 = (f32x4)0.f, a02 = (f32x4)0.f, a03 = (f32x4)0.f; \
    f32x4 a10 = (f32x4)0.f, a11 = (f32x4)0.f, a12 = (f32x4)0.f, a13 = (f32x4)0.f; \
    f32x4 a20 = (f32x4)0.f, a21 = (f32x4)0.f, a22 = (f32x4)0.f, a23 = (f32x4)0.f; \
    f32x4 a30 = (f32x4)0.f, a31 = (f32x4)0.f, a32 = (f32x4)0.f, a33 = (f32x4)0.f; \
    for (int kt = 0; kt < 16; ++kt) {                                          \
        int k0 = kt * 64;                                                      \
        __syncthreads();                                                       \
        GLOAD16(Ag + k0,         AsW);                                         \
        GLOAD16(Ag + 8192 + k0,  AsW + 512);                                   \
        GLOAD16(Ag + 16384 + k0, AsW + 1024);                                  \
        GLOAD16(Ag + 24576 + k0, AsW + 1536);                                  \
        GLOAD16(Bg + k0,         BsW);                                         \
        GLOAD16(Bg + 8192 + k0,  BsW + 512);                                   \
        GLOAD16(Bg + 16384 + k0, BsW + 1024);                                  \
        GLOAD16(Bg + 24576 + k0, BsW + 1536);                                  \
        __syncthreads();                                                       \
        GEMM_KH(0)                                                             \
        GEMM_KH(1)                                                             \
    }

// ---------------------------------------------------------------------------
// QKV GEMM (MFMA) + fused RoPE, LDS-bounce epilogue with wide stores.
// 1-D grid of 768, swizzled into 8(ct)x4(rt) super-tiles for L2 locality.
// ---------------------------------------------------------------------------
#define ROPE_REG(i, reg, A0, A1, A2, A3)                                       \
    {                                                                          \
        int mloc = wr * 64 + (i) * 16 + quad * 4 + (reg);                      \
        int crow = mloc * CSTR + wc * 64;                                      \
        float fl = (float)((rt * 128 + mloc) & 511);                           \
        float aa0 = fl * inv0, aa1 = fl * inv1;                                \
        float c0 = cosf(aa0), s0 = sinf(aa0);                                  \
        float c1 = cosf(aa1), s1 = sinf(aa1);                                  \
        float e0 = A0[(reg)], o0 = A2[(reg)];                                  \
        float e1 = A1[(reg)], o1 = A3[(reg)];                                  \
        smem.C[crow + c]      = f2bf(e0 * c0 - o0 * s0);                       \
        smem.C[crow + 32 + c] = f2bf(e0 * s0 + o0 * c0);                       \
        smem.C[crow + 16 + c] = f2bf(e1 * c1 - o1 * s1);                       \
        smem.C[crow + 48 + c] = f2bf(e1 * s1 + o1 * c1);                       \
    }
#define ROPE_ROW(i, A0, A1, A2, A3)                                            \
    ROPE_REG(i, 0, A0, A1, A2, A3) ROPE_REG(i, 1, A0, A1, A2, A3)              \
    ROPE_REG(i, 2, A0, A1, A2, A3) ROPE_REG(i, 3, A0, A1, A2, A3)

#define VSEC_REG(i, reg, A0, A1, A2, A3)                                       \
    {                                                                          \
        int crow = (wr * 64 + (i) * 16 + quad * 4 + (reg)) * CSTR + wc * 64;   \
        smem.C[crow + c]      = f2bf(A0[(reg)]);                               \
        smem.C[crow + 16 + c] = f2bf(A1[(reg)]);                               \
        smem.C[crow + 32 + c] = f2bf(A2[(reg)]);                               \
        smem.C[crow + 48 + c] = f2bf(A3[(reg)]);                               \
    }
#define VSEC_ROW(i, A0, A1, A2, A3)                                            \
    VSEC_REG(i, 0, A0, A1, A2, A3) VSEC_REG(i, 1, A0, A1, A2, A3)              \
    VSEC_REG(i, 2, A0, A1, A2, A3) VSEC_REG(i, 3, A0, A1, A2, A3)

__global__ __launch_bounds__(256, 1)
void qkv_gemm_mfma(const unsigned short* __restrict__ q_ln,
                   const unsigned short* __restrict__ kv_ln,
                   const unsigned short* __restrict__ Wb,
                   unsigned short* __restrict__ qo,
                   unsigned short* __restrict__ ko,
                   unsigned short* __restrict__ vo) {
    int bid = blockIdx.x;               // 0..767
    int st = bid >> 5, in = bid & 31;   // 24 super-tiles of 32 blocks
    int stc = st % 3, str = st / 3;
    int ct = stc * 8 + (in & 7);        // 0..23
    int rt = str * 4 + (in >> 3);       // 0..31
    int n0 = ct * 128;
    int section = n0 >> 10;             // 0=q 1=k 2=v (uniform per block)
    const unsigned short* A = (section == 0) ? q_ln : kv_ln;

    GEMM_MAIN_LOOP(A, Wb)

    __syncthreads();                    // all waves done reading As/Bs
    if (section == 2) {
        VSEC_ROW(0, a00, a01, a02, a03)
        VSEC_ROW(1, a10, a11, a12, a13)
        VSEC_ROW(2, a20, a21, a22, a23)
        VSEC_ROW(3, a30, a31, a32, a33)
    } else {
        float inv0 = expf(-0.2878231366f * (float)c);          // 10000^(-c/32)
        float inv1 = expf(-0.2878231366f * (float)(16 + c));
        ROPE_ROW(0, a00, a01, a02, a03)
        ROPE_ROW(1, a10, a11, a12, a13)
        ROPE_ROW(2, a20, a21, a22, a23)
        ROPE_ROW(3, a30, a31, a32, a33)
    }
    __syncthreads();

    unsigned short* outp = (section == 0) ? qo : (section == 1) ? ko : vo;
    int rr = tid >> 1, ch = tid & 1;    // row 0..127, head-half 0/1
    int mm = rt * 128 + rr;
    int bb = mm >> 9, ll = mm & 511;
    int h = ((n0 & 1023) >> 6) + ch;
    unsigned short* orow = outp + (((size_t)bb * NHEADS + h) * SEQ + ll) * HDIM;
    const unsigned short* csrc = &smem.C[rr * CSTR + ch * 64];
    #pragma unroll
    for (int kc = 0; kc < 8; ++kc)
        *(u16x8*)(orow + kc * 8) = *(const u16x8*)(csrc + kc * 8);
}

// ---------------------------------------------------------------------------
// Projection 1 (MFMA): t = att @ Wout^T + b_out -> bf16 t_bf only
// (R10: fp32 t_proj dropped — the gate GEMM already consumed bf16 t, so the
//  mix epilogue uses bf16 t too; saves 16 MB write + 16 MB read)
// ---------------------------------------------------------------------------
#define OUT1_REG(mb, reg, n, Aij)                                              \
    {                                                                          \
        float v = Aij[(reg)] + bo;                                             \
        t_bf[(size_t)((mb) + (reg)) * 1024 + (n)] = f2bf(v);                   \
    }
#define OUT1_TILE(i, j, Aij)                                                   \
    {                                                                          \
        int n = ct * 128 + wc * 64 + (j) * 16 + c;                             \
        float bo = b_out[n];                                                   \
        int mb = rt * 128 + wr * 64 + (i) * 16 + quad * 4;                     \
        OUT1_REG(mb, 0, n, Aij) OUT1_REG(mb, 1, n, Aij)                        \
        OUT1_REG(mb, 2, n, Aij) OUT1_REG(mb, 3, n, Aij)                        \
    }

__global__ __launch_bounds__(256, 1)
void out_gemm1_mfma(const unsigned short* __restrict__ att,
                    const unsigned short* __restrict__ Wob,
                    const float* __restrict__ b_out,
                    unsigned short* __restrict__ t_bf) {
    int ct = blockIdx.x, rt = blockIdx.y;

    GEMM_MAIN_LOOP(att, Wob)

    OUT1_TILE(0, 0, a00) OUT1_TILE(0, 1, a01) OUT1_TILE(0, 2, a02) OUT1_TILE(0, 3, a03)
    OUT1_TILE(1, 0, a10) OUT1_TILE(1, 1, a11) OUT1_TILE(1, 2, a12) OUT1_TILE(1, 3, a13)
    OUT1_TILE(2, 0, a20) OUT1_TILE(2, 1, a21) OUT1_TILE(2, 2, a22) OUT1_TILE(2, 3, a23)
    OUT1_TILE(3, 0, a30) OUT1_TILE(3, 1, a31) OUT1_TILE(3, 2, a32) OUT1_TILE(3, 3, a33)
}

// ---------------------------------------------------------------------------
// Projection 2 (MFMA): gz = t_bf @ Wgate^T + b_gate;
// out = sigmoid(gz)*t + (1-sigmoid)*residual   (t read back as bf16)
// ---------------------------------------------------------------------------
#define OUT2_REG(mb, reg, n, Aij)                                              \
    {                                                                          \
        float gz = Aij[(reg)] + bg;                                            \
        float g = 1.0f / (1.0f + expf(-gz));                                   \
        size_t idx = (size_t)((mb) + (reg)) * 1024 + (n);                      \
        float tv = bf2f(t_bf[idx]);                                            \
        float rv = residual[idx];                                              \
        out[idx] = g * tv + (1.0f - g) * rv;                                   \
    }
#define OUT2_TILE(i, j, Aij)                                                   \
    {                                                                          \
        int n = ct * 128 + wc * 64 + (j) * 16 + c;                             \
        float bg = b_gate[n];                                                  \
        int mb = rt * 128 + wr * 64 + (i) * 16 + quad * 4;                     \
        OUT2_REG(mb, 0, n, Aij) OUT2_REG(mb, 1, n, Aij)                        \
        OUT2_REG(mb, 2, n, Aij) OUT2_REG(mb, 3, n, Aij)                        \
    }

__global__ __launch_bounds__(256, 1)
void out_gemm2_mfma(const unsigned short* __restrict__ t_bf,
                    const unsigned short* __restrict__ Wgb,
                    const float* __restrict__ b_gate,
                    const float* __restrict__ residual,
                    float* __restrict__ out) {
    int ct = blockIdx.x, rt = blockIdx.y;

    GEMM_MAIN_LOOP(t_bf, Wgb)

    OUT2_TILE(0, 0, a00) OUT2_TILE(0, 1, a01) OUT2_TILE(0, 2, a02) OUT2_TILE(0, 3, a03)
    OUT2_TILE(1, 0, a10) OUT2_TILE(1, 1, a11) OUT2_TILE(1, 2, a12) OUT2_TILE(1, 3, a13)
    OUT2_TILE(2, 0, a20) OUT2_TILE(2, 1, a21) OUT2_TILE(2, 2, a22) OUT2_TILE(2, 3, a23)
    OUT2_TILE(3, 0, a30) OUT2_TILE(3, 1, a31) OUT2_TILE(3, 2, a32) OUT2_TILE(3, 3, a33)
}

// ---------------------------------------------------------------------------
// Flash attention, bf16 MFMA (16x16x32).
// R10: Q-tile 128 rows / 8 waves (512 thr) — same wave-local compute as the
// verified 64-row version; halves KV-staging work + barriers per FLOP and
// reaches 32 waves/CU (4 blocks x 8 waves, 37.9 KB LDS).
// ---------------------------------------------------------------------------
#define KSTR 72

__global__ __launch_bounds__(512)
void attn_kernel(const unsigned short* __restrict__ q,
                 const unsigned short* __restrict__ k,
                 const unsigned short* __restrict__ v,
                 const float* __restrict__ bias,
                 unsigned short* __restrict__ attended) {
    int qt = blockIdx.x, h = blockIdx.y, b = blockIdx.z;
    __shared__ unsigned short Ks[64 * KSTR];
    __shared__ unsigned short Vt[64 * KSTR];
    __shared__ unsigned short Ps[128 * KSTR];
    __shared__ float af[128];
    __shared__ float lf[128];

    int tid = threadIdx.x;
    int wave = tid >> 6, lane = tid & 63;   // wave 0..7
    int quad = lane >> 4, c = lane & 15;
    int wb = wave * 16;                     // wave's q-row base, 0..112
    size_t headbase = (((size_t)b * NHEADS + h) * SEQ) * HDIM;
    int q0 = qt * 128;

    const unsigned short* qrow = q + headbase + (size_t)(q0 + wb + c) * HDIM;
    bf16x8 aq0 = *(const bf16x8*)(qrow + quad * 8);
    bf16x8 aq1 = *(const bf16x8*)(qrow + 32 + quad * 8);

    int sr = tid >> 3, sc0 = (tid & 7) * 8;   // staging: 64 rows x 8 shorts/thread

    f32x4 oacc[4];
    #pragma unroll
    for (int t = 0; t < 4; ++t) oacc[t] = (f32x4)0.f;
    float mrow[4], lrow[4];
    #pragma unroll
    for (int r = 0; r < 4; ++r) { mrow[r] = -1e30f; lrow[r] = 0.f; }

    for (int kt = 0; kt < 8; ++kt) {
        int kv0 = kt * 64;
        __syncthreads();
        {
            const unsigned short* krow = k + headbase + (size_t)(kv0 + sr) * HDIM + sc0;
            const unsigned short* vrow = v + headbase + (size_t)(kv0 + sr) * HDIM + sc0;
            u16x8 ka = *(const u16x8*)(krow);
            u16x8 va = *(const u16x8*)(vrow);
            *(u16x8*)&Ks[sr * KSTR + sc0] = ka;
            #pragma unroll
            for (int j = 0; j < 8; ++j) Vt[(sc0 + j) * KSTR + sr] = va[j];
        }
        __syncthreads();

        f32x4 sacc[4];
        #pragma unroll
        for (int nt = 0; nt < 4; ++nt) {
            const unsigned short* kbase = &Ks[(nt * 16 + c) * KSTR];
            bf16x8 b0 = *(const bf16x8*)(kbase + quad * 8);
            bf16x8 b1 = *(const bf16x8*)(kbase + 32 + quad * 8);
            f32x4 a = (f32x4)0.f;
            a = __builtin_amdgcn_mfma_f32_16x16x32_bf16(aq0, b0, a, 0, 0, 0);
            a = __builtin_amdgcn_mfma_f32_16x16x32_bf16(aq1, b1, a, 0, 0, 0);
            sacc[nt] = a;
        }

        const float* bbase = bias + (size_t)(q0 + wb + quad * 4) * 512 + kv0 + c;
        float tmax[4];
        #pragma unroll
        for (int r = 0; r < 4; ++r) tmax[r] = -1e30f;
        #pragma unroll
        for (int nt = 0; nt < 4; ++nt)
            #pragma unroll
            for (int r = 0; r < 4; ++r) {
                float s = sacc[nt][r] * SCALE + bbase[(size_t)r * 512 + nt * 16];
                sacc[nt][r] = s;
                tmax[r] = fmaxf(tmax[r], s);
            }
        #pragma unroll
        for (int r = 0; r < 4; ++r) {
            float t = tmax[r];
            t = fmaxf(t, __shfl_xor(t, 1));
            t = fmaxf(t, __shfl_xor(t, 2));
            t = fmaxf(t, __shfl_xor(t, 4));
            t = fmaxf(t, __shfl_xor(t, 8));
            tmax[r] = t;
        }
        float alpha[4];
        #pragma unroll
        for (int r = 0; r < 4; ++r) {
            float mnew = fmaxf(mrow[r], tmax[r]);
            alpha[r] = __expf(mrow[r] - mnew);
            mrow[r] = mnew;
        }
        float tsum[4];
        #pragma unroll
        for (int r = 0; r < 4; ++r) tsum[r] = 0.f;
        #pragma unroll
        for (int nt = 0; nt < 4; ++nt)
            #pragma unroll
            for (int r = 0; r < 4; ++r) {
                float p = __expf(sacc[nt][r] - mrow[r]);
                tsum[r] += p;
                Ps[(wb + quad * 4 + r) * KSTR + nt * 16 + c] = f2bf(p);
            }
        #pragma unroll
        for (int r = 0; r < 4; ++r) {
            float t = tsum[r];
            t += __shfl_xor(t, 1);
            t += __shfl_xor(t, 2);
            t += __shfl_xor(t, 4);
            t += __shfl_xor(t, 8);
            lrow[r] = lrow[r] * alpha[r] + t;
        }
        if (c == 0) {
            f32x4 av;
            av[0] = alpha[0]; av[1] = alpha[1]; av[2] = alpha[2]; av[3] = alpha[3];
            *(f32x4*)&af[wb + quad * 4] = av;
        }
        float myalpha = af[wb + c];
        #pragma unroll
        for (int t = 0; t < 4; ++t) oacc[t] *= myalpha;

        bf16x8 pb0 = *(const bf16x8*)&Ps[(wb + c) * KSTR + quad * 8];
        bf16x8 pb1 = *(const bf16x8*)&Ps[(wb + c) * KSTR + 32 + quad * 8];
        #pragma unroll
        for (int t = 0; t < 4; ++t) {
            const unsigned short* vbase = &Vt[(t * 16 + c) * KSTR];
            bf16x8 a0 = *(const bf16x8*)(vbase + quad * 8);
            bf16x8 a1 = *(const bf16x8*)(vbase + 32 + quad * 8);
            oacc[t] = __builtin_amdgcn_mfma_f32_16x16x32_bf16(a0, pb0, oacc[t], 0, 0, 0);
            oacc[t] = __builtin_amdgcn_mfma_f32_16x16x32_bf16(a1, pb1, oacc[t], 0, 0, 0);
        }
    }

    if (c == 0) {
        f32x4 lv;
        lv[0] = lrow[0]; lv[1] = lrow[1]; lv[2] = lrow[2]; lv[3] = lrow[3];
        *(f32x4*)&lf[wb + quad * 4] = lv;
    }
    float invl = 1.0f / lf[wb + c];
    unsigned short* drow = attended + ((size_t)b * SEQ + (q0 + wb + c)) * D_MODEL + h * HDIM;
    #pragma unroll
    for (int t = 0; t < 4; ++t) {
        ushort4 o;
        o.x = f2bf(oacc[t][0] * invl);
        o.y = f2bf(oacc[t][1] * invl);
        o.z = f2bf(oacc[t][2] * invl);
        o.w = f2bf(oacc[t][3] * invl);
        *(ushort4*)(drow + t * 16 + quad * 4) = o;
    }
}

extern "C" void kernel_launch(void* const* d_in, const int* in_sizes, int n_in,
                              void* d_out, int out_size, void* d_ws, size_t ws_size,
                              hipStream_t stream) {
    const float* dec    = (const float*)d_in[0];
    const float* enc    = (const float*)d_in[1];
    const float* Wqkv   = (const float*)d_in[2];
    const float* Wout   = (const float*)d_in[3];
    const float* b_out  = (const float*)d_in[4];
    const float* Wgate  = (const float*)d_in[5];
    const float* b_gate = (const float*)d_in[6];
    const float* gamma  = (const float*)d_in[7];
    const float* beta   = (const float*)d_in[8];
    float* out = (float*)d_out;

    char* ws = (char*)d_ws;
    const size_t MB = 1024 * 1024;
    unsigned short* q_ln    = (unsigned short*)(ws + 0 * MB);
    unsigned short* kv_ln   = (unsigned short*)(ws + 8 * MB);
    unsigned short* qb      = (unsigned short*)(ws + 16 * MB);
    unsigned short* kb      = (unsigned short*)(ws + 24 * MB);
    unsigned short* vb      = (unsigned short*)(ws + 32 * MB);
    unsigned short* Wqkv_bf = (unsigned short*)(ws + 40 * MB);
    float*          bias    = (float*)(ws + 46 * MB);
    unsigned short* att     = (unsigned short*)(ws + 0 * MB);    // q_ln dead after qkv
    unsigned short* t_bf    = (unsigned short*)(ws + 24 * MB);   // kb dead after attn
    unsigned short* Wout_bf = (unsigned short*)(ws + 32 * MB);   // vb dead after attn
    unsigned short* Wgate_bf= (unsigned short*)(ws + 34 * MB);

    prep_kernel<<<12288, 256, 0, stream>>>(dec, enc, gamma, beta, Wqkv,
                                           q_ln, kv_ln, bias, Wqkv_bf);
    qkv_gemm_mfma<<<768, 256, 0, stream>>>(q_ln, kv_ln, Wqkv_bf, qb, kb, vb);
    attn_kernel<<<dim3(4, 16, 8), 512, 0, stream>>>(qb, kb, vb, bias, att);
    convert_og<<<2048, 256, 0, stream>>>(Wout, Wgate, Wout_bf, Wgate_bf);
    out_gemm1_mfma<<<dim3(8, 32), 256, 0, stream>>>(att, Wout_bf, b_out, t_bf);
    out_gemm2_mfma<<<dim3(8, 32), 256, 0, stream>>>(t_bf, Wgate_bf, b_gate, dec, out);
}

// Round 11
// 250.412 us; speedup vs baseline: 1.1558x; 1.0709x over previous
//
#include <hip/hip_runtime.h>
#include <hip/hip_bf16.h>

#define D_MODEL 1024
#define NHEADS 16
#define HDIM 64
#define BATCH 8
#define SEQ 512
#define NROWS 4096          // BATCH*SEQ
#define SCALE 0.125f
#define LN_EPS 1e-5f

typedef __attribute__((ext_vector_type(8))) short bf16x8;      // 8 bf16 (4 VGPRs)
typedef __attribute__((ext_vector_type(4))) float f32x4;
typedef __attribute__((ext_vector_type(8))) unsigned short u16x8;

static __device__ __forceinline__ float bf2f(unsigned short u) {
    return __uint_as_float(((unsigned int)u) << 16);
}
static __device__ __forceinline__ unsigned short f2bf(float f) {
    unsigned int x = __float_as_uint(f);
    unsigned int r = (x + 0x7fffu + ((x >> 16) & 1u)) >> 16;   // RNE
    return (unsigned short)r;
}

// async 16B/lane global->LDS DMA; LDS dest = wave-uniform base + lane*16
#define GLOAD16(gp, lp)                                                        \
    __builtin_amdgcn_global_load_lds(                                          \
        (const __attribute__((address_space(1))) void*)(gp),                   \
        (__attribute__((address_space(3))) void*)(lp), 16, 0, 0)

// ---------------------------------------------------------------------------
// Bias helper: jax.image.resize(bias128, (512,512), 'bilinear')
// ---------------------------------------------------------------------------
static __device__ __forceinline__ float bias128(int a, int b) {
    float d = fabsf((float)(a - b));
    return expf(-d * 0.1f) - d * 0.05f;
}

// ---------------------------------------------------------------------------
// prep_kernel: fused LN (blocks 0..8191) + bias table (8192..9215) +
// Wqkv fp32->bf16 convert (9216..12287)
// ---------------------------------------------------------------------------
__global__ void prep_kernel(const float* __restrict__ dec, const float* __restrict__ enc,
                            const float* __restrict__ gamma, const float* __restrict__ beta,
                            const float* __restrict__ Wqkv,
                            unsigned short* __restrict__ q_ln, unsigned short* __restrict__ kv_ln,
                            float* __restrict__ bias, unsigned short* __restrict__ Wqkv_bf) {
    int blk = blockIdx.x;
    int t = threadIdx.x;
    if (blk >= 9216) {          // Wqkv convert
        int idx = (blk - 9216) * 256 + t;
        float4 v = ((const float4*)Wqkv)[idx];
        ushort4 u;
        u.x = f2bf(v.x); u.y = f2bf(v.y); u.z = f2bf(v.z); u.w = f2bf(v.w);
        ((ushort4*)Wqkv_bf)[idx] = u;
        return;
    }
    if (blk >= 8192) {          // bias
        int idx = (blk - 8192) * 256 + t;
        int qi = idx >> 9, kj = idx & 511;
        float fq = (qi + 0.5f) * 0.25f - 0.5f;
        float fk = (kj + 0.5f) * 0.25f - 0.5f;
        int iq = (int)floorf(fq); float tq = fq - (float)iq;
        int ik = (int)floorf(fk); float tk = fk - (float)ik;
        int iq0 = min(max(iq, 0), 127), iq1 = min(max(iq + 1, 0), 127);
        int ik0 = min(max(ik, 0), 127), ik1 = min(max(ik + 1, 0), 127);
        float v = (1.f - tq) * ((1.f - tk) * bias128(iq0, ik0) + tk * bias128(iq0, ik1))
                +        tq  * ((1.f - tk) * bias128(iq1, ik0) + tk * bias128(iq1, ik1));
        bias[idx] = v;
        return;
    }
    int row = blk;
    const float* src = (row < NROWS) ? dec + (size_t)row * D_MODEL
                                     : enc + (size_t)(row - NROWS) * D_MODEL;
    unsigned short* dst = (row < NROWS) ? q_ln + (size_t)row * D_MODEL
                                        : kv_ln + (size_t)(row - NROWS) * D_MODEL;
    float4 x = ((const float4*)src)[t];
    float s  = x.x + x.y + x.z + x.w;
    float ss = x.x * x.x + x.y * x.y + x.z * x.z + x.w * x.w;
    #pragma unroll
    for (int off = 32; off > 0; off >>= 1) {
        s  += __shfl_down(s, off);
        ss += __shfl_down(ss, off);
    }
    __shared__ float red_s[4], red_ss[4];
    int wid = t >> 6, lane = t & 63;
    if (lane == 0) { red_s[wid] = s; red_ss[wid] = ss; }
    __syncthreads();
    if (t == 0) {
        float S = red_s[0] + red_s[1] + red_s[2] + red_s[3];
        float SS = red_ss[0] + red_ss[1] + red_ss[2] + red_ss[3];
        red_s[0] = S; red_ss[0] = SS;
    }
    __syncthreads();
    float mu  = red_s[0] * (1.0f / 1024.0f);
    float var = red_ss[0] * (1.0f / 1024.0f) - mu * mu;
    float rstd = rsqrtf(var + LN_EPS);
    float4 g = ((const float4*)gamma)[t];
    float4 bb = ((const float4*)beta)[t];
    ushort4 u;
    u.x = f2bf((x.x - mu) * rstd * g.x + bb.x);
    u.y = f2bf((x.y - mu) * rstd * g.y + bb.y);
    u.z = f2bf((x.z - mu) * rstd * g.z + bb.z);
    u.w = f2bf((x.w - mu) * rstd * g.w + bb.w);
    ((ushort4*)dst)[t] = u;
}

// ---------------------------------------------------------------------------
// Wout + Wgate fp32 -> bf16 (runs after attn; targets freed vb region)
// ---------------------------------------------------------------------------
__global__ void convert_og(const float* __restrict__ Wout, const float* __restrict__ Wgate,
                           unsigned short* __restrict__ Wout_bf, unsigned short* __restrict__ Wgate_bf) {
    int idx = blockIdx.x * 256 + threadIdx.x;
    const float* src; unsigned short* dst; int off;
    if (idx < 262144) { src = (const float*)Wout; dst = Wout_bf; off = idx; }
    else              { src = (const float*)Wgate; dst = Wgate_bf; off = idx - 262144; }
    float4 v = ((const float4*)src)[off];
    ushort4 u;
    u.x = f2bf(v.x); u.y = f2bf(v.y); u.z = f2bf(v.z); u.w = f2bf(v.w);
    ((ushort4*)dst)[off] = u;
}

// ===========================================================================
// MFMA GEMM cores (bf16). Permanent lessons:
// R7: accumulators must be NAMED scalars (arrays -> scratch: VGPR~68 +
//     GB-scale WRITE_SIZE + MfmaUtil ~3%).
// R8: register prefetch / scheduling tweaks on the 2-barrier K-loop regress.
// R9: global_load_lds width=16 + XOR chunk swizzle -> 0 bank conflicts,
//     363 TF on qkv — the m97-structure plateau at K=1024.
// R11: out-GEMMs were grid-limited to 1 block/CU (256 blocks); split to
//     64x128 tiles -> 512 blocks = 2 blocks/CU, 8 waves/CU.
// ===========================================================================
#define CSTR 136   // C-bounce row stride (multiple of 8 -> 16B-aligned rows)

union alignas(16) GemmSmem {
    struct { unsigned short A[128 * 64]; unsigned short B[128 * 64]; } ab;  // 32 KB staging
    unsigned short C[128 * CSTR];                                           // 34816 B bounce
};

struct alignas(16) Smem64 {
    unsigned short A[64 * 64];      // 8 KB
    unsigned short B[128 * 64];     // 16 KB
};

#define MF(a, b, d) __builtin_amdgcn_mfma_f32_16x16x32_bf16((a), (b), (d), 0, 0, 0)

#define GEMM_KH(kh)                                                            \
    {                                                                          \
        const unsigned short* Arow_ = &As[(wr * 64 + c) * 64 + pofs##kh];      \
        const unsigned short* Brow_ = &Bs[(wc * 64 + c) * 64 + pofs##kh];      \
        bf16x8 f0 = *(const bf16x8*)(Arow_);                                   \
        bf16x8 f1 = *(const bf16x8*)(Arow_ + 1024);                            \
        bf16x8 f2 = *(const bf16x8*)(Arow_ + 2048);                            \
        bf16x8 f3 = *(const bf16x8*)(Arow_ + 3072);                            \
        bf16x8 g0 = *(const bf16x8*)(Brow_);                                   \
        bf16x8 g1 = *(const bf16x8*)(Brow_ + 1024);                            \
        bf16x8 g2 = *(const bf16x8*)(Brow_ + 2048);                            \
        bf16x8 g3 = *(const bf16x8*)(Brow_ + 3072);                            \
        a00 = MF(f0, g0, a00); a01 = MF(f0, g1, a01); a02 = MF(f0, g2, a02); a03 = MF(f0, g3, a03); \
        a10 = MF(f1, g0, a10); a11 = MF(f1, g1, a11); a12 = MF(f1, g2, a12); a13 = MF(f1, g3, a13); \
        a20 = MF(f2, g0, a20); a21 = MF(f2, g1, a21); a22 = MF(f2, g2, a22); a23 = MF(f2, g3, a23); \
        a30 = MF(f3, g0, a30); a31 = MF(f3, g1, a31); a32 = MF(f3, g2, a32); a33 = MF(f3, g3, a33); \
    }

#define GEMM_MAIN_LOOP(Aptr, Bptr)                                             \
    __shared__ GemmSmem smem;                                                  \
    unsigned short* As = smem.ab.A;                                            \
    unsigned short* Bs = smem.ab.B;                                            \
    int tid = threadIdx.x;                                                     \
    int wave = tid >> 6, lane = tid & 63, quad = lane >> 4, c = lane & 15;     \
    int wr = wave >> 1, wc = wave & 1;                                         \
    int x7 = c & 7;                                                            \
    int pofs0 = (quad ^ x7) * 8;                                               \
    int pofs1 = ((4 + quad) ^ x7) * 8;                                         \
    int grow = lane >> 3;                                                      \
    int cg = ((lane & 7) ^ grow) * 8;                                          \
    const unsigned short* Ag = (Aptr) + (size_t)(rt * 128 + wave * 32 + grow) * 1024 + cg; \
    const unsigned short* Bg = (Bptr) + (size_t)(ct * 128 + wave * 32 + grow) * 1024 + cg; \
    unsigned short* AsW = As + wave * 2048;                                    \
    unsigned short* BsW = Bs + wave * 2048;                                    \
    f32x4 a00 = (f32x4)0.f, a01 = (f32x4)0.f, a02 = (f32x4)0.f, a03 = (f32x4)0.f; \
    f32x4 a10 = (f32x4)0.f, a11 = (f32x4)0.f, a12 = (f32x4)0.f, a13 = (f32x4)0.f; \
    f32x4 a20 = (f32x4)0.f, a21 = (f32x4)0.f, a22 = (f32x4)0.f, a23 = (f32x4)0.f; \
    f32x4 a30 = (f32x4)0.f, a31 = (f32x4)0.f, a32 = (f32x4)0.f, a33 = (f32x4)0.f; \
    for (int kt = 0; kt < 16; ++kt) {                                          \
        int k0 = kt * 64;                                                      \
        __syncthreads();                                                       \
        GLOAD16(Ag + k0,         AsW);                                         \
        GLOAD16(Ag + 8192 + k0,  AsW + 512);                                   \
        GLOAD16(Ag + 16384 + k0, AsW + 1024);                                  \
        GLOAD16(Ag + 24576 + k0, AsW + 1536);                                  \
        GLOAD16(Bg + k0,         BsW);                                         \
        GLOAD16(Bg + 8192 + k0,  BsW + 512);                                   \
        GLOAD16(Bg + 16384 + k0, BsW + 1024);                                  \
        GLOAD16(Bg + 24576 + k0, BsW + 1536);                                  \
        __syncthreads();                                                       \
        GEMM_KH(0)                                                             \
        GEMM_KH(1)                                                             \
    }

// ---- 64x128 variant: wave tile 32x64 (2x4 MFMA tiles, 8 named accs) ----
#define GEMM_KH2(kh)                                                           \
    {                                                                          \
        const unsigned short* Arow_ = &As2[(wr * 32 + c) * 64 + pofs##kh];     \
        const unsigned short* Brow_ = &Bs2[(wc * 64 + c) * 64 + pofs##kh];     \
        bf16x8 f0 = *(const bf16x8*)(Arow_);                                   \
        bf16x8 f1 = *(const bf16x8*)(Arow_ + 1024);                            \
        bf16x8 g0 = *(const bf16x8*)(Brow_);                                   \
        bf16x8 g1 = *(const bf16x8*)(Brow_ + 1024);                            \
        bf16x8 g2 = *(const bf16x8*)(Brow_ + 2048);                            \
        bf16x8 g3 = *(const bf16x8*)(Brow_ + 3072);                            \
        c00 = MF(f0, g0, c00); c01 = MF(f0, g1, c01); c02 = MF(f0, g2, c02); c03 = MF(f0, g3, c03); \
        c10 = MF(f1, g0, c10); c11 = MF(f1, g1, c11); c12 = MF(f1, g2, c12); c13 = MF(f1, g3, c13); \
    }

#define GEMM_LOOP_64(Aptr, Bptr)                                               \
    __shared__ Smem64 smem2;                                                   \
    unsigned short* As2 = smem2.A;                                             \
    unsigned short* Bs2 = smem2.B;                                             \
    int tid = threadIdx.x;                                                     \
    int wave = tid >> 6, lane = tid & 63, quad = lane >> 4, c = lane & 15;     \
    int wr = wave >> 1, wc = wave & 1;                                         \
    int x7 = c & 7;                                                            \
    int pofs0 = (quad ^ x7) * 8;                                               \
    int pofs1 = ((4 + quad) ^ x7) * 8;                                         \
    int grow = lane >> 3;                                                      \
    int cg = ((lane & 7) ^ grow) * 8;                                          \
    const unsigned short* Ag = (Aptr) + (size_t)(rt * 64 + wave * 16 + grow) * 1024 + cg;  \
    const unsigned short* Bg = (Bptr) + (size_t)(ct * 128 + wave * 32 + grow) * 1024 + cg; \
    unsigned short* AsW = As2 + wave * 1024;                                   \
    unsigned short* BsW = Bs2 + wave * 2048;                                   \
    f32x4 c00 = (f32x4)0.f, c01 = (f32x4)0.f, c02 = (f32x4)0.f, c03 = (f32x4)0.f; \
    f32x4 c10 = (f32x4)0.f, c11 = (f32x4)0.f, c12 = (f32x4)0.f, c13 = (f32x4)0.f; \
    for (int kt = 0; kt < 16; ++kt) {                                          \
        int k0 = kt * 64;                                                      \
        __syncthreads();                                                       \
        GLOAD16(Ag + k0,         AsW);                                         \
        GLOAD16(Ag + 8192 + k0,  AsW + 512);                                   \
        GLOAD16(Bg + k0,         BsW);                                         \
        GLOAD16(Bg + 8192 + k0,  BsW + 512);                                   \
        GLOAD16(Bg + 16384 + k0, BsW + 1024);                                  \
        GLOAD16(Bg + 24576 + k0, BsW + 1536);                                  \
        __syncthreads();                                                       \
        GEMM_KH2(0)                                                            \
        GEMM_KH2(1)                                                            \
    }

// ---------------------------------------------------------------------------
// QKV GEMM (MFMA) + fused RoPE, LDS-bounce epilogue with wide stores.
// 1-D grid of 768, swizzled into 8(ct)x4(rt) super-tiles for L2 locality.
// ---------------------------------------------------------------------------
#define ROPE_REG(i, reg, A0, A1, A2, A3)                                       \
    {                                                                          \
        int mloc = wr * 64 + (i) * 16 + quad * 4 + (reg);                      \
        int crow = mloc * CSTR + wc * 64;                                      \
        float fl = (float)((rt * 128 + mloc) & 511);                           \
        float aa0 = fl * inv0, aa1 = fl * inv1;                                \
        float c0 = cosf(aa0), s0 = sinf(aa0);                                  \
        float c1 = cosf(aa1), s1 = sinf(aa1);                                  \
        float e0 = A0[(reg)], o0 = A2[(reg)];                                  \
        float e1 = A1[(reg)], o1 = A3[(reg)];                                  \
        smem.C[crow + c]      = f2bf(e0 * c0 - o0 * s0);                       \
        smem.C[crow + 32 + c] = f2bf(e0 * s0 + o0 * c0);                       \
        smem.C[crow + 16 + c] = f2bf(e1 * c1 - o1 * s1);                       \
        smem.C[crow + 48 + c] = f2bf(e1 * s1 + o1 * c1);                       \
    }
#define ROPE_ROW(i, A0, A1, A2, A3)                                            \
    ROPE_REG(i, 0, A0, A1, A2, A3) ROPE_REG(i, 1, A0, A1, A2, A3)              \
    ROPE_REG(i, 2, A0, A1, A2, A3) ROPE_REG(i, 3, A0, A1, A2, A3)

#define VSEC_REG(i, reg, A0, A1, A2, A3)                                       \
    {                                                                          \
        int crow = (wr * 64 + (i) * 16 + quad * 4 + (reg)) * CSTR + wc * 64;   \
        smem.C[crow + c]      = f2bf(A0[(reg)]);                               \
        smem.C[crow + 16 + c] = f2bf(A1[(reg)]);                               \
        smem.C[crow + 32 + c] = f2bf(A2[(reg)]);                               \
        smem.C[crow + 48 + c] = f2bf(A3[(reg)]);                               \
    }
#define VSEC_ROW(i, A0, A1, A2, A3)                                            \
    VSEC_REG(i, 0, A0, A1, A2, A3) VSEC_REG(i, 1, A0, A1, A2, A3)              \
    VSEC_REG(i, 2, A0, A1, A2, A3) VSEC_REG(i, 3, A0, A1, A2, A3)

__global__ __launch_bounds__(256, 1)
void qkv_gemm_mfma(const unsigned short* __restrict__ q_ln,
                   const unsigned short* __restrict__ kv_ln,
                   const unsigned short* __restrict__ Wb,
                   unsigned short* __restrict__ qo,
                   unsigned short* __restrict__ ko,
                   unsigned short* __restrict__ vo) {
    int bid = blockIdx.x;               // 0..767
    int st = bid >> 5, in = bid & 31;   // 24 super-tiles of 32 blocks
    int stc = st % 3, str = st / 3;
    int ct = stc * 8 + (in & 7);        // 0..23
    int rt = str * 4 + (in >> 3);       // 0..31
    int n0 = ct * 128;
    int section = n0 >> 10;             // 0=q 1=k 2=v (uniform per block)
    const unsigned short* A = (section == 0) ? q_ln : kv_ln;

    GEMM_MAIN_LOOP(A, Wb)

    __syncthreads();                    // all waves done reading As/Bs
    if (section == 2) {
        VSEC_ROW(0, a00, a01, a02, a03)
        VSEC_ROW(1, a10, a11, a12, a13)
        VSEC_ROW(2, a20, a21, a22, a23)
        VSEC_ROW(3, a30, a31, a32, a33)
    } else {
        float inv0 = expf(-0.2878231366f * (float)c);          // 10000^(-c/32)
        float inv1 = expf(-0.2878231366f * (float)(16 + c));
        ROPE_ROW(0, a00, a01, a02, a03)
        ROPE_ROW(1, a10, a11, a12, a13)
        ROPE_ROW(2, a20, a21, a22, a23)
        ROPE_ROW(3, a30, a31, a32, a33)
    }
    __syncthreads();

    unsigned short* outp = (section == 0) ? qo : (section == 1) ? ko : vo;
    int rr = tid >> 1, ch = tid & 1;    // row 0..127, head-half 0/1
    int mm = rt * 128 + rr;
    int bb = mm >> 9, ll = mm & 511;
    int h = ((n0 & 1023) >> 6) + ch;
    unsigned short* orow = outp + (((size_t)bb * NHEADS + h) * SEQ + ll) * HDIM;
    const unsigned short* csrc = &smem.C[rr * CSTR + ch * 64];
    #pragma unroll
    for (int kc = 0; kc < 8; ++kc)
        *(u16x8*)(orow + kc * 8) = *(const u16x8*)(csrc + kc * 8);
}

// ---------------------------------------------------------------------------
// Projection 1 (MFMA, 64x128 tile): t = att @ Wout^T + b_out -> bf16 t_bf
// grid (8, 64) = 512 blocks
// ---------------------------------------------------------------------------
#define O1_REG(mb, reg, n, Acc)                                                \
    t_bf[(size_t)((mb) + (reg)) * 1024 + (n)] = f2bf(Acc[(reg)] + bo);
#define O1_TILE(i, j, Acc)                                                     \
    {                                                                          \
        int n = ct * 128 + wc * 64 + (j) * 16 + c;                             \
        float bo = b_out[n];                                                   \
        int mb = rt * 64 + wr * 32 + (i) * 16 + quad * 4;                      \
        O1_REG(mb, 0, n, Acc) O1_REG(mb, 1, n, Acc)                            \
        O1_REG(mb, 2, n, Acc) O1_REG(mb, 3, n, Acc)                            \
    }

__global__ __launch_bounds__(256, 1)
void out_gemm1_mfma(const unsigned short* __restrict__ att,
                    const unsigned short* __restrict__ Wob,
                    const float* __restrict__ b_out,
                    unsigned short* __restrict__ t_bf) {
    int ct = blockIdx.x, rt = blockIdx.y;

    GEMM_LOOP_64(att, Wob)

    O1_TILE(0, 0, c00) O1_TILE(0, 1, c01) O1_TILE(0, 2, c02) O1_TILE(0, 3, c03)
    O1_TILE(1, 0, c10) O1_TILE(1, 1, c11) O1_TILE(1, 2, c12) O1_TILE(1, 3, c13)
}

// ---------------------------------------------------------------------------
// Projection 2 (MFMA, 64x128 tile): gz = t_bf @ Wgate^T + b_gate;
// out = sigmoid(gz)*t + (1-sigmoid)*residual   (t read back as bf16)
// grid (8, 64) = 512 blocks
// ---------------------------------------------------------------------------
#define O2_REG(mb, reg, n, Acc)                                                \
    {                                                                          \
        float gz = Acc[(reg)] + bg;                                            \
        float g = 1.0f / (1.0f + expf(-gz));                                   \
        size_t idx = (size_t)((mb) + (reg)) * 1024 + (n);                      \
        float tv = bf2f(t_bf[idx]);                                            \
        float rv = residual[idx];                                              \
        out[idx] = g * tv + (1.0f - g) * rv;                                   \
    }
#define O2_TILE(i, j, Acc)                                                     \
    {                                                                          \
        int n = ct * 128 + wc * 64 + (j) * 16 + c;                             \
        float bg = b_gate[n];                                                  \
        int mb = rt * 64 + wr * 32 + (i) * 16 + quad * 4;                      \
        O2_REG(mb, 0, n, Acc) O2_REG(mb, 1, n, Acc)                            \
        O2_REG(mb, 2, n, Acc) O2_REG(mb, 3, n, Acc)                            \
    }

__global__ __launch_bounds__(256, 1)
void out_gemm2_mfma(const unsigned short* __restrict__ t_bf,
                    const unsigned short* __restrict__ Wgb,
                    const float* __restrict__ b_gate,
                    const float* __restrict__ residual,
                    float* __restrict__ out) {
    int ct = blockIdx.x, rt = blockIdx.y;

    GEMM_LOOP_64(t_bf, Wgb)

    O2_TILE(0, 0, c00) O2_TILE(0, 1, c01) O2_TILE(0, 2, c02) O2_TILE(0, 3, c03)
    O2_TILE(1, 0, c10) O2_TILE(1, 1, c11) O2_TILE(1, 2, c12) O2_TILE(1, 3, c13)
}

// ---------------------------------------------------------------------------
// Flash attention, bf16 MFMA (16x16x32). 128-row Q tile, 8 waves.
// ---------------------------------------------------------------------------
#define KSTR 72

__global__ __launch_bounds__(512)
void attn_kernel(const unsigned short* __restrict__ q,
                 const unsigned short* __restrict__ k,
                 const unsigned short* __restrict__ v,
                 const float* __restrict__ bias,
                 unsigned short* __restrict__ attended) {
    int qt = blockIdx.x, h = blockIdx.y, b = blockIdx.z;
    __shared__ unsigned short Ks[64 * KSTR];
    __shared__ unsigned short Vt[64 * KSTR];
    __shared__ unsigned short Ps[128 * KSTR];
    __shared__ float af[128];
    __shared__ float lf[128];

    int tid = threadIdx.x;
    int wave = tid >> 6, lane = tid & 63;   // wave 0..7
    int quad = lane >> 4, c = lane & 15;
    int wb = wave * 16;                     // wave's q-row base, 0..112
    size_t headbase = (((size_t)b * NHEADS + h) * SEQ) * HDIM;
    int q0 = qt * 128;

    const unsigned short* qrow = q + headbase + (size_t)(q0 + wb + c) * HDIM;
    bf16x8 aq0 = *(const bf16x8*)(qrow + quad * 8);
    bf16x8 aq1 = *(const bf16x8*)(qrow + 32 + quad * 8);

    int sr = tid >> 3, sc0 = (tid & 7) * 8;   // staging: 64 rows x 8 shorts/thread

    f32x4 oacc[4];
    #pragma unroll
    for (int t = 0; t < 4; ++t) oacc[t] = (f32x4)0.f;
    float mrow[4], lrow[4];
    #pragma unroll
    for (int r = 0; r < 4; ++r) { mrow[r] = -1e30f; lrow[r] = 0.f; }

    for (int kt = 0; kt < 8; ++kt) {
        int kv0 = kt * 64;
        __syncthreads();
        {
            const unsigned short* krow = k + headbase + (size_t)(kv0 + sr) * HDIM + sc0;
            const unsigned short* vrow = v + headbase + (size_t)(kv0 + sr) * HDIM + sc0;
            u16x8 ka = *(const u16x8*)(krow);
            u16x8 va = *(const u16x8*)(vrow);
            *(u16x8*)&Ks[sr * KSTR + sc0] = ka;
            #pragma unroll
            for (int j = 0; j < 8; ++j) Vt[(sc0 + j) * KSTR + sr] = va[j];
        }
        __syncthreads();

        f32x4 sacc[4];
        #pragma unroll
        for (int nt = 0; nt < 4; ++nt) {
            const unsigned short* kbase = &Ks[(nt * 16 + c) * KSTR];
            bf16x8 b0 = *(const bf16x8*)(kbase + quad * 8);
            bf16x8 b1 = *(const bf16x8*)(kbase + 32 + quad * 8);
            f32x4 a = (f32x4)0.f;
            a = __builtin_amdgcn_mfma_f32_16x16x32_bf16(aq0, b0, a, 0, 0, 0);
            a = __builtin_amdgcn_mfma_f32_16x16x32_bf16(aq1, b1, a, 0, 0, 0);
            sacc[nt] = a;
        }

        const float* bbase = bias + (size_t)(q0 + wb + quad * 4) * 512 + kv0 + c;
        float tmax[4];
        #pragma unroll
        for (int r = 0; r < 4; ++r) tmax[r] = -1e30f;
        #pragma unroll
        for (int nt = 0; nt < 4; ++nt)
            #pragma unroll
            for (int r = 0; r < 4; ++r) {
                float s = sacc[nt][r] * SCALE + bbase[(size_t)r * 512 + nt * 16];
                sacc[nt][r] = s;
                tmax[r] = fmaxf(tmax[r], s);
            }
        #pragma unroll
        for (int r = 0; r < 4; ++r) {
            float t = tmax[r];
            t = fmaxf(t, __shfl_xor(t, 1));
            t = fmaxf(t, __shfl_xor(t, 2));
            t = fmaxf(t, __shfl_xor(t, 4));
            t = fmaxf(t, __shfl_xor(t, 8));
            tmax[r] = t;
        }
        float alpha[4];
        #pragma unroll
        for (int r = 0; r < 4; ++r) {
            float mnew = fmaxf(mrow[r], tmax[r]);
            alpha[r] = __expf(mrow[r] - mnew);
            mrow[r] = mnew;
        }
        float tsum[4];
        #pragma unroll
        for (int r = 0; r < 4; ++r) tsum[r] = 0.f;
        #pragma unroll
        for (int nt = 0; nt < 4; ++nt)
            #pragma unroll
            for (int r = 0; r < 4; ++r) {
                float p = __expf(sacc[nt][r] - mrow[r]);
                tsum[r] += p;
                Ps[(wb + quad * 4 + r) * KSTR + nt * 16 + c] = f2bf(p);
            }
        #pragma unroll
        for (int r = 0; r < 4; ++r) {
            float t = tsum[r];
            t += __shfl_xor(t, 1);
            t += __shfl_xor(t, 2);
            t += __shfl_xor(t, 4);
            t += __shfl_xor(t, 8);
            lrow[r] = lrow[r] * alpha[r] + t;
        }
        if (c == 0) {
            f32x4 av;
            av[0] = alpha[0]; av[1] = alpha[1]; av[2] = alpha[2]; av[3] = alpha[3];
            *(f32x4*)&af[wb + quad * 4] = av;
        }
        float myalpha = af[wb + c];
        #pragma unroll
        for (int t = 0; t < 4; ++t) oacc[t] *= myalpha;

        bf16x8 pb0 = *(const bf16x8*)&Ps[(wb + c) * KSTR + quad * 8];
        bf16x8 pb1 = *(const bf16x8*)&Ps[(wb + c) * KSTR + 32 + quad * 8];
        #pragma unroll
        for (int t = 0; t < 4; ++t) {
            const unsigned short* vbase = &Vt[(t * 16 + c) * KSTR];
            bf16x8 a0 = *(const bf16x8*)(vbase + quad * 8);
            bf16x8 a1 = *(const bf16x8*)(vbase + 32 + quad * 8);
            oacc[t] = __builtin_amdgcn_mfma_f32_16x16x32_bf16(a0, pb0, oacc[t], 0, 0, 0);
            oacc[t] = __builtin_amdgcn_mfma_f32_16x16x32_bf16(a1, pb1, oacc[t], 0, 0, 0);
        }
    }

    if (c == 0) {
        f32x4 lv;
        lv[0] = lrow[0]; lv[1] = lrow[1]; lv[2] = lrow[2]; lv[3] = lrow[3];
        *(f32x4*)&lf[wb + quad * 4] = lv;
    }
    float invl = 1.0f / lf[wb + c];
    unsigned short* drow = attended + ((size_t)b * SEQ + (q0 + wb + c)) * D_MODEL + h * HDIM;
    #pragma unroll
    for (int t = 0; t < 4; ++t) {
        ushort4 o;
        o.x = f2bf(oacc[t][0] * invl);
        o.y = f2bf(oacc[t][1] * invl);
        o.z = f2bf(oacc[t][2] * invl);
        o.w = f2bf(oacc[t][3] * invl);
        *(ushort4*)(drow + t * 16 + quad * 4) = o;
    }
}

extern "C" void kernel_launch(void* const* d_in, const int* in_sizes, int n_in,
                              void* d_out, int out_size, void* d_ws, size_t ws_size,
                              hipStream_t stream) {
    const float* dec    = (const float*)d_in[0];
    const float* enc    = (const float*)d_in[1];
    const float* Wqkv   = (const float*)d_in[2];
    const float* Wout   = (const float*)d_in[3];
    const float* b_out  = (const float*)d_in[4];
    const float* Wgate  = (const float*)d_in[5];
    const float* b_gate = (const float*)d_in[6];
    const float* gamma  = (const float*)d_in[7];
    const float* beta   = (const float*)d_in[8];
    float* out = (float*)d_out;

    char* ws = (char*)d_ws;
    const size_t MB = 1024 * 1024;
    unsigned short* q_ln    = (unsigned short*)(ws + 0 * MB);
    unsigned short* kv_ln   = (unsigned short*)(ws + 8 * MB);
    unsigned short* qb      = (unsigned short*)(ws + 16 * MB);
    unsigned short* kb      = (unsigned short*)(ws + 24 * MB);
    unsigned short* vb      = (unsigned short*)(ws + 32 * MB);
    unsigned short* Wqkv_bf = (unsigned short*)(ws + 40 * MB);
    float*          bias    = (float*)(ws + 46 * MB);
    unsigned short* att     = (unsigned short*)(ws + 0 * MB);    // q_ln dead after qkv
    unsigned short* t_bf    = (unsigned short*)(ws + 24 * MB);   // kb dead after attn
    unsigned short* Wout_bf = (unsigned short*)(ws + 32 * MB);   // vb dead after attn
    unsigned short* Wgate_bf= (unsigned short*)(ws + 34 * MB);

    prep_kernel<<<12288, 256, 0, stream>>>(dec, enc, gamma, beta, Wqkv,
                                           q_ln, kv_ln, bias, Wqkv_bf);
    qkv_gemm_mfma<<<768, 256, 0, stream>>>(q_ln, kv_ln, Wqkv_bf, qb, kb, vb);
    attn_kernel<<<dim3(4, 16, 8), 512, 0, stream>>>(qb, kb, vb, bias, att);
    convert_og<<<2048, 256, 0, stream>>>(Wout, Wgate, Wout_bf, Wgate_bf);
    out_gemm1_mfma<<<dim3(8, 64), 256, 0, stream>>>(att, Wout_bf, b_out, t_bf);
    out_gemm2_mfma<<<dim3(8, 64), 256, 0, stream>>>(t_bf, Wgate_bf, b_gate, dec, out);
}

// Round 12
// 244.255 us; speedup vs baseline: 1.1849x; 1.0252x over previous
//
#include <hip/hip_runtime.h>
#include <hip/hip_bf16.h>

#define D_MODEL 1024
#define NHEADS 16
#define HDIM 64
#define BATCH 8
#define SEQ 512
#define NROWS 4096          // BATCH*SEQ
#define SCALE 0.125f
#define LN_EPS 1e-5f

typedef __attribute__((ext_vector_type(8))) short bf16x8;      // 8 bf16 (4 VGPRs)
typedef __attribute__((ext_vector_type(4))) float f32x4;
typedef __attribute__((ext_vector_type(8))) unsigned short u16x8;

static __device__ __forceinline__ float bf2f(unsigned short u) {
    return __uint_as_float(((unsigned int)u) << 16);
}
static __device__ __forceinline__ unsigned short f2bf(float f) {
    unsigned int x = __float_as_uint(f);
    unsigned int r = (x + 0x7fffu + ((x >> 16) & 1u)) >> 16;   // RNE
    return (unsigned short)r;
}

// async 16B/lane global->LDS DMA; LDS dest = wave-uniform base + lane*16
#define GLOAD16(gp, lp)                                                        \
    __builtin_amdgcn_global_load_lds(                                          \
        (const __attribute__((address_space(1))) void*)(gp),                   \
        (__attribute__((address_space(3))) void*)(lp), 16, 0, 0)

// ---------------------------------------------------------------------------
// Bias helper: jax.image.resize(bias128, (512,512), 'bilinear')
// ---------------------------------------------------------------------------
static __device__ __forceinline__ float bias128(int a, int b) {
    float d = fabsf((float)(a - b));
    return expf(-d * 0.1f) - d * 0.05f;
}

// ---------------------------------------------------------------------------
// prep_kernel: fused LN (blocks 0..8191) + bias table (8192..9215) +
// Wqkv fp32->bf16 convert (9216..12287)
// ---------------------------------------------------------------------------
__global__ void prep_kernel(const float* __restrict__ dec, const float* __restrict__ enc,
                            const float* __restrict__ gamma, const float* __restrict__ beta,
                            const float* __restrict__ Wqkv,
                            unsigned short* __restrict__ q_ln, unsigned short* __restrict__ kv_ln,
                            float* __restrict__ bias, unsigned short* __restrict__ Wqkv_bf) {
    int blk = blockIdx.x;
    int t = threadIdx.x;
    if (blk >= 9216) {          // Wqkv convert
        int idx = (blk - 9216) * 256 + t;
        float4 v = ((const float4*)Wqkv)[idx];
        ushort4 u;
        u.x = f2bf(v.x); u.y = f2bf(v.y); u.z = f2bf(v.z); u.w = f2bf(v.w);
        ((ushort4*)Wqkv_bf)[idx] = u;
        return;
    }
    if (blk >= 8192) {          // bias
        int idx = (blk - 8192) * 256 + t;
        int qi = idx >> 9, kj = idx & 511;
        float fq = (qi + 0.5f) * 0.25f - 0.5f;
        float fk = (kj + 0.5f) * 0.25f - 0.5f;
        int iq = (int)floorf(fq); float tq = fq - (float)iq;
        int ik = (int)floorf(fk); float tk = fk - (float)ik;
        int iq0 = min(max(iq, 0), 127), iq1 = min(max(iq + 1, 0), 127);
        int ik0 = min(max(ik, 0), 127), ik1 = min(max(ik + 1, 0), 127);
        float v = (1.f - tq) * ((1.f - tk) * bias128(iq0, ik0) + tk * bias128(iq0, ik1))
                +        tq  * ((1.f - tk) * bias128(iq1, ik0) + tk * bias128(iq1, ik1));
        bias[idx] = v;
        return;
    }
    int row = blk;
    const float* src = (row < NROWS) ? dec + (size_t)row * D_MODEL
                                     : enc + (size_t)(row - NROWS) * D_MODEL;
    unsigned short* dst = (row < NROWS) ? q_ln + (size_t)row * D_MODEL
                                        : kv_ln + (size_t)(row - NROWS) * D_MODEL;
    float4 x = ((const float4*)src)[t];
    float s  = x.x + x.y + x.z + x.w;
    float ss = x.x * x.x + x.y * x.y + x.z * x.z + x.w * x.w;
    #pragma unroll
    for (int off = 32; off > 0; off >>= 1) {
        s  += __shfl_down(s, off);
        ss += __shfl_down(ss, off);
    }
    __shared__ float red_s[4], red_ss[4];
    int wid = t >> 6, lane = t & 63;
    if (lane == 0) { red_s[wid] = s; red_ss[wid] = ss; }
    __syncthreads();
    if (t == 0) {
        float S = red_s[0] + red_s[1] + red_s[2] + red_s[3];
        float SS = red_ss[0] + red_ss[1] + red_ss[2] + red_ss[3];
        red_s[0] = S; red_ss[0] = SS;
    }
    __syncthreads();
    float mu  = red_s[0] * (1.0f / 1024.0f);
    float var = red_ss[0] * (1.0f / 1024.0f) - mu * mu;
    float rstd = rsqrtf(var + LN_EPS);
    float4 g = ((const float4*)gamma)[t];
    float4 bb = ((const float4*)beta)[t];
    ushort4 u;
    u.x = f2bf((x.x - mu) * rstd * g.x + bb.x);
    u.y = f2bf((x.y - mu) * rstd * g.y + bb.y);
    u.z = f2bf((x.z - mu) * rstd * g.z + bb.z);
    u.w = f2bf((x.w - mu) * rstd * g.w + bb.w);
    ((ushort4*)dst)[t] = u;
}

// ---------------------------------------------------------------------------
// Wout + Wgate fp32 -> bf16 (runs after attn; targets freed vb region)
// ---------------------------------------------------------------------------
__global__ void convert_og(const float* __restrict__ Wout, const float* __restrict__ Wgate,
                           unsigned short* __restrict__ Wout_bf, unsigned short* __restrict__ Wgate_bf) {
    int idx = blockIdx.x * 256 + threadIdx.x;
    const float* src; unsigned short* dst; int off;
    if (idx < 262144) { src = (const float*)Wout; dst = Wout_bf; off = idx; }
    else              { src = (const float*)Wgate; dst = Wgate_bf; off = idx - 262144; }
    float4 v = ((const float4*)src)[off];
    ushort4 u;
    u.x = f2bf(v.x); u.y = f2bf(v.y); u.z = f2bf(v.z); u.w = f2bf(v.w);
    ((ushort4*)dst)[off] = u;
}

// ===========================================================================
// MFMA GEMM cores (bf16). Permanent lessons:
// R7: accumulators must be NAMED scalars (arrays -> scratch: VGPR~68 +
//     GB-scale WRITE_SIZE + MfmaUtil ~3%).
// R8: register prefetch / scheduling tweaks on the 2-barrier K-loop regress.
// R9: global_load_lds width=16 + XOR chunk swizzle -> 0 bank conflicts,
//     363 TF on qkv — the m97-structure plateau at K=1024.
// R11: out-GEMMs split to 64x128 tiles -> 512 blocks = 2 blocks/CU.
// ===========================================================================
#define CSTR 136   // C-bounce row stride (multiple of 8 -> 16B-aligned rows)

union alignas(16) GemmSmem {
    struct { unsigned short A[128 * 64]; unsigned short B[128 * 64]; } ab;  // 32 KB staging
    unsigned short C[128 * CSTR];                                           // 34816 B bounce
};

struct alignas(16) Smem64 {
    unsigned short A[64 * 64];      // 8 KB
    unsigned short B[128 * 64];     // 16 KB
};

#define MF(a, b, d) __builtin_amdgcn_mfma_f32_16x16x32_bf16((a), (b), (d), 0, 0, 0)

#define GEMM_KH(kh)                                                            \
    {                                                                          \
        const unsigned short* Arow_ = &As[(wr * 64 + c) * 64 + pofs##kh];      \
        const unsigned short* Brow_ = &Bs[(wc * 64 + c) * 64 + pofs##kh];      \
        bf16x8 f0 = *(const bf16x8*)(Arow_);                                   \
        bf16x8 f1 = *(const bf16x8*)(Arow_ + 1024);                            \
        bf16x8 f2 = *(const bf16x8*)(Arow_ + 2048);                            \
        bf16x8 f3 = *(const bf16x8*)(Arow_ + 3072);                            \
        bf16x8 g0 = *(const bf16x8*)(Brow_);                                   \
        bf16x8 g1 = *(const bf16x8*)(Brow_ + 1024);                            \
        bf16x8 g2 = *(const bf16x8*)(Brow_ + 2048);                            \
        bf16x8 g3 = *(const bf16x8*)(Brow_ + 3072);                            \
        a00 = MF(f0, g0, a00); a01 = MF(f0, g1, a01); a02 = MF(f0, g2, a02); a03 = MF(f0, g3, a03); \
        a10 = MF(f1, g0, a10); a11 = MF(f1, g1, a11); a12 = MF(f1, g2, a12); a13 = MF(f1, g3, a13); \
        a20 = MF(f2, g0, a20); a21 = MF(f2, g1, a21); a22 = MF(f2, g2, a22); a23 = MF(f2, g3, a23); \
        a30 = MF(f3, g0, a30); a31 = MF(f3, g1, a31); a32 = MF(f3, g2, a32); a33 = MF(f3, g3, a33); \
    }

#define GEMM_MAIN_LOOP(Aptr, Bptr)                                             \
    __shared__ GemmSmem smem;                                                  \
    unsigned short* As = smem.ab.A;                                            \
    unsigned short* Bs = smem.ab.B;                                            \
    int tid = threadIdx.x;                                                     \
    int wave = tid >> 6, lane = tid & 63, quad = lane >> 4, c = lane & 15;     \
    int wr = wave >> 1, wc = wave & 1;                                         \
    int x7 = c & 7;                                                            \
    int pofs0 = (quad ^ x7) * 8;                                               \
    int pofs1 = ((4 + quad) ^ x7) * 8;                                         \
    int grow = lane >> 3;                                                      \
    int cg = ((lane & 7) ^ grow) * 8;                                          \
    const unsigned short* Ag = (Aptr) + (size_t)(rt * 128 + wave * 32 + grow) * 1024 + cg; \
    const unsigned short* Bg = (Bptr) + (size_t)(ct * 128 + wave * 32 + grow) * 1024 + cg; \
    unsigned short* AsW = As + wave * 2048;                                    \
    unsigned short* BsW = Bs + wave * 2048;                                    \
    f32x4 a00 = (f32x4)0.f, a01 = (f32x4)0.f, a02 = (f32x4)0.f, a03 = (f32x4)0.f; \
    f32x4 a10 = (f32x4)0.f, a11 = (f32x4)0.f, a12 = (f32x4)0.f, a13 = (f32x4)0.f; \
    f32x4 a20 = (f32x4)0.f, a21 = (f32x4)0.f, a22 = (f32x4)0.f, a23 = (f32x4)0.f; \
    f32x4 a30 = (f32x4)0.f, a31 = (f32x4)0.f, a32 = (f32x4)0.f, a33 = (f32x4)0.f; \
    for (int kt = 0; kt < 16; ++kt) {                                          \
        int k0 = kt * 64;                                                      \
        __syncthreads();                                                       \
        GLOAD16(Ag + k0,         AsW);                                         \
        GLOAD16(Ag + 8192 + k0,  AsW + 512);                                   \
        GLOAD16(Ag + 16384 + k0, AsW + 1024);                                  \
        GLOAD16(Ag + 24576 + k0, AsW + 1536);                                  \
        GLOAD16(Bg + k0,         BsW);                                         \
        GLOAD16(Bg + 8192 + k0,  BsW + 512);                                   \
        GLOAD16(Bg + 16384 + k0, BsW + 1024);                                  \
        GLOAD16(Bg + 24576 + k0, BsW + 1536);                                  \
        __syncthreads();                                                       \
        GEMM_KH(0)                                                             \
        GEMM_KH(1)                                                             \
    }

// ---- 64x128 variant: wave tile 32x64 (2x4 MFMA tiles, 8 named accs) ----
#define GEMM_KH2(kh)                                                           \
    {                                                                          \
        const unsigned short* Arow_ = &As2[(wr * 32 + c) * 64 + pofs##kh];     \
        const unsigned short* Brow_ = &Bs2[(wc * 64 + c) * 64 + pofs##kh];     \
        bf16x8 f0 = *(const bf16x8*)(Arow_);                                   \
        bf16x8 f1 = *(const bf16x8*)(Arow_ + 1024);                            \
        bf16x8 g0 = *(const bf16x8*)(Brow_);                                   \
        bf16x8 g1 = *(const bf16x8*)(Brow_ + 1024);                            \
        bf16x8 g2 = *(const bf16x8*)(Brow_ + 2048);                            \
        bf16x8 g3 = *(const bf16x8*)(Brow_ + 3072);                            \
        c00 = MF(f0, g0, c00); c01 = MF(f0, g1, c01); c02 = MF(f0, g2, c02); c03 = MF(f0, g3, c03); \
        c10 = MF(f1, g0, c10); c11 = MF(f1, g1, c11); c12 = MF(f1, g2, c12); c13 = MF(f1, g3, c13); \
    }

#define GEMM_LOOP_64(Aptr, Bptr)                                               \
    __shared__ Smem64 smem2;                                                   \
    unsigned short* As2 = smem2.A;                                             \
    unsigned short* Bs2 = smem2.B;                                             \
    int tid = threadIdx.x;                                                     \
    int wave = tid >> 6, lane = tid & 63, quad = lane >> 4, c = lane & 15;     \
    int wr = wave >> 1, wc = wave & 1;                                         \
    int x7 = c & 7;                                                            \
    int pofs0 = (quad ^ x7) * 8;                                               \
    int pofs1 = ((4 + quad) ^ x7) * 8;                                         \
    int grow = lane >> 3;                                                      \
    int cg = ((lane & 7) ^ grow) * 8;                                          \
    const unsigned short* Ag = (Aptr) + (size_t)(rt * 64 + wave * 16 + grow) * 1024 + cg;  \
    const unsigned short* Bg = (Bptr) + (size_t)(ct * 128 + wave * 32 + grow) * 1024 + cg; \
    unsigned short* AsW = As2 + wave * 1024;                                   \
    unsigned short* BsW = Bs2 + wave * 2048;                                   \
    f32x4 c00 = (f32x4)0.f, c01 = (f32x4)0.f, c02 = (f32x4)0.f, c03 = (f32x4)0.f; \
    f32x4 c10 = (f32x4)0.f, c11 = (f32x4)0.f, c12 = (f32x4)0.f, c13 = (f32x4)0.f; \
    for (int kt = 0; kt < 16; ++kt) {                                          \
        int k0 = kt * 64;                                                      \
        __syncthreads();                                                       \
        GLOAD16(Ag + k0,         AsW);                                         \
        GLOAD16(Ag + 8192 + k0,  AsW + 512);                                   \
        GLOAD16(Bg + k0,         BsW);                                         \
        GLOAD16(Bg + 8192 + k0,  BsW + 512);                                   \
        GLOAD16(Bg + 16384 + k0, BsW + 1024);                                  \
        GLOAD16(Bg + 24576 + k0, BsW + 1536);                                  \
        __syncthreads();                                                       \
        GEMM_KH2(0)                                                            \
        GEMM_KH2(1)                                                            \
    }

// ---------------------------------------------------------------------------
// QKV GEMM (MFMA) + fused RoPE, LDS-bounce epilogue with wide stores.
// 1-D grid of 768, swizzled into 8(ct)x4(rt) super-tiles for L2 locality.
// ---------------------------------------------------------------------------
#define ROPE_REG(i, reg, A0, A1, A2, A3)                                       \
    {                                                                          \
        int mloc = wr * 64 + (i) * 16 + quad * 4 + (reg);                      \
        int crow = mloc * CSTR + wc * 64;                                      \
        float fl = (float)((rt * 128 + mloc) & 511);                           \
        float aa0 = fl * inv0, aa1 = fl * inv1;                                \
        float c0 = cosf(aa0), s0 = sinf(aa0);                                  \
        float c1 = cosf(aa1), s1 = sinf(aa1);                                  \
        float e0 = A0[(reg)], o0 = A2[(reg)];                                  \
        float e1 = A1[(reg)], o1 = A3[(reg)];                                  \
        smem.C[crow + c]      = f2bf(e0 * c0 - o0 * s0);                       \
        smem.C[crow + 32 + c] = f2bf(e0 * s0 + o0 * c0);                       \
        smem.C[crow + 16 + c] = f2bf(e1 * c1 - o1 * s1);                       \
        smem.C[crow + 48 + c] = f2bf(e1 * s1 + o1 * c1);                       \
    }
#define ROPE_ROW(i, A0, A1, A2, A3)                                            \
    ROPE_REG(i, 0, A0, A1, A2, A3) ROPE_REG(i, 1, A0, A1, A2, A3)              \
    ROPE_REG(i, 2, A0, A1, A2, A3) ROPE_REG(i, 3, A0, A1, A2, A3)

#define VSEC_REG(i, reg, A0, A1, A2, A3)                                       \
    {                                                                          \
        int crow = (wr * 64 + (i) * 16 + quad * 4 + (reg)) * CSTR + wc * 64;   \
        smem.C[crow + c]      = f2bf(A0[(reg)]);                               \
        smem.C[crow + 16 + c] = f2bf(A1[(reg)]);                               \
        smem.C[crow + 32 + c] = f2bf(A2[(reg)]);                               \
        smem.C[crow + 48 + c] = f2bf(A3[(reg)]);                               \
    }
#define VSEC_ROW(i, A0, A1, A2, A3)                                            \
    VSEC_REG(i, 0, A0, A1, A2, A3) VSEC_REG(i, 1, A0, A1, A2, A3)              \
    VSEC_REG(i, 2, A0, A1, A2, A3) VSEC_REG(i, 3, A0, A1, A2, A3)

__global__ __launch_bounds__(256, 1)
void qkv_gemm_mfma(const unsigned short* __restrict__ q_ln,
                   const unsigned short* __restrict__ kv_ln,
                   const unsigned short* __restrict__ Wb,
                   unsigned short* __restrict__ qo,
                   unsigned short* __restrict__ ko,
                   unsigned short* __restrict__ vo) {
    int bid = blockIdx.x;               // 0..767
    int st = bid >> 5, in = bid & 31;   // 24 super-tiles of 32 blocks
    int stc = st % 3, str = st / 3;
    int ct = stc * 8 + (in & 7);        // 0..23
    int rt = str * 4 + (in >> 3);       // 0..31
    int n0 = ct * 128;
    int section = n0 >> 10;             // 0=q 1=k 2=v (uniform per block)
    const unsigned short* A = (section == 0) ? q_ln : kv_ln;

    GEMM_MAIN_LOOP(A, Wb)

    __syncthreads();                    // all waves done reading As/Bs
    if (section == 2) {
        VSEC_ROW(0, a00, a01, a02, a03)
        VSEC_ROW(1, a10, a11, a12, a13)
        VSEC_ROW(2, a20, a21, a22, a23)
        VSEC_ROW(3, a30, a31, a32, a33)
    } else {
        float inv0 = expf(-0.2878231366f * (float)c);          // 10000^(-c/32)
        float inv1 = expf(-0.2878231366f * (float)(16 + c));
        ROPE_ROW(0, a00, a01, a02, a03)
        ROPE_ROW(1, a10, a11, a12, a13)
        ROPE_ROW(2, a20, a21, a22, a23)
        ROPE_ROW(3, a30, a31, a32, a33)
    }
    __syncthreads();

    unsigned short* outp = (section == 0) ? qo : (section == 1) ? ko : vo;
    int rr = tid >> 1, ch = tid & 1;    // row 0..127, head-half 0/1
    int mm = rt * 128 + rr;
    int bb = mm >> 9, ll = mm & 511;
    int h = ((n0 & 1023) >> 6) + ch;
    unsigned short* orow = outp + (((size_t)bb * NHEADS + h) * SEQ + ll) * HDIM;
    const unsigned short* csrc = &smem.C[rr * CSTR + ch * 64];
    #pragma unroll
    for (int kc = 0; kc < 8; ++kc)
        *(u16x8*)(orow + kc * 8) = *(const u16x8*)(csrc + kc * 8);
}

// ---------------------------------------------------------------------------
// Projection 1 (MFMA, 64x128 tile): t = att @ Wout^T + b_out -> bf16 t_bf
// grid (8, 64) = 512 blocks
// ---------------------------------------------------------------------------
#define O1_REG(mb, reg, n, Acc)                                                \
    t_bf[(size_t)((mb) + (reg)) * 1024 + (n)] = f2bf(Acc[(reg)] + bo);
#define O1_TILE(i, j, Acc)                                                     \
    {                                                                          \
        int n = ct * 128 + wc * 64 + (j) * 16 + c;                             \
        float bo = b_out[n];                                                   \
        int mb = rt * 64 + wr * 32 + (i) * 16 + quad * 4;                      \
        O1_REG(mb, 0, n, Acc) O1_REG(mb, 1, n, Acc)                            \
        O1_REG(mb, 2, n, Acc) O1_REG(mb, 3, n, Acc)                            \
    }

__global__ __launch_bounds__(256, 1)
void out_gemm1_mfma(const unsigned short* __restrict__ att,
                    const unsigned short* __restrict__ Wob,
                    const float* __restrict__ b_out,
                    unsigned short* __restrict__ t_bf) {
    int ct = blockIdx.x, rt = blockIdx.y;

    GEMM_LOOP_64(att, Wob)

    O1_TILE(0, 0, c00) O1_TILE(0, 1, c01) O1_TILE(0, 2, c02) O1_TILE(0, 3, c03)
    O1_TILE(1, 0, c10) O1_TILE(1, 1, c11) O1_TILE(1, 2, c12) O1_TILE(1, 3, c13)
}

// ---------------------------------------------------------------------------
// Projection 2 (MFMA, 64x128 tile): gz = t_bf @ Wgate^T + b_gate;
// out = sigmoid(gz)*t + (1-sigmoid)*residual   (t read back as bf16)
// grid (8, 64) = 512 blocks
// ---------------------------------------------------------------------------
#define O2_REG(mb, reg, n, Acc)                                                \
    {                                                                          \
        float gz = Acc[(reg)] + bg;                                            \
        float g = 1.0f / (1.0f + expf(-gz));                                   \
        size_t idx = (size_t)((mb) + (reg)) * 1024 + (n);                      \
        float tv = bf2f(t_bf[idx]);                                            \
        float rv = residual[idx];                                              \
        out[idx] = g * tv + (1.0f - g) * rv;                                   \
    }
#define O2_TILE(i, j, Acc)                                                     \
    {                                                                          \
        int n = ct * 128 + wc * 64 + (j) * 16 + c;                             \
        float bg = b_gate[n];                                                  \
        int mb = rt * 64 + wr * 32 + (i) * 16 + quad * 4;                      \
        O2_REG(mb, 0, n, Acc) O2_REG(mb, 1, n, Acc)                            \
        O2_REG(mb, 2, n, Acc) O2_REG(mb, 3, n, Acc)                            \
    }

__global__ __launch_bounds__(256, 1)
void out_gemm2_mfma(const unsigned short* __restrict__ t_bf,
                    const unsigned short* __restrict__ Wgb,
                    const float* __restrict__ b_gate,
                    const float* __restrict__ residual,
                    float* __restrict__ out) {
    int ct = blockIdx.x, rt = blockIdx.y;

    GEMM_LOOP_64(t_bf, Wgb)

    O2_TILE(0, 0, c00) O2_TILE(0, 1, c01) O2_TILE(0, 2, c02) O2_TILE(0, 3, c03)
    O2_TILE(1, 0, c10) O2_TILE(1, 1, c11) O2_TILE(1, 2, c12) O2_TILE(1, 3, c13)
}

// ---------------------------------------------------------------------------
// Flash attention, bf16 MFMA (16x16x32). 128-row Q tile, 8 waves.
// R12: UNNORMALIZED streaming softmax — scores are tightly bounded
// (|s| < ~10: q,k ~ N(0,0.64^2), bias in [-6.5,1]), so p = expf(s) directly,
// accumulate l and O, normalize once at the end. Removes per-tile max
// reduction, alpha rescale, and the af LDS broadcast. fp32 overflow margin
// is decades (exp(88) limit vs exp(~4) actual).
// ---------------------------------------------------------------------------
#define KSTR 72

__global__ __launch_bounds__(512)
void attn_kernel(const unsigned short* __restrict__ q,
                 const unsigned short* __restrict__ k,
                 const unsigned short* __restrict__ v,
                 const float* __restrict__ bias,
                 unsigned short* __restrict__ attended) {
    int qt = blockIdx.x, h = blockIdx.y, b = blockIdx.z;
    __shared__ unsigned short Ks[64 * KSTR];
    __shared__ unsigned short Vt[64 * KSTR];
    __shared__ unsigned short Ps[128 * KSTR];
    __shared__ float lf[128];

    int tid = threadIdx.x;
    int wave = tid >> 6, lane = tid & 63;   // wave 0..7
    int quad = lane >> 4, c = lane & 15;
    int wb = wave * 16;                     // wave's q-row base, 0..112
    size_t headbase = (((size_t)b * NHEADS + h) * SEQ) * HDIM;
    int q0 = qt * 128;

    const unsigned short* qrow = q + headbase + (size_t)(q0 + wb + c) * HDIM;
    bf16x8 aq0 = *(const bf16x8*)(qrow + quad * 8);
    bf16x8 aq1 = *(const bf16x8*)(qrow + 32 + quad * 8);

    int sr = tid >> 3, sc0 = (tid & 7) * 8;   // staging: 64 rows x 8 shorts/thread

    f32x4 oacc[4];
    #pragma unroll
    for (int t = 0; t < 4; ++t) oacc[t] = (f32x4)0.f;
    float lrow[4];
    #pragma unroll
    for (int r = 0; r < 4; ++r) lrow[r] = 0.f;

    for (int kt = 0; kt < 8; ++kt) {
        int kv0 = kt * 64;
        __syncthreads();
        {
            const unsigned short* krow = k + headbase + (size_t)(kv0 + sr) * HDIM + sc0;
            const unsigned short* vrow = v + headbase + (size_t)(kv0 + sr) * HDIM + sc0;
            u16x8 ka = *(const u16x8*)(krow);
            u16x8 va = *(const u16x8*)(vrow);
            *(u16x8*)&Ks[sr * KSTR + sc0] = ka;
            #pragma unroll
            for (int j = 0; j < 8; ++j) Vt[(sc0 + j) * KSTR + sr] = va[j];
        }
        __syncthreads();

        f32x4 sacc[4];
        #pragma unroll
        for (int nt = 0; nt < 4; ++nt) {
            const unsigned short* kbase = &Ks[(nt * 16 + c) * KSTR];
            bf16x8 b0 = *(const bf16x8*)(kbase + quad * 8);
            bf16x8 b1 = *(const bf16x8*)(kbase + 32 + quad * 8);
            f32x4 a = (f32x4)0.f;
            a = __builtin_amdgcn_mfma_f32_16x16x32_bf16(aq0, b0, a, 0, 0, 0);
            a = __builtin_amdgcn_mfma_f32_16x16x32_bf16(aq1, b1, a, 0, 0, 0);
            sacc[nt] = a;
        }

        const float* bbase = bias + (size_t)(q0 + wb + quad * 4) * 512 + kv0 + c;
        float tsum[4];
        #pragma unroll
        for (int r = 0; r < 4; ++r) tsum[r] = 0.f;
        #pragma unroll
        for (int nt = 0; nt < 4; ++nt)
            #pragma unroll
            for (int r = 0; r < 4; ++r) {
                float p = __expf(sacc[nt][r] * SCALE + bbase[(size_t)r * 512 + nt * 16]);
                tsum[r] += p;
                Ps[(wb + quad * 4 + r) * KSTR + nt * 16 + c] = f2bf(p);
            }
        #pragma unroll
        for (int r = 0; r < 4; ++r) {
            float t = tsum[r];
            t += __shfl_xor(t, 1);
            t += __shfl_xor(t, 2);
            t += __shfl_xor(t, 4);
            t += __shfl_xor(t, 8);
            lrow[r] += t;
        }

        bf16x8 pb0 = *(const bf16x8*)&Ps[(wb + c) * KSTR + quad * 8];
        bf16x8 pb1 = *(const bf16x8*)&Ps[(wb + c) * KSTR + 32 + quad * 8];
        #pragma unroll
        for (int t = 0; t < 4; ++t) {
            const unsigned short* vbase = &Vt[(t * 16 + c) * KSTR];
            bf16x8 a0 = *(const bf16x8*)(vbase + quad * 8);
            bf16x8 a1 = *(const bf16x8*)(vbase + 32 + quad * 8);
            oacc[t] = __builtin_amdgcn_mfma_f32_16x16x32_bf16(a0, pb0, oacc[t], 0, 0, 0);
            oacc[t] = __builtin_amdgcn_mfma_f32_16x16x32_bf16(a1, pb1, oacc[t], 0, 0, 0);
        }
    }

    if (c == 0) {
        f32x4 lv;
        lv[0] = lrow[0]; lv[1] = lrow[1]; lv[2] = lrow[2]; lv[3] = lrow[3];
        *(f32x4*)&lf[wb + quad * 4] = lv;
    }
    float invl = 1.0f / lf[wb + c];
    unsigned short* drow = attended + ((size_t)b * SEQ + (q0 + wb + c)) * D_MODEL + h * HDIM;
    #pragma unroll
    for (int t = 0; t < 4; ++t) {
        ushort4 o;
        o.x = f2bf(oacc[t][0] * invl);
        o.y = f2bf(oacc[t][1] * invl);
        o.z = f2bf(oacc[t][2] * invl);
        o.w = f2bf(oacc[t][3] * invl);
        *(ushort4*)(drow + t * 16 + quad * 4) = o;
    }
}

extern "C" void kernel_launch(void* const* d_in, const int* in_sizes, int n_in,
                              void* d_out, int out_size, void* d_ws, size_t ws_size,
                              hipStream_t stream) {
    const float* dec    = (const float*)d_in[0];
    const float* enc    = (const float*)d_in[1];
    const float* Wqkv   = (const float*)d_in[2];
    const float* Wout   = (const float*)d_in[3];
    const float* b_out  = (const float*)d_in[4];
    const float* Wgate  = (const float*)d_in[5];
    const float* b_gate = (const float*)d_in[6];
    const float* gamma  = (const float*)d_in[7];
    const float* beta   = (const float*)d_in[8];
    float* out = (float*)d_out;

    char* ws = (char*)d_ws;
    const size_t MB = 1024 * 1024;
    unsigned short* q_ln    = (unsigned short*)(ws + 0 * MB);
    unsigned short* kv_ln   = (unsigned short*)(ws + 8 * MB);
    unsigned short* qb      = (unsigned short*)(ws + 16 * MB);
    unsigned short* kb      = (unsigned short*)(ws + 24 * MB);
    unsigned short* vb      = (unsigned short*)(ws + 32 * MB);
    unsigned short* Wqkv_bf = (unsigned short*)(ws + 40 * MB);
    float*          bias    = (float*)(ws + 46 * MB);
    unsigned short* att     = (unsigned short*)(ws + 0 * MB);    // q_ln dead after qkv
    unsigned short* t_bf    = (unsigned short*)(ws + 24 * MB);   // kb dead after attn
    unsigned short* Wout_bf = (unsigned short*)(ws + 32 * MB);   // vb dead after attn
    unsigned short* Wgate_bf= (unsigned short*)(ws + 34 * MB);

    prep_kernel<<<12288, 256, 0, stream>>>(dec, enc, gamma, beta, Wqkv,
                                           q_ln, kv_ln, bias, Wqkv_bf);
    qkv_gemm_mfma<<<768, 256, 0, stream>>>(q_ln, kv_ln, Wqkv_bf, qb, kb, vb);
    attn_kernel<<<dim3(4, 16, 8), 512, 0, stream>>>(qb, kb, vb, bias, att);
    convert_og<<<2048, 256, 0, stream>>>(Wout, Wgate, Wout_bf, Wgate_bf);
    out_gemm1_mfma<<<dim3(8, 64), 256, 0, stream>>>(att, Wout_bf, b_out, t_bf);
    out_gemm2_mfma<<<dim3(8, 64), 256, 0, stream>>>(t_bf, Wgate_bf, b_gate, dec, out);
}

// Round 13
// 237.453 us; speedup vs baseline: 1.2188x; 1.0286x over previous
//
#include <hip/hip_runtime.h>
#include <hip/hip_bf16.h>

#define D_MODEL 1024
#define NHEADS 16
#define HDIM 64
#define BATCH 8
#define SEQ 512
#define NROWS 4096          // BATCH*SEQ
#define SCALE 0.125f
#define LN_EPS 1e-5f

typedef __attribute__((ext_vector_type(8))) short bf16x8;      // 8 bf16 (4 VGPRs)
typedef __attribute__((ext_vector_type(4))) float f32x4;
typedef __attribute__((ext_vector_type(8))) unsigned short u16x8;

static __device__ __forceinline__ float bf2f(unsigned short u) {
    return __uint_as_float(((unsigned int)u) << 16);
}
static __device__ __forceinline__ unsigned short f2bf(float f) {
    unsigned int x = __float_as_uint(f);
    unsigned int r = (x + 0x7fffu + ((x >> 16) & 1u)) >> 16;   // RNE
    return (unsigned short)r;
}

// async 16B/lane global->LDS DMA; LDS dest = wave-uniform base + lane*16
#define GLOAD16(gp, lp)                                                        \
    __builtin_amdgcn_global_load_lds(                                          \
        (const __attribute__((address_space(1))) void*)(gp),                   \
        (__attribute__((address_space(3))) void*)(lp), 16, 0, 0)

// ---------------------------------------------------------------------------
// Bias helper: jax.image.resize(bias128, (512,512), 'bilinear')
// ---------------------------------------------------------------------------
static __device__ __forceinline__ float bias128(int a, int b) {
    float d = fabsf((float)(a - b));
    return expf(-d * 0.1f) - d * 0.05f;
}

// ---------------------------------------------------------------------------
// prep_kernel: fused LN (blocks 0..8191) + bias table (8192..9215) +
// Wqkv convert (9216..12287) + [hoisted Wout/Wgate convert (12288..14335)]
// ---------------------------------------------------------------------------
__global__ void prep_kernel(const float* __restrict__ dec, const float* __restrict__ enc,
                            const float* __restrict__ gamma, const float* __restrict__ beta,
                            const float* __restrict__ Wqkv,
                            const float* __restrict__ Wout, const float* __restrict__ Wgate,
                            unsigned short* __restrict__ q_ln, unsigned short* __restrict__ kv_ln,
                            float* __restrict__ bias, unsigned short* __restrict__ Wqkv_bf,
                            unsigned short* __restrict__ Wout_bf, unsigned short* __restrict__ Wgate_bf) {
    int blk = blockIdx.x;
    int t = threadIdx.x;
    if (blk >= 12288) {         // hoisted Wout/Wgate convert (only when launched)
        int idx = (blk - 12288) * 256 + t;
        const float* src; unsigned short* dst; int off;
        if (idx < 262144) { src = Wout; dst = Wout_bf; off = idx; }
        else              { src = Wgate; dst = Wgate_bf; off = idx - 262144; }
        float4 v = ((const float4*)src)[off];
        ushort4 u;
        u.x = f2bf(v.x); u.y = f2bf(v.y); u.z = f2bf(v.z); u.w = f2bf(v.w);
        ((ushort4*)dst)[off] = u;
        return;
    }
    if (blk >= 9216) {          // Wqkv convert
        int idx = (blk - 9216) * 256 + t;
        float4 v = ((const float4*)Wqkv)[idx];
        ushort4 u;
        u.x = f2bf(v.x); u.y = f2bf(v.y); u.z = f2bf(v.z); u.w = f2bf(v.w);
        ((ushort4*)Wqkv_bf)[idx] = u;
        return;
    }
    if (blk >= 8192) {          // bias
        int idx = (blk - 8192) * 256 + t;
        int qi = idx >> 9, kj = idx & 511;
        float fq = (qi + 0.5f) * 0.25f - 0.5f;
        float fk = (kj + 0.5f) * 0.25f - 0.5f;
        int iq = (int)floorf(fq); float tq = fq - (float)iq;
        int ik = (int)floorf(fk); float tk = fk - (float)ik;
        int iq0 = min(max(iq, 0), 127), iq1 = min(max(iq + 1, 0), 127);
        int ik0 = min(max(ik, 0), 127), ik1 = min(max(ik + 1, 0), 127);
        float v = (1.f - tq) * ((1.f - tk) * bias128(iq0, ik0) + tk * bias128(iq0, ik1))
                +        tq  * ((1.f - tk) * bias128(iq1, ik0) + tk * bias128(iq1, ik1));
        bias[idx] = v;
        return;
    }
    int row = blk;
    const float* src = (row < NROWS) ? dec + (size_t)row * D_MODEL
                                     : enc + (size_t)(row - NROWS) * D_MODEL;
    unsigned short* dst = (row < NROWS) ? q_ln + (size_t)row * D_MODEL
                                        : kv_ln + (size_t)(row - NROWS) * D_MODEL;
    float4 x = ((const float4*)src)[t];
    float s  = x.x + x.y + x.z + x.w;
    float ss = x.x * x.x + x.y * x.y + x.z * x.z + x.w * x.w;
    #pragma unroll
    for (int off = 32; off > 0; off >>= 1) {
        s  += __shfl_down(s, off);
        ss += __shfl_down(ss, off);
    }
    __shared__ float red_s[4], red_ss[4];
    int wid = t >> 6, lane = t & 63;
    if (lane == 0) { red_s[wid] = s; red_ss[wid] = ss; }
    __syncthreads();
    if (t == 0) {
        float S = red_s[0] + red_s[1] + red_s[2] + red_s[3];
        float SS = red_ss[0] + red_ss[1] + red_ss[2] + red_ss[3];
        red_s[0] = S; red_ss[0] = SS;
    }
    __syncthreads();
    float mu  = red_s[0] * (1.0f / 1024.0f);
    float var = red_ss[0] * (1.0f / 1024.0f) - mu * mu;
    float rstd = rsqrtf(var + LN_EPS);
    float4 g = ((const float4*)gamma)[t];
    float4 bb = ((const float4*)beta)[t];
    ushort4 u;
    u.x = f2bf((x.x - mu) * rstd * g.x + bb.x);
    u.y = f2bf((x.y - mu) * rstd * g.y + bb.y);
    u.z = f2bf((x.z - mu) * rstd * g.z + bb.z);
    u.w = f2bf((x.w - mu) * rstd * g.w + bb.w);
    ((ushort4*)dst)[t] = u;
}

// ---------------------------------------------------------------------------
// Wout + Wgate fp32 -> bf16 (fallback path when ws too small to hoist)
// ---------------------------------------------------------------------------
__global__ void convert_og(const float* __restrict__ Wout, const float* __restrict__ Wgate,
                           unsigned short* __restrict__ Wout_bf, unsigned short* __restrict__ Wgate_bf) {
    int idx = blockIdx.x * 256 + threadIdx.x;
    const float* src; unsigned short* dst; int off;
    if (idx < 262144) { src = (const float*)Wout; dst = Wout_bf; off = idx; }
    else              { src = (const float*)Wgate; dst = Wgate_bf; off = idx - 262144; }
    float4 v = ((const float4*)src)[off];
    ushort4 u;
    u.x = f2bf(v.x); u.y = f2bf(v.y); u.z = f2bf(v.z); u.w = f2bf(v.w);
    ((ushort4*)dst)[off] = u;
}

// ===========================================================================
// MFMA GEMM cores (bf16). Permanent lessons:
// R7: accumulators/offsets must be NAMED scalars (arrays -> scratch).
// R8: register prefetch / scheduling tweaks on the 2-barrier K-loop regress.
// R9: global_load_lds width=16 + XOR chunk swizzle -> 0 bank conflicts.
// R11: out-GEMMs 64x128 tiles -> 512 blocks = 2 blocks/CU.
// R13: out-GEMMs BK=128 (8 iters, 32 MFMA/wave-stage) — halves barrier
//      drains; 48 KB LDS still allows 3 blocks/CU (grid is the limit).
// ===========================================================================
#define CSTR 136   // C-bounce row stride (multiple of 8 -> 16B-aligned rows)

union alignas(16) GemmSmem {
    struct { unsigned short A[128 * 64]; unsigned short B[128 * 64]; } ab;  // 32 KB staging
    unsigned short C[128 * CSTR];                                           // 34816 B bounce
};

struct alignas(16) Smem64B {
    unsigned short A[64 * 128];     // 16 KB
    unsigned short B[128 * 128];    // 32 KB
};

#define MF(a, b, d) __builtin_amdgcn_mfma_f32_16x16x32_bf16((a), (b), (d), 0, 0, 0)

#define GEMM_KH(kh)                                                            \
    {                                                                          \
        const unsigned short* Arow_ = &As[(wr * 64 + c) * 64 + pofs##kh];      \
        const unsigned short* Brow_ = &Bs[(wc * 64 + c) * 64 + pofs##kh];      \
        bf16x8 f0 = *(const bf16x8*)(Arow_);                                   \
        bf16x8 f1 = *(const bf16x8*)(Arow_ + 1024);                            \
        bf16x8 f2 = *(const bf16x8*)(Arow_ + 2048);                            \
        bf16x8 f3 = *(const bf16x8*)(Arow_ + 3072);                            \
        bf16x8 g0 = *(const bf16x8*)(Brow_);                                   \
        bf16x8 g1 = *(const bf16x8*)(Brow_ + 1024);                            \
        bf16x8 g2 = *(const bf16x8*)(Brow_ + 2048);                            \
        bf16x8 g3 = *(const bf16x8*)(Brow_ + 3072);                            \
        a00 = MF(f0, g0, a00); a01 = MF(f0, g1, a01); a02 = MF(f0, g2, a02); a03 = MF(f0, g3, a03); \
        a10 = MF(f1, g0, a10); a11 = MF(f1, g1, a11); a12 = MF(f1, g2, a12); a13 = MF(f1, g3, a13); \
        a20 = MF(f2, g0, a20); a21 = MF(f2, g1, a21); a22 = MF(f2, g2, a22); a23 = MF(f2, g3, a23); \
        a30 = MF(f3, g0, a30); a31 = MF(f3, g1, a31); a32 = MF(f3, g2, a32); a33 = MF(f3, g3, a33); \
    }

#define GEMM_MAIN_LOOP(Aptr, Bptr)                                             \
    __shared__ GemmSmem smem;                                                  \
    unsigned short* As = smem.ab.A;                                            \
    unsigned short* Bs = smem.ab.B;                                            \
    int tid = threadIdx.x;                                                     \
    int wave = tid >> 6, lane = tid & 63, quad = lane >> 4, c = lane & 15;     \
    int wr = wave >> 1, wc = wave & 1;                                         \
    int x7 = c & 7;                                                            \
    int pofs0 = (quad ^ x7) * 8;                                               \
    int pofs1 = ((4 + quad) ^ x7) * 8;                                         \
    int grow = lane >> 3;                                                      \
    int cg = ((lane & 7) ^ grow) * 8;                                          \
    const unsigned short* Ag = (Aptr) + (size_t)(rt * 128 + wave * 32 + grow) * 1024 + cg; \
    const unsigned short* Bg = (Bptr) + (size_t)(ct * 128 + wave * 32 + grow) * 1024 + cg; \
    unsigned short* AsW = As + wave * 2048;                                    \
    unsigned short* BsW = Bs + wave * 2048;                                    \
    f32x4 a00 = (f32x4)0.f, a01 = (f32x4)0.f, a02 = (f32x4)0.f, a03 = (f32x4)0.f; \
    f32x4 a10 = (f32x4)0.f, a11 = (f32x4)0.f, a12 = (f32x4)0.f, a13 = (f32x4)0.f; \
    f32x4 a20 = (f32x4)0.f, a21 = (f32x4)0.f, a22 = (f32x4)0.f, a23 = (f32x4)0.f; \
    f32x4 a30 = (f32x4)0.f, a31 = (f32x4)0.f, a32 = (f32x4)0.f, a33 = (f32x4)0.f; \
    for (int kt = 0; kt < 16; ++kt) {                                          \
        int k0 = kt * 64;                                                      \
        __syncthreads();                                                       \
        GLOAD16(Ag + k0,         AsW);                                         \
        GLOAD16(Ag + 8192 + k0,  AsW + 512);                                   \
        GLOAD16(Ag + 16384 + k0, AsW + 1024);                                  \
        GLOAD16(Ag + 24576 + k0, AsW + 1536);                                  \
        GLOAD16(Bg + k0,         BsW);                                         \
        GLOAD16(Bg + 8192 + k0,  BsW + 512);                                   \
        GLOAD16(Bg + 16384 + k0, BsW + 1024);                                  \
        GLOAD16(Bg + 24576 + k0, BsW + 1536);                                  \
        __syncthreads();                                                       \
        GEMM_KH(0)                                                             \
        GEMM_KH(1)                                                             \
    }

// ---- 64x128 tile, BK=128 (R13): wave tile 32x64, 8 iters, 32 MFMA/stage ----
// LDS rows of 128 shorts, 16 chunk-slots; row r slot s holds chunk s^(r&15).
#define GEMM_KH2B(kh)                                                          \
    {                                                                          \
        int pofs = (((kh) * 4 + quad) ^ c) * 8;                                \
        const unsigned short* Arow_ = &As2[(wr * 32 + c) * 128 + pofs];        \
        const unsigned short* Brow_ = &Bs2[(wc * 64 + c) * 128 + pofs];        \
        bf16x8 f0 = *(const bf16x8*)(Arow_);                                   \
        bf16x8 f1 = *(const bf16x8*)(Arow_ + 2048);                            \
        bf16x8 g0 = *(const bf16x8*)(Brow_);                                   \
        bf16x8 g1 = *(const bf16x8*)(Brow_ + 2048);                            \
        bf16x8 g2 = *(const bf16x8*)(Brow_ + 4096);                            \
        bf16x8 g3 = *(const bf16x8*)(Brow_ + 6144);                            \
        c00 = MF(f0, g0, c00); c01 = MF(f0, g1, c01); c02 = MF(f0, g2, c02); c03 = MF(f0, g3, c03); \
        c10 = MF(f1, g0, c10); c11 = MF(f1, g1, c11); c12 = MF(f1, g2, c12); c13 = MF(f1, g3, c13); \
    }

#define GEMM_LOOP_64B(Aptr, Bptr)                                              \
    __shared__ Smem64B smem2;                                                  \
    unsigned short* As2 = smem2.A;                                             \
    unsigned short* Bs2 = smem2.B;                                             \
    int tid = threadIdx.x;                                                     \
    int wave = tid >> 6, lane = tid & 63, quad = lane >> 4, c = lane & 15;     \
    int wr = wave >> 1, wc = wave & 1;                                         \
    int l4 = lane >> 4, l15 = lane & 15;                                       \
    const unsigned short* Abase = (Aptr) + (size_t)(rt * 64) * 1024;           \
    const unsigned short* Bbase = (Bptr) + (size_t)(ct * 128) * 1024;          \
    int aoff0 = (wave * 16 +  0 + l4) * 1024 + ((l15 ^ ( 0 + l4)) * 8);        \
    int aoff1 = (wave * 16 +  4 + l4) * 1024 + ((l15 ^ ( 4 + l4)) * 8);        \
    int aoff2 = (wave * 16 +  8 + l4) * 1024 + ((l15 ^ ( 8 + l4)) * 8);        \
    int aoff3 = (wave * 16 + 12 + l4) * 1024 + ((l15 ^ (12 + l4)) * 8);        \
    int boff0 = (wave * 32 +  0 + l4) * 1024 + ((l15 ^ (( 0 + l4) & 15)) * 8); \
    int boff1 = (wave * 32 +  4 + l4) * 1024 + ((l15 ^ (( 4 + l4) & 15)) * 8); \
    int boff2 = (wave * 32 +  8 + l4) * 1024 + ((l15 ^ (( 8 + l4) & 15)) * 8); \
    int boff3 = (wave * 32 + 12 + l4) * 1024 + ((l15 ^ ((12 + l4) & 15)) * 8); \
    int boff4 = (wave * 32 + 16 + l4) * 1024 + ((l15 ^ ((16 + l4) & 15)) * 8); \
    int boff5 = (wave * 32 + 20 + l4) * 1024 + ((l15 ^ ((20 + l4) & 15)) * 8); \
    int boff6 = (wave * 32 + 24 + l4) * 1024 + ((l15 ^ ((24 + l4) & 15)) * 8); \
    int boff7 = (wave * 32 + 28 + l4) * 1024 + ((l15 ^ ((28 + l4) & 15)) * 8); \
    unsigned short* AsW = As2 + wave * 2048;                                   \
    unsigned short* BsW = Bs2 + wave * 4096;                                   \
    f32x4 c00 = (f32x4)0.f, c01 = (f32x4)0.f, c02 = (f32x4)0.f, c03 = (f32x4)0.f; \
    f32x4 c10 = (f32x4)0.f, c11 = (f32x4)0.f, c12 = (f32x4)0.f, c13 = (f32x4)0.f; \
    for (int kt = 0; kt < 8; ++kt) {                                           \
        int k0 = kt * 128;                                                     \
        __syncthreads();                                                       \
        GLOAD16(Abase + aoff0 + k0, AsW);                                      \
        GLOAD16(Abase + aoff1 + k0, AsW + 512);                                \
        GLOAD16(Abase + aoff2 + k0, AsW + 1024);                               \
        GLOAD16(Abase + aoff3 + k0, AsW + 1536);                               \
        GLOAD16(Bbase + boff0 + k0, BsW);                                      \
        GLOAD16(Bbase + boff1 + k0, BsW + 512);                                \
        GLOAD16(Bbase + boff2 + k0, BsW + 1024);                               \
        GLOAD16(Bbase + boff3 + k0, BsW + 1536);                               \
        GLOAD16(Bbase + boff4 + k0, BsW + 2048);                               \
        GLOAD16(Bbase + boff5 + k0, BsW + 2560);                               \
        GLOAD16(Bbase + boff6 + k0, BsW + 3072);                               \
        GLOAD16(Bbase + boff7 + k0, BsW + 3584);                               \
        __syncthreads();                                                       \
        GEMM_KH2B(0)                                                           \
        GEMM_KH2B(1)                                                           \
        GEMM_KH2B(2)                                                           \
        GEMM_KH2B(3)                                                           \
    }

// ---------------------------------------------------------------------------
// QKV GEMM (MFMA) + fused RoPE, LDS-bounce epilogue with wide stores.
// ---------------------------------------------------------------------------
#define ROPE_REG(i, reg, A0, A1, A2, A3)                                       \
    {                                                                          \
        int mloc = wr * 64 + (i) * 16 + quad * 4 + (reg);                      \
        int crow = mloc * CSTR + wc * 64;                                      \
        float fl = (float)((rt * 128 + mloc) & 511);                           \
        float aa0 = fl * inv0, aa1 = fl * inv1;                                \
        float c0 = cosf(aa0), s0 = sinf(aa0);                                  \
        float c1 = cosf(aa1), s1 = sinf(aa1);                                  \
        float e0 = A0[(reg)], o0 = A2[(reg)];                                  \
        float e1 = A1[(reg)], o1 = A3[(reg)];                                  \
        smem.C[crow + c]      = f2bf(e0 * c0 - o0 * s0);                       \
        smem.C[crow + 32 + c] = f2bf(e0 * s0 + o0 * c0);                       \
        smem.C[crow + 16 + c] = f2bf(e1 * c1 - o1 * s1);                       \
        smem.C[crow + 48 + c] = f2bf(e1 * s1 + o1 * c1);                       \
    }
#define ROPE_ROW(i, A0, A1, A2, A3)                                            \
    ROPE_REG(i, 0, A0, A1, A2, A3) ROPE_REG(i, 1, A0, A1, A2, A3)              \
    ROPE_REG(i, 2, A0, A1, A2, A3) ROPE_REG(i, 3, A0, A1, A2, A3)

#define VSEC_REG(i, reg, A0, A1, A2, A3)                                       \
    {                                                                          \
        int crow = (wr * 64 + (i) * 16 + quad * 4 + (reg)) * CSTR + wc * 64;   \
        smem.C[crow + c]      = f2bf(A0[(reg)]);                               \
        smem.C[crow + 16 + c] = f2bf(A1[(reg)]);                               \
        smem.C[crow + 32 + c] = f2bf(A2[(reg)]);                               \
        smem.C[crow + 48 + c] = f2bf(A3[(reg)]);                               \
    }
#define VSEC_ROW(i, A0, A1, A2, A3)                                            \
    VSEC_REG(i, 0, A0, A1, A2, A3) VSEC_REG(i, 1, A0, A1, A2, A3)              \
    VSEC_REG(i, 2, A0, A1, A2, A3) VSEC_REG(i, 3, A0, A1, A2, A3)

__global__ __launch_bounds__(256, 1)
void qkv_gemm_mfma(const unsigned short* __restrict__ q_ln,
                   const unsigned short* __restrict__ kv_ln,
                   const unsigned short* __restrict__ Wb,
                   unsigned short* __restrict__ qo,
                   unsigned short* __restrict__ ko,
                   unsigned short* __restrict__ vo) {
    int bid = blockIdx.x;               // 0..767
    int st = bid >> 5, in = bid & 31;   // 24 super-tiles of 32 blocks
    int stc = st % 3, str = st / 3;
    int ct = stc * 8 + (in & 7);        // 0..23
    int rt = str * 4 + (in >> 3);       // 0..31
    int n0 = ct * 128;
    int section = n0 >> 10;             // 0=q 1=k 2=v (uniform per block)
    const unsigned short* A = (section == 0) ? q_ln : kv_ln;

    GEMM_MAIN_LOOP(A, Wb)

    __syncthreads();                    // all waves done reading As/Bs
    if (section == 2) {
        VSEC_ROW(0, a00, a01, a02, a03)
        VSEC_ROW(1, a10, a11, a12, a13)
        VSEC_ROW(2, a20, a21, a22, a23)
        VSEC_ROW(3, a30, a31, a32, a33)
    } else {
        float inv0 = expf(-0.2878231366f * (float)c);          // 10000^(-c/32)
        float inv1 = expf(-0.2878231366f * (float)(16 + c));
        ROPE_ROW(0, a00, a01, a02, a03)
        ROPE_ROW(1, a10, a11, a12, a13)
        ROPE_ROW(2, a20, a21, a22, a23)
        ROPE_ROW(3, a30, a31, a32, a33)
    }
    __syncthreads();

    unsigned short* outp = (section == 0) ? qo : (section == 1) ? ko : vo;
    int rr = tid >> 1, ch = tid & 1;    // row 0..127, head-half 0/1
    int mm = rt * 128 + rr;
    int bb = mm >> 9, ll = mm & 511;
    int h = ((n0 & 1023) >> 6) + ch;
    unsigned short* orow = outp + (((size_t)bb * NHEADS + h) * SEQ + ll) * HDIM;
    const unsigned short* csrc = &smem.C[rr * CSTR + ch * 64];
    #pragma unroll
    for (int kc = 0; kc < 8; ++kc)
        *(u16x8*)(orow + kc * 8) = *(const u16x8*)(csrc + kc * 8);
}

// ---------------------------------------------------------------------------
// Projection 1 (MFMA, 64x128 tile, BK=128): t = att @ Wout^T + b_out -> bf16
// grid (8, 64) = 512 blocks
// ---------------------------------------------------------------------------
#define O1_REG(mb, reg, n, Acc)                                                \
    t_bf[(size_t)((mb) + (reg)) * 1024 + (n)] = f2bf(Acc[(reg)] + bo);
#define O1_TILE(i, j, Acc)                                                     \
    {                                                                          \
        int n = ct * 128 + wc * 64 + (j) * 16 + c;                             \
        float bo = b_out[n];                                                   \
        int mb = rt * 64 + wr * 32 + (i) * 16 + quad * 4;                      \
        O1_REG(mb, 0, n, Acc) O1_REG(mb, 1, n, Acc)                            \
        O1_REG(mb, 2, n, Acc) O1_REG(mb, 3, n, Acc)                            \
    }

__global__ __launch_bounds__(256, 1)
void out_gemm1_mfma(const unsigned short* __restrict__ att,
                    const unsigned short* __restrict__ Wob,
                    const float* __restrict__ b_out,
                    unsigned short* __restrict__ t_bf) {
    int ct = blockIdx.x, rt = blockIdx.y;

    GEMM_LOOP_64B(att, Wob)

    O1_TILE(0, 0, c00) O1_TILE(0, 1, c01) O1_TILE(0, 2, c02) O1_TILE(0, 3, c03)
    O1_TILE(1, 0, c10) O1_TILE(1, 1, c11) O1_TILE(1, 2, c12) O1_TILE(1, 3, c13)
}

// ---------------------------------------------------------------------------
// Projection 2 (MFMA, 64x128 tile, BK=128): gz = t_bf @ Wgate^T + b_gate;
// out = sigmoid(gz)*t + (1-sigmoid)*residual   (t read back as bf16)
// ---------------------------------------------------------------------------
#define O2_REG(mb, reg, n, Acc)                                                \
    {                                                                          \
        float gz = Acc[(reg)] + bg;                                            \
        float g = 1.0f / (1.0f + expf(-gz));                                   \
        size_t idx = (size_t)((mb) + (reg)) * 1024 + (n);                      \
        float tv = bf2f(t_bf[idx]);                                            \
        float rv = residual[idx];                                              \
        out[idx] = g * tv + (1.0f - g) * rv;                                   \
    }
#define O2_TILE(i, j, Acc)                                                     \
    {                                                                          \
        int n = ct * 128 + wc * 64 + (j) * 16 + c;                             \
        float bg = b_gate[n];                                                  \
        int mb = rt * 64 + wr * 32 + (i) * 16 + quad * 4;                      \
        O2_REG(mb, 0, n, Acc) O2_REG(mb, 1, n, Acc)                            \
        O2_REG(mb, 2, n, Acc) O2_REG(mb, 3, n, Acc)                            \
    }

__global__ __launch_bounds__(256, 1)
void out_gemm2_mfma(const unsigned short* __restrict__ t_bf,
                    const unsigned short* __restrict__ Wgb,
                    const float* __restrict__ b_gate,
                    const float* __restrict__ residual,
                    float* __restrict__ out) {
    int ct = blockIdx.x, rt = blockIdx.y;

    GEMM_LOOP_64B(t_bf, Wgb)

    O2_TILE(0, 0, c00) O2_TILE(0, 1, c01) O2_TILE(0, 2, c02) O2_TILE(0, 3, c03)
    O2_TILE(1, 0, c10) O2_TILE(1, 1, c11) O2_TILE(1, 2, c12) O2_TILE(1, 3, c13)
}

// ---------------------------------------------------------------------------
// Flash attention, bf16 MFMA (16x16x32). 128-row Q tile, 8 waves.
// R12: unnormalized streaming softmax (scores bounded: |s| < ~10).
// ---------------------------------------------------------------------------
#define KSTR 72

__global__ __launch_bounds__(512)
void attn_kernel(const unsigned short* __restrict__ q,
                 const unsigned short* __restrict__ k,
                 const unsigned short* __restrict__ v,
                 const float* __restrict__ bias,
                 unsigned short* __restrict__ attended) {
    int qt = blockIdx.x, h = blockIdx.y, b = blockIdx.z;
    __shared__ unsigned short Ks[64 * KSTR];
    __shared__ unsigned short Vt[64 * KSTR];
    __shared__ unsigned short Ps[128 * KSTR];
    __shared__ float lf[128];

    int tid = threadIdx.x;
    int wave = tid >> 6, lane = tid & 63;   // wave 0..7
    int quad = lane >> 4, c = lane & 15;
    int wb = wave * 16;                     // wave's q-row base, 0..112
    size_t headbase = (((size_t)b * NHEADS + h) * SEQ) * HDIM;
    int q0 = qt * 128;

    const unsigned short* qrow = q + headbase + (size_t)(q0 + wb + c) * HDIM;
    bf16x8 aq0 = *(const bf16x8*)(qrow + quad * 8);
    bf16x8 aq1 = *(const bf16x8*)(qrow + 32 + quad * 8);

    int sr = tid >> 3, sc0 = (tid & 7) * 8;   // staging: 64 rows x 8 shorts/thread

    f32x4 oacc[4];
    #pragma unroll
    for (int t = 0; t < 4; ++t) oacc[t] = (f32x4)0.f;
    float lrow[4];
    #pragma unroll
    for (int r = 0; r < 4; ++r) lrow[r] = 0.f;

    for (int kt = 0; kt < 8; ++kt) {
        int kv0 = kt * 64;
        __syncthreads();
        {
            const unsigned short* krow = k + headbase + (size_t)(kv0 + sr) * HDIM + sc0;
            const unsigned short* vrow = v + headbase + (size_t)(kv0 + sr) * HDIM + sc0;
            u16x8 ka = *(const u16x8*)(krow);
            u16x8 va = *(const u16x8*)(vrow);
            *(u16x8*)&Ks[sr * KSTR + sc0] = ka;
            #pragma unroll
            for (int j = 0; j < 8; ++j) Vt[(sc0 + j) * KSTR + sr] = va[j];
        }
        __syncthreads();

        f32x4 sacc[4];
        #pragma unroll
        for (int nt = 0; nt < 4; ++nt) {
            const unsigned short* kbase = &Ks[(nt * 16 + c) * KSTR];
            bf16x8 b0 = *(const bf16x8*)(kbase + quad * 8);
            bf16x8 b1 = *(const bf16x8*)(kbase + 32 + quad * 8);
            f32x4 a = (f32x4)0.f;
            a = __builtin_amdgcn_mfma_f32_16x16x32_bf16(aq0, b0, a, 0, 0, 0);
            a = __builtin_amdgcn_mfma_f32_16x16x32_bf16(aq1, b1, a, 0, 0, 0);
            sacc[nt] = a;
        }

        const float* bbase = bias + (size_t)(q0 + wb + quad * 4) * 512 + kv0 + c;
        float tsum[4];
        #pragma unroll
        for (int r = 0; r < 4; ++r) tsum[r] = 0.f;
        #pragma unroll
        for (int nt = 0; nt < 4; ++nt)
            #pragma unroll
            for (int r = 0; r < 4; ++r) {
                float p = __expf(sacc[nt][r] * SCALE + bbase[(size_t)r * 512 + nt * 16]);
                tsum[r] += p;
                Ps[(wb + quad * 4 + r) * KSTR + nt * 16 + c] = f2bf(p);
            }
        #pragma unroll
        for (int r = 0; r < 4; ++r) {
            float t = tsum[r];
            t += __shfl_xor(t, 1);
            t += __shfl_xor(t, 2);
            t += __shfl_xor(t, 4);
            t += __shfl_xor(t, 8);
            lrow[r] += t;
        }

        bf16x8 pb0 = *(const bf16x8*)&Ps[(wb + c) * KSTR + quad * 8];
        bf16x8 pb1 = *(const bf16x8*)&Ps[(wb + c) * KSTR + 32 + quad * 8];
        #pragma unroll
        for (int t = 0; t < 4; ++t) {
            const unsigned short* vbase = &Vt[(t * 16 + c) * KSTR];
            bf16x8 a0 = *(const bf16x8*)(vbase + quad * 8);
            bf16x8 a1 = *(const bf16x8*)(vbase + 32 + quad * 8);
            oacc[t] = __builtin_amdgcn_mfma_f32_16x16x32_bf16(a0, pb0, oacc[t], 0, 0, 0);
            oacc[t] = __builtin_amdgcn_mfma_f32_16x16x32_bf16(a1, pb1, oacc[t], 0, 0, 0);
        }
    }

    if (c == 0) {
        f32x4 lv;
        lv[0] = lrow[0]; lv[1] = lrow[1]; lv[2] = lrow[2]; lv[3] = lrow[3];
        *(f32x4*)&lf[wb + quad * 4] = lv;
    }
    float invl = 1.0f / lf[wb + c];
    unsigned short* drow = attended + ((size_t)b * SEQ + (q0 + wb + c)) * D_MODEL + h * HDIM;
    #pragma unroll
    for (int t = 0; t < 4; ++t) {
        ushort4 o;
        o.x = f2bf(oacc[t][0] * invl);
        o.y = f2bf(oacc[t][1] * invl);
        o.z = f2bf(oacc[t][2] * invl);
        o.w = f2bf(oacc[t][3] * invl);
        *(ushort4*)(drow + t * 16 + quad * 4) = o;
    }
}

extern "C" void kernel_launch(void* const* d_in, const int* in_sizes, int n_in,
                              void* d_out, int out_size, void* d_ws, size_t ws_size,
                              hipStream_t stream) {
    const float* dec    = (const float*)d_in[0];
    const float* enc    = (const float*)d_in[1];
    const float* Wqkv   = (const float*)d_in[2];
    const float* Wout   = (const float*)d_in[3];
    const float* b_out  = (const float*)d_in[4];
    const float* Wgate  = (const float*)d_in[5];
    const float* b_gate = (const float*)d_in[6];
    const float* gamma  = (const float*)d_in[7];
    const float* beta   = (const float*)d_in[8];
    float* out = (float*)d_out;

    char* ws = (char*)d_ws;
    const size_t MB = 1024 * 1024;
    unsigned short* q_ln    = (unsigned short*)(ws + 0 * MB);
    unsigned short* kv_ln   = (unsigned short*)(ws + 8 * MB);
    unsigned short* qb      = (unsigned short*)(ws + 16 * MB);
    unsigned short* kb      = (unsigned short*)(ws + 24 * MB);
    unsigned short* vb      = (unsigned short*)(ws + 32 * MB);
    unsigned short* Wqkv_bf = (unsigned short*)(ws + 40 * MB);
    float*          bias    = (float*)(ws + 46 * MB);
    unsigned short* att     = (unsigned short*)(ws + 0 * MB);    // q_ln dead after qkv
    unsigned short* t_bf    = (unsigned short*)(ws + 24 * MB);   // kb dead after attn

    // Hoisted weight-convert needs 4 MB of never-aliased space at 47..51 MB.
    bool hoist = (ws_size >= 51 * MB);
    unsigned short* Wout_bf  = (unsigned short*)(ws + (hoist ? 47 * MB : 32 * MB));
    unsigned short* Wgate_bf = (unsigned short*)(ws + (hoist ? 49 * MB : 34 * MB));

    prep_kernel<<<hoist ? 14336 : 12288, 256, 0, stream>>>(
        dec, enc, gamma, beta, Wqkv, Wout, Wgate,
        q_ln, kv_ln, bias, Wqkv_bf, Wout_bf, Wgate_bf);
    qkv_gemm_mfma<<<768, 256, 0, stream>>>(q_ln, kv_ln, Wqkv_bf, qb, kb, vb);
    attn_kernel<<<dim3(4, 16, 8), 512, 0, stream>>>(qb, kb, vb, bias, att);
    if (!hoist)
        convert_og<<<2048, 256, 0, stream>>>(Wout, Wgate, Wout_bf, Wgate_bf);
    out_gemm1_mfma<<<dim3(8, 64), 256, 0, stream>>>(att, Wout_bf, b_out, t_bf);
    out_gemm2_mfma<<<dim3(8, 64), 256, 0, stream>>>(t_bf, Wgate_bf, b_gate, dec, out);
}

// Round 14
// 215.648 us; speedup vs baseline: 1.3421x; 1.1011x over previous
//
#include <hip/hip_runtime.h>
#include <hip/hip_bf16.h>

#define D_MODEL 1024
#define NHEADS 16
#define HDIM 64
#define BATCH 8
#define SEQ 512
#define NROWS 4096          // BATCH*SEQ
#define SCALE 0.125f
#define LN_EPS 1e-5f

typedef __attribute__((ext_vector_type(8))) short bf16x8;      // 8 bf16 (4 VGPRs)
typedef __attribute__((ext_vector_type(4))) float f32x4;
typedef __attribute__((ext_vector_type(8))) unsigned short u16x8;

static __device__ __forceinline__ float bf2f(unsigned short u) {
    return __uint_as_float(((unsigned int)u) << 16);
}
static __device__ __forceinline__ unsigned short f2bf(float f) {
    unsigned int x = __float_as_uint(f);
    unsigned int r = (x + 0x7fffu + ((x >> 16) & 1u)) >> 16;   // RNE
    return (unsigned short)r;
}

// async 16B/lane global->LDS DMA; LDS dest = wave-uniform base + lane*16
#define GLOAD16(gp, lp)                                                        \
    __builtin_amdgcn_global_load_lds(                                          \
        (const __attribute__((address_space(1))) void*)(gp),                   \
        (__attribute__((address_space(3))) void*)(lp), 16, 0, 0)

// ---------------------------------------------------------------------------
// Bias helper: jax.image.resize(bias128, (512,512), 'bilinear')
// ---------------------------------------------------------------------------
static __device__ __forceinline__ float bias128(int a, int b) {
    float d = fabsf((float)(a - b));
    return expf(-d * 0.1f) - d * 0.05f;
}

// ---------------------------------------------------------------------------
// prep_kernel: fused LN (blocks 0..8191) + bias table (8192..9215) +
// Wqkv convert (9216..12287) + [hoisted Wout/Wgate convert (12288..14335)]
// ---------------------------------------------------------------------------
__global__ void prep_kernel(const float* __restrict__ dec, const float* __restrict__ enc,
                            const float* __restrict__ gamma, const float* __restrict__ beta,
                            const float* __restrict__ Wqkv,
                            const float* __restrict__ Wout, const float* __restrict__ Wgate,
                            unsigned short* __restrict__ q_ln, unsigned short* __restrict__ kv_ln,
                            float* __restrict__ bias, unsigned short* __restrict__ Wqkv_bf,
                            unsigned short* __restrict__ Wout_bf, unsigned short* __restrict__ Wgate_bf) {
    int blk = blockIdx.x;
    int t = threadIdx.x;
    if (blk >= 12288) {         // hoisted Wout/Wgate convert (only when launched)
        int idx = (blk - 12288) * 256 + t;
        const float* src; unsigned short* dst; int off;
        if (idx < 262144) { src = Wout; dst = Wout_bf; off = idx; }
        else              { src = Wgate; dst = Wgate_bf; off = idx - 262144; }
        float4 v = ((const float4*)src)[off];
        ushort4 u;
        u.x = f2bf(v.x); u.y = f2bf(v.y); u.z = f2bf(v.z); u.w = f2bf(v.w);
        ((ushort4*)dst)[off] = u;
        return;
    }
    if (blk >= 9216) {          // Wqkv convert
        int idx = (blk - 9216) * 256 + t;
        float4 v = ((const float4*)Wqkv)[idx];
        ushort4 u;
        u.x = f2bf(v.x); u.y = f2bf(v.y); u.z = f2bf(v.z); u.w = f2bf(v.w);
        ((ushort4*)Wqkv_bf)[idx] = u;
        return;
    }
    if (blk >= 8192) {          // bias
        int idx = (blk - 8192) * 256 + t;
        int qi = idx >> 9, kj = idx & 511;
        float fq = (qi + 0.5f) * 0.25f - 0.5f;
        float fk = (kj + 0.5f) * 0.25f - 0.5f;
        int iq = (int)floorf(fq); float tq = fq - (float)iq;
        int ik = (int)floorf(fk); float tk = fk - (float)ik;
        int iq0 = min(max(iq, 0), 127), iq1 = min(max(iq + 1, 0), 127);
        int ik0 = min(max(ik, 0), 127), ik1 = min(max(ik + 1, 0), 127);
        float v = (1.f - tq) * ((1.f - tk) * bias128(iq0, ik0) + tk * bias128(iq0, ik1))
                +        tq  * ((1.f - tk) * bias128(iq1, ik0) + tk * bias128(iq1, ik1));
        bias[idx] = v;
        return;
    }
    int row = blk;
    const float* src = (row < NROWS) ? dec + (size_t)row * D_MODEL
                                     : enc + (size_t)(row - NROWS) * D_MODEL;
    unsigned short* dst = (row < NROWS) ? q_ln + (size_t)row * D_MODEL
                                        : kv_ln + (size_t)(row - NROWS) * D_MODEL;
    float4 x = ((const float4*)src)[t];
    float s  = x.x + x.y + x.z + x.w;
    float ss = x.x * x.x + x.y * x.y + x.z * x.z + x.w * x.w;
    #pragma unroll
    for (int off = 32; off > 0; off >>= 1) {
        s  += __shfl_down(s, off);
        ss += __shfl_down(ss, off);
    }
    __shared__ float red_s[4], red_ss[4];
    int wid = t >> 6, lane = t & 63;
    if (lane == 0) { red_s[wid] = s; red_ss[wid] = ss; }
    __syncthreads();
    if (t == 0) {
        float S = red_s[0] + red_s[1] + red_s[2] + red_s[3];
        float SS = red_ss[0] + red_ss[1] + red_ss[2] + red_ss[3];
        red_s[0] = S; red_ss[0] = SS;
    }
    __syncthreads();
    float mu  = red_s[0] * (1.0f / 1024.0f);
    float var = red_ss[0] * (1.0f / 1024.0f) - mu * mu;
    float rstd = rsqrtf(var + LN_EPS);
    float4 g = ((const float4*)gamma)[t];
    float4 bb = ((const float4*)beta)[t];
    ushort4 u;
    u.x = f2bf((x.x - mu) * rstd * g.x + bb.x);
    u.y = f2bf((x.y - mu) * rstd * g.y + bb.y);
    u.z = f2bf((x.z - mu) * rstd * g.z + bb.z);
    u.w = f2bf((x.w - mu) * rstd * g.w + bb.w);
    ((ushort4*)dst)[t] = u;
}

// ---------------------------------------------------------------------------
// Wout + Wgate fp32 -> bf16 (fallback path when ws too small to hoist)
// ---------------------------------------------------------------------------
__global__ void convert_og(const float* __restrict__ Wout, const float* __restrict__ Wgate,
                           unsigned short* __restrict__ Wout_bf, unsigned short* __restrict__ Wgate_bf) {
    int idx = blockIdx.x * 256 + threadIdx.x;
    const float* src; unsigned short* dst; int off;
    if (idx < 262144) { src = (const float*)Wout; dst = Wout_bf; off = idx; }
    else              { src = (const float*)Wgate; dst = Wgate_bf; off = idx - 262144; }
    float4 v = ((const float4*)src)[off];
    ushort4 u;
    u.x = f2bf(v.x); u.y = f2bf(v.y); u.z = f2bf(v.z); u.w = f2bf(v.w);
    ((ushort4*)dst)[off] = u;
}

// ===========================================================================
// MFMA GEMM core (bf16): 64x128 tile, BK=128, wave tile 32x64, 8 K-iters,
// 32 MFMA/wave-stage. Permanent lessons:
// R7: accumulators/offsets must be NAMED scalars (arrays -> scratch).
// R8: register prefetch / scheduling tweaks on the 2-barrier K-loop regress.
// R9: global_load_lds width=16 + XOR chunk swizzle -> 0 bank conflicts.
// R13: BK=128 halves barrier drains, pass-verified on out-GEMMs.
// R14: qkv ported to the same core (was 128x128/BK=64 at 71.7 us).
// LDS rows of 128 shorts, 16 chunk-slots; row r slot s holds chunk s^(r&15);
// read recomputes slot = kchunk ^ (row&15); all frag rows have row&15 == c.
// ===========================================================================
#define CSTR 136   // C-bounce row stride (multiple of 8 -> 16B-aligned rows)

struct alignas(16) Smem64B {
    unsigned short A[64 * 128];     // 16 KB
    unsigned short B[128 * 128];    // 32 KB
};

union alignas(16) Smem64Q {
    struct { unsigned short A[64 * 128]; unsigned short B[128 * 128]; } ab;  // 48 KB
    unsigned short C[64 * CSTR];    // 17408 B bounce
};

#define MF(a, b, d) __builtin_amdgcn_mfma_f32_16x16x32_bf16((a), (b), (d), 0, 0, 0)

#define GEMM_KH2B(kh)                                                          \
    {                                                                          \
        int pofs = (((kh) * 4 + quad) ^ c) * 8;                                \
        const unsigned short* Arow_ = &As2[(wr * 32 + c) * 128 + pofs];        \
        const unsigned short* Brow_ = &Bs2[(wc * 64 + c) * 128 + pofs];        \
        bf16x8 f0 = *(const bf16x8*)(Arow_);                                   \
        bf16x8 f1 = *(const bf16x8*)(Arow_ + 2048);                            \
        bf16x8 g0 = *(const bf16x8*)(Brow_);                                   \
        bf16x8 g1 = *(const bf16x8*)(Brow_ + 2048);                            \
        bf16x8 g2 = *(const bf16x8*)(Brow_ + 4096);                            \
        bf16x8 g3 = *(const bf16x8*)(Brow_ + 6144);                            \
        c00 = MF(f0, g0, c00); c01 = MF(f0, g1, c01); c02 = MF(f0, g2, c02); c03 = MF(f0, g3, c03); \
        c10 = MF(f1, g0, c10); c11 = MF(f1, g1, c11); c12 = MF(f1, g2, c12); c13 = MF(f1, g3, c13); \
    }

// Requires As2, Bs2, tid already declared. Declares wave/lane/quad/c/wr/wc
// and accumulators c00..c13.
#define GEMM_BODY_64B(Aptr, Bptr)                                              \
    int wave = tid >> 6, lane = tid & 63, quad = lane >> 4, c = lane & 15;     \
    int wr = wave >> 1, wc = wave & 1;                                         \
    int l4 = lane >> 4, l15 = lane & 15;                                       \
    const unsigned short* Abase = (Aptr) + (size_t)(rt * 64) * 1024;           \
    const unsigned short* Bbase = (Bptr) + (size_t)(ct * 128) * 1024;          \
    int aoff0 = (wave * 16 +  0 + l4) * 1024 + ((l15 ^ ( 0 + l4)) * 8);        \
    int aoff1 = (wave * 16 +  4 + l4) * 1024 + ((l15 ^ ( 4 + l4)) * 8);        \
    int aoff2 = (wave * 16 +  8 + l4) * 1024 + ((l15 ^ ( 8 + l4)) * 8);        \
    int aoff3 = (wave * 16 + 12 + l4) * 1024 + ((l15 ^ (12 + l4)) * 8);        \
    int boff0 = (wave * 32 +  0 + l4) * 1024 + ((l15 ^ (( 0 + l4) & 15)) * 8); \
    int boff1 = (wave * 32 +  4 + l4) * 1024 + ((l15 ^ (( 4 + l4) & 15)) * 8); \
    int boff2 = (wave * 32 +  8 + l4) * 1024 + ((l15 ^ (( 8 + l4) & 15)) * 8); \
    int boff3 = (wave * 32 + 12 + l4) * 1024 + ((l15 ^ ((12 + l4) & 15)) * 8); \
    int boff4 = (wave * 32 + 16 + l4) * 1024 + ((l15 ^ ((16 + l4) & 15)) * 8); \
    int boff5 = (wave * 32 + 20 + l4) * 1024 + ((l15 ^ ((20 + l4) & 15)) * 8); \
    int boff6 = (wave * 32 + 24 + l4) * 1024 + ((l15 ^ ((24 + l4) & 15)) * 8); \
    int boff7 = (wave * 32 + 28 + l4) * 1024 + ((l15 ^ ((28 + l4) & 15)) * 8); \
    unsigned short* AsW = As2 + wave * 2048;                                   \
    unsigned short* BsW = Bs2 + wave * 4096;                                   \
    f32x4 c00 = (f32x4)0.f, c01 = (f32x4)0.f, c02 = (f32x4)0.f, c03 = (f32x4)0.f; \
    f32x4 c10 = (f32x4)0.f, c11 = (f32x4)0.f, c12 = (f32x4)0.f, c13 = (f32x4)0.f; \
    for (int kt = 0; kt < 8; ++kt) {                                           \
        int k0 = kt * 128;                                                     \
        __syncthreads();                                                       \
        GLOAD16(Abase + aoff0 + k0, AsW);                                      \
        GLOAD16(Abase + aoff1 + k0, AsW + 512);                                \
        GLOAD16(Abase + aoff2 + k0, AsW + 1024);                               \
        GLOAD16(Abase + aoff3 + k0, AsW + 1536);                               \
        GLOAD16(Bbase + boff0 + k0, BsW);                                      \
        GLOAD16(Bbase + boff1 + k0, BsW + 512);                                \
        GLOAD16(Bbase + boff2 + k0, BsW + 1024);                               \
        GLOAD16(Bbase + boff3 + k0, BsW + 1536);                               \
        GLOAD16(Bbase + boff4 + k0, BsW + 2048);                               \
        GLOAD16(Bbase + boff5 + k0, BsW + 2560);                               \
        GLOAD16(Bbase + boff6 + k0, BsW + 3072);                               \
        GLOAD16(Bbase + boff7 + k0, BsW + 3584);                               \
        __syncthreads();                                                       \
        GEMM_KH2B(0)                                                           \
        GEMM_KH2B(1)                                                           \
        GEMM_KH2B(2)                                                           \
        GEMM_KH2B(3)                                                           \
    }

// ---------------------------------------------------------------------------
// QKV GEMM (MFMA, 64x128 tile, BK=128) + fused RoPE, LDS-bounce epilogue.
// Grid 1536 (1-D), swizzled into 8(ct)x4(rt) super-tiles for L2 locality.
// ---------------------------------------------------------------------------
#define QROPE_REG(i, reg, A0, A1, A2, A3)                                      \
    {                                                                          \
        int mloc = wr * 32 + (i) * 16 + quad * 4 + (reg);                      \
        int crow = mloc * CSTR + wc * 64;                                      \
        float fl = (float)((rt * 64 + mloc) & 511);                            \
        float aa0 = fl * inv0, aa1 = fl * inv1;                                \
        float c0 = cosf(aa0), s0 = sinf(aa0);                                  \
        float c1 = cosf(aa1), s1 = sinf(aa1);                                  \
        float e0 = A0[(reg)], o0 = A2[(reg)];                                  \
        float e1 = A1[(reg)], o1 = A3[(reg)];                                  \
        smemq.C[crow + c]      = f2bf(e0 * c0 - o0 * s0);                      \
        smemq.C[crow + 32 + c] = f2bf(e0 * s0 + o0 * c0);                      \
        smemq.C[crow + 16 + c] = f2bf(e1 * c1 - o1 * s1);                      \
        smemq.C[crow + 48 + c] = f2bf(e1 * s1 + o1 * c1);                      \
    }
#define QROPE_ROW(i, A0, A1, A2, A3)                                           \
    QROPE_REG(i, 0, A0, A1, A2, A3) QROPE_REG(i, 1, A0, A1, A2, A3)            \
    QROPE_REG(i, 2, A0, A1, A2, A3) QROPE_REG(i, 3, A0, A1, A2, A3)

#define QVSEC_REG(i, reg, A0, A1, A2, A3)                                      \
    {                                                                          \
        int crow = (wr * 32 + (i) * 16 + quad * 4 + (reg)) * CSTR + wc * 64;   \
        smemq.C[crow + c]      = f2bf(A0[(reg)]);                              \
        smemq.C[crow + 16 + c] = f2bf(A1[(reg)]);                              \
        smemq.C[crow + 32 + c] = f2bf(A2[(reg)]);                              \
        smemq.C[crow + 48 + c] = f2bf(A3[(reg)]);                              \
    }
#define QVSEC_ROW(i, A0, A1, A2, A3)                                           \
    QVSEC_REG(i, 0, A0, A1, A2, A3) QVSEC_REG(i, 1, A0, A1, A2, A3)            \
    QVSEC_REG(i, 2, A0, A1, A2, A3) QVSEC_REG(i, 3, A0, A1, A2, A3)

__global__ __launch_bounds__(256, 1)
void qkv_gemm_mfma(const unsigned short* __restrict__ q_ln,
                   const unsigned short* __restrict__ kv_ln,
                   const unsigned short* __restrict__ Wb,
                   unsigned short* __restrict__ qo,
                   unsigned short* __restrict__ ko,
                   unsigned short* __restrict__ vo) {
    int bid = blockIdx.x;               // 0..1535
    int st = bid >> 5, in = bid & 31;   // 48 super-tiles of 32 blocks
    int stc = st % 3, str = st / 3;     // stc 0..2, str 0..15
    int ct = stc * 8 + (in & 7);        // 0..23
    int rt = str * 4 + (in >> 3);       // 0..63
    int n0 = ct * 128;
    int section = n0 >> 10;             // 0=q 1=k 2=v (8 blocks/section: clean)
    const unsigned short* A = (section == 0) ? q_ln : kv_ln;

    __shared__ Smem64Q smemq;
    unsigned short* As2 = smemq.ab.A;
    unsigned short* Bs2 = smemq.ab.B;
    int tid = threadIdx.x;

    GEMM_BODY_64B(A, Wb)

    __syncthreads();                    // all waves done reading As/Bs
    if (section == 2) {
        QVSEC_ROW(0, c00, c01, c02, c03)
        QVSEC_ROW(1, c10, c11, c12, c13)
    } else {
        float inv0 = expf(-0.2878231366f * (float)c);          // 10000^(-c/32)
        float inv1 = expf(-0.2878231366f * (float)(16 + c));
        QROPE_ROW(0, c00, c01, c02, c03)
        QROPE_ROW(1, c10, c11, c12, c13)
    }
    __syncthreads();

    unsigned short* outp = (section == 0) ? qo : (section == 1) ? ko : vo;
    int rr = tid >> 2;                  // row 0..63
    int ch = (tid >> 1) & 1;            // head-half 0/1
    int sub = tid & 1;                  // 32-short half within head
    int mm = rt * 64 + rr;
    int bb = mm >> 9, ll = mm & 511;
    int h = ((n0 & 1023) >> 6) + ch;
    unsigned short* orow = outp + (((size_t)bb * NHEADS + h) * SEQ + ll) * HDIM + sub * 32;
    const unsigned short* csrc = &smemq.C[rr * CSTR + ch * 64 + sub * 32];
    #pragma unroll
    for (int kc = 0; kc < 4; ++kc)
        *(u16x8*)(orow + kc * 8) = *(const u16x8*)(csrc + kc * 8);
}

// ---------------------------------------------------------------------------
// Projection 1 (MFMA, 64x128 tile, BK=128): t = att @ Wout^T + b_out -> bf16
// grid (8, 64) = 512 blocks
// ---------------------------------------------------------------------------
#define O1_REG(mb, reg, n, Acc)                                                \
    t_bf[(size_t)((mb) + (reg)) * 1024 + (n)] = f2bf(Acc[(reg)] + bo);
#define O1_TILE(i, j, Acc)                                                     \
    {                                                                          \
        int n = ct * 128 + wc * 64 + (j) * 16 + c;                             \
        float bo = b_out[n];                                                   \
        int mb = rt * 64 + wr * 32 + (i) * 16 + quad * 4;                      \
        O1_REG(mb, 0, n, Acc) O1_REG(mb, 1, n, Acc)                            \
        O1_REG(mb, 2, n, Acc) O1_REG(mb, 3, n, Acc)                            \
    }

__global__ __launch_bounds__(256, 1)
void out_gemm1_mfma(const unsigned short* __restrict__ att,
                    const unsigned short* __restrict__ Wob,
                    const float* __restrict__ b_out,
                    unsigned short* __restrict__ t_bf) {
    int ct = blockIdx.x, rt = blockIdx.y;
    __shared__ Smem64B smem2;
    unsigned short* As2 = smem2.A;
    unsigned short* Bs2 = smem2.B;
    int tid = threadIdx.x;

    GEMM_BODY_64B(att, Wob)

    O1_TILE(0, 0, c00) O1_TILE(0, 1, c01) O1_TILE(0, 2, c02) O1_TILE(0, 3, c03)
    O1_TILE(1, 0, c10) O1_TILE(1, 1, c11) O1_TILE(1, 2, c12) O1_TILE(1, 3, c13)
}

// ---------------------------------------------------------------------------
// Projection 2 (MFMA, 64x128 tile, BK=128): gz = t_bf @ Wgate^T + b_gate;
// out = sigmoid(gz)*t + (1-sigmoid)*residual   (t read back as bf16)
// ---------------------------------------------------------------------------
#define O2_REG(mb, reg, n, Acc)                                                \
    {                                                                          \
        float gz = Acc[(reg)] + bg;                                            \
        float g = 1.0f / (1.0f + expf(-gz));                                   \
        size_t idx = (size_t)((mb) + (reg)) * 1024 + (n);                      \
        float tv = bf2f(t_bf[idx]);                                            \
        float rv = residual[idx];                                              \
        out[idx] = g * tv + (1.0f - g) * rv;                                   \
    }
#define O2_TILE(i, j, Acc)                                                     \
    {                                                                          \
        int n = ct * 128 + wc * 64 + (j) * 16 + c;                             \
        float bg = b_gate[n];                                                  \
        int mb = rt * 64 + wr * 32 + (i) * 16 + quad * 4;                      \
        O2_REG(mb, 0, n, Acc) O2_REG(mb, 1, n, Acc)                            \
        O2_REG(mb, 2, n, Acc) O2_REG(mb, 3, n, Acc)                            \
    }

__global__ __launch_bounds__(256, 1)
void out_gemm2_mfma(const unsigned short* __restrict__ t_bf,
                    const unsigned short* __restrict__ Wgb,
                    const float* __restrict__ b_gate,
                    const float* __restrict__ residual,
                    float* __restrict__ out) {
    int ct = blockIdx.x, rt = blockIdx.y;
    __shared__ Smem64B smem2;
    unsigned short* As2 = smem2.A;
    unsigned short* Bs2 = smem2.B;
    int tid = threadIdx.x;

    GEMM_BODY_64B(t_bf, Wgb)

    O2_TILE(0, 0, c00) O2_TILE(0, 1, c01) O2_TILE(0, 2, c02) O2_TILE(0, 3, c03)
    O2_TILE(1, 0, c10) O2_TILE(1, 1, c11) O2_TILE(1, 2, c12) O2_TILE(1, 3, c13)
}

// ---------------------------------------------------------------------------
// Flash attention, bf16 MFMA (16x16x32). 128-row Q tile, 8 waves.
// R12: unnormalized streaming softmax (scores bounded: |s| < ~10).
// ---------------------------------------------------------------------------
#define KSTR 72

__global__ __launch_bounds__(512)
void attn_kernel(const unsigned short* __restrict__ q,
                 const unsigned short* __restrict__ k,
                 const unsigned short* __restrict__ v,
                 const float* __restrict__ bias,
                 unsigned short* __restrict__ attended) {
    int qt = blockIdx.x, h = blockIdx.y, b = blockIdx.z;
    __shared__ unsigned short Ks[64 * KSTR];
    __shared__ unsigned short Vt[64 * KSTR];
    __shared__ unsigned short Ps[128 * KSTR];
    __shared__ float lf[128];

    int tid = threadIdx.x;
    int wave = tid >> 6, lane = tid & 63;   // wave 0..7
    int quad = lane >> 4, c = lane & 15;
    int wb = wave * 16;                     // wave's q-row base, 0..112
    size_t headbase = (((size_t)b * NHEADS + h) * SEQ) * HDIM;
    int q0 = qt * 128;

    const unsigned short* qrow = q + headbase + (size_t)(q0 + wb + c) * HDIM;
    bf16x8 aq0 = *(const bf16x8*)(qrow + quad * 8);
    bf16x8 aq1 = *(const bf16x8*)(qrow + 32 + quad * 8);

    int sr = tid >> 3, sc0 = (tid & 7) * 8;   // staging: 64 rows x 8 shorts/thread

    f32x4 oacc[4];
    #pragma unroll
    for (int t = 0; t < 4; ++t) oacc[t] = (f32x4)0.f;
    float lrow[4];
    #pragma unroll
    for (int r = 0; r < 4; ++r) lrow[r] = 0.f;

    for (int kt = 0; kt < 8; ++kt) {
        int kv0 = kt * 64;
        __syncthreads();
        {
            const unsigned short* krow = k + headbase + (size_t)(kv0 + sr) * HDIM + sc0;
            const unsigned short* vrow = v + headbase + (size_t)(kv0 + sr) * HDIM + sc0;
            u16x8 ka = *(const u16x8*)(krow);
            u16x8 va = *(const u16x8*)(vrow);
            *(u16x8*)&Ks[sr * KSTR + sc0] = ka;
            #pragma unroll
            for (int j = 0; j < 8; ++j) Vt[(sc0 + j) * KSTR + sr] = va[j];
        }
        __syncthreads();

        f32x4 sacc[4];
        #pragma unroll
        for (int nt = 0; nt < 4; ++nt) {
            const unsigned short* kbase = &Ks[(nt * 16 + c) * KSTR];
            bf16x8 b0 = *(const bf16x8*)(kbase + quad * 8);
            bf16x8 b1 = *(const bf16x8*)(kbase + 32 + quad * 8);
            f32x4 a = (f32x4)0.f;
            a = __builtin_amdgcn_mfma_f32_16x16x32_bf16(aq0, b0, a, 0, 0, 0);
            a = __builtin_amdgcn_mfma_f32_16x16x32_bf16(aq1, b1, a, 0, 0, 0);
            sacc[nt] = a;
        }

        const float* bbase = bias + (size_t)(q0 + wb + quad * 4) * 512 + kv0 + c;
        float tsum[4];
        #pragma unroll
        for (int r = 0; r < 4; ++r) tsum[r] = 0.f;
        #pragma unroll
        for (int nt = 0; nt < 4; ++nt)
            #pragma unroll
            for (int r = 0; r < 4; ++r) {
                float p = __expf(sacc[nt][r] * SCALE + bbase[(size_t)r * 512 + nt * 16]);
                tsum[r] += p;
                Ps[(wb + quad * 4 + r) * KSTR + nt * 16 + c] = f2bf(p);
            }
        #pragma unroll
        for (int r = 0; r < 4; ++r) {
            float t = tsum[r];
            t += __shfl_xor(t, 1);
            t += __shfl_xor(t, 2);
            t += __shfl_xor(t, 4);
            t += __shfl_xor(t, 8);
            lrow[r] += t;
        }

        bf16x8 pb0 = *(const bf16x8*)&Ps[(wb + c) * KSTR + quad * 8];
        bf16x8 pb1 = *(const bf16x8*)&Ps[(wb + c) * KSTR + 32 + quad * 8];
        #pragma unroll
        for (int t = 0; t < 4; ++t) {
            const unsigned short* vbase = &Vt[(t * 16 + c) * KSTR];
            bf16x8 a0 = *(const bf16x8*)(vbase + quad * 8);
            bf16x8 a1 = *(const bf16x8*)(vbase + 32 + quad * 8);
            oacc[t] = __builtin_amdgcn_mfma_f32_16x16x32_bf16(a0, pb0, oacc[t], 0, 0, 0);
            oacc[t] = __builtin_amdgcn_mfma_f32_16x16x32_bf16(a1, pb1, oacc[t], 0, 0, 0);
        }
    }

    if (c == 0) {
        f32x4 lv;
        lv[0] = lrow[0]; lv[1] = lrow[1]; lv[2] = lrow[2]; lv[3] = lrow[3];
        *(f32x4*)&lf[wb + quad * 4] = lv;
    }
    float invl = 1.0f / lf[wb + c];
    unsigned short* drow = attended + ((size_t)b * SEQ + (q0 + wb + c)) * D_MODEL + h * HDIM;
    #pragma unroll
    for (int t = 0; t < 4; ++t) {
        ushort4 o;
        o.x = f2bf(oacc[t][0] * invl);
        o.y = f2bf(oacc[t][1] * invl);
        o.z = f2bf(oacc[t][2] * invl);
        o.w = f2bf(oacc[t][3] * invl);
        *(ushort4*)(drow + t * 16 + quad * 4) = o;
    }
}

extern "C" void kernel_launch(void* const* d_in, const int* in_sizes, int n_in,
                              void* d_out, int out_size, void* d_ws, size_t ws_size,
                              hipStream_t stream) {
    const float* dec    = (const float*)d_in[0];
    const float* enc    = (const float*)d_in[1];
    const float* Wqkv   = (const float*)d_in[2];
    const float* Wout   = (const float*)d_in[3];
    const float* b_out  = (const float*)d_in[4];
    const float* Wgate  = (const float*)d_in[5];
    const float* b_gate = (const float*)d_in[6];
    const float* gamma  = (const float*)d_in[7];
    const float* beta   = (const float*)d_in[8];
    float* out = (float*)d_out;

    char* ws = (char*)d_ws;
    const size_t MB = 1024 * 1024;
    unsigned short* q_ln    = (unsigned short*)(ws + 0 * MB);
    unsigned short* kv_ln   = (unsigned short*)(ws + 8 * MB);
    unsigned short* qb      = (unsigned short*)(ws + 16 * MB);
    unsigned short* kb      = (unsigned short*)(ws + 24 * MB);
    unsigned short* vb      = (unsigned short*)(ws + 32 * MB);
    unsigned short* Wqkv_bf = (unsigned short*)(ws + 40 * MB);
    float*          bias    = (float*)(ws + 46 * MB);
    unsigned short* att     = (unsigned short*)(ws + 0 * MB);    // q_ln dead after qkv
    unsigned short* t_bf    = (unsigned short*)(ws + 24 * MB);   // kb dead after attn

    // Hoisted weight-convert needs 4 MB of never-aliased space at 47..51 MB.
    bool hoist = (ws_size >= 51 * MB);
    unsigned short* Wout_bf  = (unsigned short*)(ws + (hoist ? 47 * MB : 32 * MB));
    unsigned short* Wgate_bf = (unsigned short*)(ws + (hoist ? 49 * MB : 34 * MB));

    prep_kernel<<<hoist ? 14336 : 12288, 256, 0, stream>>>(
        dec, enc, gamma, beta, Wqkv, Wout, Wgate,
        q_ln, kv_ln, bias, Wqkv_bf, Wout_bf, Wgate_bf);
    qkv_gemm_mfma<<<1536, 256, 0, stream>>>(q_ln, kv_ln, Wqkv_bf, qb, kb, vb);
    attn_kernel<<<dim3(4, 16, 8), 512, 0, stream>>>(qb, kb, vb, bias, att);
    if (!hoist)
        convert_og<<<2048, 256, 0, stream>>>(Wout, Wgate, Wout_bf, Wgate_bf);
    out_gemm1_mfma<<<dim3(8, 64), 256, 0, stream>>>(att, Wout_bf, b_out, t_bf);
    out_gemm2_mfma<<<dim3(8, 64), 256, 0, stream>>>(t_bf, Wgate_bf, b_gate, dec, out);
}

// Round 15
// 212.945 us; speedup vs baseline: 1.3591x; 1.0127x over previous
//
#include <hip/hip_runtime.h>
#include <hip/hip_bf16.h>

#define D_MODEL 1024
#define NHEADS 16
#define HDIM 64
#define BATCH 8
#define SEQ 512
#define NROWS 4096          // BATCH*SEQ
#define SCALE 0.125f
#define LN_EPS 1e-5f

typedef __attribute__((ext_vector_type(8))) short bf16x8;      // 8 bf16 (4 VGPRs)
typedef __attribute__((ext_vector_type(4))) float f32x4;
typedef __attribute__((ext_vector_type(8))) unsigned short u16x8;

static __device__ __forceinline__ float bf2f(unsigned short u) {
    return __uint_as_float(((unsigned int)u) << 16);
}
static __device__ __forceinline__ unsigned short f2bf(float f) {
    unsigned int x = __float_as_uint(f);
    unsigned int r = (x + 0x7fffu + ((x >> 16) & 1u)) >> 16;   // RNE
    return (unsigned short)r;
}

// async 16B/lane global->LDS DMA; LDS dest = wave-uniform base + lane*16
#define GLOAD16(gp, lp)                                                        \
    __builtin_amdgcn_global_load_lds(                                          \
        (const __attribute__((address_space(1))) void*)(gp),                   \
        (__attribute__((address_space(3))) void*)(lp), 16, 0, 0)

// ---------------------------------------------------------------------------
// Bias helper: jax.image.resize(bias128, (512,512), 'bilinear')
// ---------------------------------------------------------------------------
static __device__ __forceinline__ float bias128(int a, int b) {
    float d = fabsf((float)(a - b));
    return expf(-d * 0.1f) - d * 0.05f;
}

// ---------------------------------------------------------------------------
// prep_kernel: fused LN (blocks 0..8191) + bias table (8192..9215) +
// Wqkv convert (9216..12287) + [hoisted Wout/Wgate convert (12288..14335)]
// ---------------------------------------------------------------------------
__global__ void prep_kernel(const float* __restrict__ dec, const float* __restrict__ enc,
                            const float* __restrict__ gamma, const float* __restrict__ beta,
                            const float* __restrict__ Wqkv,
                            const float* __restrict__ Wout, const float* __restrict__ Wgate,
                            unsigned short* __restrict__ q_ln, unsigned short* __restrict__ kv_ln,
                            float* __restrict__ bias, unsigned short* __restrict__ Wqkv_bf,
                            unsigned short* __restrict__ Wout_bf, unsigned short* __restrict__ Wgate_bf) {
    int blk = blockIdx.x;
    int t = threadIdx.x;
    if (blk >= 12288) {         // hoisted Wout/Wgate convert (only when launched)
        int idx = (blk - 12288) * 256 + t;
        const float* src; unsigned short* dst; int off;
        if (idx < 262144) { src = Wout; dst = Wout_bf; off = idx; }
        else              { src = Wgate; dst = Wgate_bf; off = idx - 262144; }
        float4 v = ((const float4*)src)[off];
        ushort4 u;
        u.x = f2bf(v.x); u.y = f2bf(v.y); u.z = f2bf(v.z); u.w = f2bf(v.w);
        ((ushort4*)dst)[off] = u;
        return;
    }
    if (blk >= 9216) {          // Wqkv convert
        int idx = (blk - 9216) * 256 + t;
        float4 v = ((const float4*)Wqkv)[idx];
        ushort4 u;
        u.x = f2bf(v.x); u.y = f2bf(v.y); u.z = f2bf(v.z); u.w = f2bf(v.w);
        ((ushort4*)Wqkv_bf)[idx] = u;
        return;
    }
    if (blk >= 8192) {          // bias
        int idx = (blk - 8192) * 256 + t;
        int qi = idx >> 9, kj = idx & 511;
        float fq = (qi + 0.5f) * 0.25f - 0.5f;
        float fk = (kj + 0.5f) * 0.25f - 0.5f;
        int iq = (int)floorf(fq); float tq = fq - (float)iq;
        int ik = (int)floorf(fk); float tk = fk - (float)ik;
        int iq0 = min(max(iq, 0), 127), iq1 = min(max(iq + 1, 0), 127);
        int ik0 = min(max(ik, 0), 127), ik1 = min(max(ik + 1, 0), 127);
        float v = (1.f - tq) * ((1.f - tk) * bias128(iq0, ik0) + tk * bias128(iq0, ik1))
                +        tq  * ((1.f - tk) * bias128(iq1, ik0) + tk * bias128(iq1, ik1));
        bias[idx] = v;
        return;
    }
    int row = blk;
    const float* src = (row < NROWS) ? dec + (size_t)row * D_MODEL
                                     : enc + (size_t)(row - NROWS) * D_MODEL;
    unsigned short* dst = (row < NROWS) ? q_ln + (size_t)row * D_MODEL
                                        : kv_ln + (size_t)(row - NROWS) * D_MODEL;
    float4 x = ((const float4*)src)[t];
    float s  = x.x + x.y + x.z + x.w;
    float ss = x.x * x.x + x.y * x.y + x.z * x.z + x.w * x.w;
    #pragma unroll
    for (int off = 32; off > 0; off >>= 1) {
        s  += __shfl_down(s, off);
        ss += __shfl_down(ss, off);
    }
    __shared__ float red_s[4], red_ss[4];
    int wid = t >> 6, lane = t & 63;
    if (lane == 0) { red_s[wid] = s; red_ss[wid] = ss; }
    __syncthreads();
    if (t == 0) {
        float S = red_s[0] + red_s[1] + red_s[2] + red_s[3];
        float SS = red_ss[0] + red_ss[1] + red_ss[2] + red_ss[3];
        red_s[0] = S; red_ss[0] = SS;
    }
    __syncthreads();
    float mu  = red_s[0] * (1.0f / 1024.0f);
    float var = red_ss[0] * (1.0f / 1024.0f) - mu * mu;
    float rstd = rsqrtf(var + LN_EPS);
    float4 g = ((const float4*)gamma)[t];
    float4 bb = ((const float4*)beta)[t];
    ushort4 u;
    u.x = f2bf((x.x - mu) * rstd * g.x + bb.x);
    u.y = f2bf((x.y - mu) * rstd * g.y + bb.y);
    u.z = f2bf((x.z - mu) * rstd * g.z + bb.z);
    u.w = f2bf((x.w - mu) * rstd * g.w + bb.w);
    ((ushort4*)dst)[t] = u;
}

// ---------------------------------------------------------------------------
// Wout + Wgate fp32 -> bf16 (fallback path when ws too small to hoist)
// ---------------------------------------------------------------------------
__global__ void convert_og(const float* __restrict__ Wout, const float* __restrict__ Wgate,
                           unsigned short* __restrict__ Wout_bf, unsigned short* __restrict__ Wgate_bf) {
    int idx = blockIdx.x * 256 + threadIdx.x;
    const float* src; unsigned short* dst; int off;
    if (idx < 262144) { src = (const float*)Wout; dst = Wout_bf; off = idx; }
    else              { src = (const float*)Wgate; dst = Wgate_bf; off = idx - 262144; }
    float4 v = ((const float4*)src)[off];
    ushort4 u;
    u.x = f2bf(v.x); u.y = f2bf(v.y); u.z = f2bf(v.z); u.w = f2bf(v.w);
    ((ushort4*)dst)[off] = u;
}

// ===========================================================================
// MFMA GEMM core (bf16): 64x128 tile, BK=128, wave tile 32x64, 8 K-iters,
// 32 MFMA/wave-stage. Permanent lessons: R7 named scalars; R8 no manual
// prefetch; R9 global_load_lds + XOR swizzle (0 conflicts); R13/R14 BK=128.
// R15: V written pre-transposed (B,H,D,L) by qkv; attn stages K/Vt via
// global_load_lds with the same swizzle (kills scalar transpose stores).
// ===========================================================================
#define CSTR 136   // C-bounce row stride (multiple of 8 -> 16B-aligned rows)

struct alignas(16) Smem64B {
    unsigned short A[64 * 128];     // 16 KB
    unsigned short B[128 * 128];    // 32 KB
};

union alignas(16) Smem64Q {
    struct { unsigned short A[64 * 128]; unsigned short B[128 * 128]; } ab;  // 48 KB
    unsigned short C[64 * CSTR];    // q/k bounce: 64 rows x 136
    unsigned short Ct[128 * 72];    // v bounce (transposed): 128 d-rows x 72
};

#define MF(a, b, d) __builtin_amdgcn_mfma_f32_16x16x32_bf16((a), (b), (d), 0, 0, 0)

#define GEMM_KH2B(kh)                                                          \
    {                                                                          \
        int pofs = (((kh) * 4 + quad) ^ c) * 8;                                \
        const unsigned short* Arow_ = &As2[(wr * 32 + c) * 128 + pofs];        \
        const unsigned short* Brow_ = &Bs2[(wc * 64 + c) * 128 + pofs];        \
        bf16x8 f0 = *(const bf16x8*)(Arow_);                                   \
        bf16x8 f1 = *(const bf16x8*)(Arow_ + 2048);                            \
        bf16x8 g0 = *(const bf16x8*)(Brow_);                                   \
        bf16x8 g1 = *(const bf16x8*)(Brow_ + 2048);                            \
        bf16x8 g2 = *(const bf16x8*)(Brow_ + 4096);                            \
        bf16x8 g3 = *(const bf16x8*)(Brow_ + 6144);                            \
        c00 = MF(f0, g0, c00); c01 = MF(f0, g1, c01); c02 = MF(f0, g2, c02); c03 = MF(f0, g3, c03); \
        c10 = MF(f1, g0, c10); c11 = MF(f1, g1, c11); c12 = MF(f1, g2, c12); c13 = MF(f1, g3, c13); \
    }

#define GEMM_BODY_64B(Aptr, Bptr)                                              \
    int wave = tid >> 6, lane = tid & 63, quad = lane >> 4, c = lane & 15;     \
    int wr = wave >> 1, wc = wave & 1;                                         \
    int l4 = lane >> 4, l15 = lane & 15;                                       \
    const unsigned short* Abase = (Aptr) + (size_t)(rt * 64) * 1024;           \
    const unsigned short* Bbase = (Bptr) + (size_t)(ct * 128) * 1024;          \
    int aoff0 = (wave * 16 +  0 + l4) * 1024 + ((l15 ^ ( 0 + l4)) * 8);        \
    int aoff1 = (wave * 16 +  4 + l4) * 1024 + ((l15 ^ ( 4 + l4)) * 8);        \
    int aoff2 = (wave * 16 +  8 + l4) * 1024 + ((l15 ^ ( 8 + l4)) * 8);        \
    int aoff3 = (wave * 16 + 12 + l4) * 1024 + ((l15 ^ (12 + l4)) * 8);        \
    int boff0 = (wave * 32 +  0 + l4) * 1024 + ((l15 ^ (( 0 + l4) & 15)) * 8); \
    int boff1 = (wave * 32 +  4 + l4) * 1024 + ((l15 ^ (( 4 + l4) & 15)) * 8); \
    int boff2 = (wave * 32 +  8 + l4) * 1024 + ((l15 ^ (( 8 + l4) & 15)) * 8); \
    int boff3 = (wave * 32 + 12 + l4) * 1024 + ((l15 ^ ((12 + l4) & 15)) * 8); \
    int boff4 = (wave * 32 + 16 + l4) * 1024 + ((l15 ^ ((16 + l4) & 15)) * 8); \
    int boff5 = (wave * 32 + 20 + l4) * 1024 + ((l15 ^ ((20 + l4) & 15)) * 8); \
    int boff6 = (wave * 32 + 24 + l4) * 1024 + ((l15 ^ ((24 + l4) & 15)) * 8); \
    int boff7 = (wave * 32 + 28 + l4) * 1024 + ((l15 ^ ((28 + l4) & 15)) * 8); \
    unsigned short* AsW = As2 + wave * 2048;                                   \
    unsigned short* BsW = Bs2 + wave * 4096;                                   \
    f32x4 c00 = (f32x4)0.f, c01 = (f32x4)0.f, c02 = (f32x4)0.f, c03 = (f32x4)0.f; \
    f32x4 c10 = (f32x4)0.f, c11 = (f32x4)0.f, c12 = (f32x4)0.f, c13 = (f32x4)0.f; \
    for (int kt = 0; kt < 8; ++kt) {                                           \
        int k0 = kt * 128;                                                     \
        __syncthreads();                                                       \
        GLOAD16(Abase + aoff0 + k0, AsW);                                      \
        GLOAD16(Abase + aoff1 + k0, AsW + 512);                                \
        GLOAD16(Abase + aoff2 + k0, AsW + 1024);                               \
        GLOAD16(Abase + aoff3 + k0, AsW + 1536);                               \
        GLOAD16(Bbase + boff0 + k0, BsW);                                      \
        GLOAD16(Bbase + boff1 + k0, BsW + 512);                                \
        GLOAD16(Bbase + boff2 + k0, BsW + 1024);                               \
        GLOAD16(Bbase + boff3 + k0, BsW + 1536);                               \
        GLOAD16(Bbase + boff4 + k0, BsW + 2048);                               \
        GLOAD16(Bbase + boff5 + k0, BsW + 2560);                               \
        GLOAD16(Bbase + boff6 + k0, BsW + 3072);                               \
        GLOAD16(Bbase + boff7 + k0, BsW + 3584);                               \
        __syncthreads();                                                       \
        GEMM_KH2B(0)                                                           \
        GEMM_KH2B(1)                                                           \
        GEMM_KH2B(2)                                                           \
        GEMM_KH2B(3)                                                           \
    }

// ---------------------------------------------------------------------------
// QKV GEMM (MFMA, 64x128 tile, BK=128) + fused RoPE, LDS-bounce epilogue.
// Q/K: (B,H,L,64) layout.  V: transposed (B,H,64,L) layout (R15).
// Grid 1536 (1-D), swizzled into 8(ct)x4(rt) super-tiles for L2 locality.
// ---------------------------------------------------------------------------
#define QROPE_REG(i, reg, A0, A1, A2, A3)                                      \
    {                                                                          \
        int mloc = wr * 32 + (i) * 16 + quad * 4 + (reg);                      \
        int crow = mloc * CSTR + wc * 64;                                      \
        float fl = (float)((rt * 64 + mloc) & 511);                            \
        float aa0 = fl * inv0, aa1 = fl * inv1;                                \
        float c0 = cosf(aa0), s0 = sinf(aa0);                                  \
        float c1 = cosf(aa1), s1 = sinf(aa1);                                  \
        float e0 = A0[(reg)], o0 = A2[(reg)];                                  \
        float e1 = A1[(reg)], o1 = A3[(reg)];                                  \
        smemq.C[crow + c]      = f2bf(e0 * c0 - o0 * s0);                      \
        smemq.C[crow + 32 + c] = f2bf(e0 * s0 + o0 * c0);                      \
        smemq.C[crow + 16 + c] = f2bf(e1 * c1 - o1 * s1);                      \
        smemq.C[crow + 48 + c] = f2bf(e1 * s1 + o1 * c1);                      \
    }
#define QROPE_ROW(i, A0, A1, A2, A3)                                           \
    QROPE_REG(i, 0, A0, A1, A2, A3) QROPE_REG(i, 1, A0, A1, A2, A3)            \
    QROPE_REG(i, 2, A0, A1, A2, A3) QROPE_REG(i, 3, A0, A1, A2, A3)

// V: bounce transposed — Ct[dcol][l_local], stride 72
#define QVSECT_REG(i, j, reg, Acc)                                             \
    smemq.Ct[(wc * 64 + (j) * 16 + c) * 72 + (wr * 32 + (i) * 16 + quad * 4 + (reg))] = f2bf(Acc[(reg)]);
#define QVSECT_TILE(i, j, Acc)                                                 \
    QVSECT_REG(i, j, 0, Acc) QVSECT_REG(i, j, 1, Acc)                          \
    QVSECT_REG(i, j, 2, Acc) QVSECT_REG(i, j, 3, Acc)

__global__ __launch_bounds__(256, 1)
void qkv_gemm_mfma(const unsigned short* __restrict__ q_ln,
                   const unsigned short* __restrict__ kv_ln,
                   const unsigned short* __restrict__ Wb,
                   unsigned short* __restrict__ qo,
                   unsigned short* __restrict__ ko,
                   unsigned short* __restrict__ vo) {
    int bid = blockIdx.x;               // 0..1535
    int st = bid >> 5, in = bid & 31;   // 48 super-tiles of 32 blocks
    int stc = st % 3, str = st / 3;     // stc 0..2, str 0..15
    int ct = stc * 8 + (in & 7);        // 0..23
    int rt = str * 4 + (in >> 3);       // 0..63
    int n0 = ct * 128;
    int section = n0 >> 10;             // 0=q 1=k 2=v
    const unsigned short* A = (section == 0) ? q_ln : kv_ln;

    __shared__ Smem64Q smemq;
    unsigned short* As2 = smemq.ab.A;
    unsigned short* Bs2 = smemq.ab.B;
    int tid = threadIdx.x;

    GEMM_BODY_64B(A, Wb)

    __syncthreads();                    // all waves done reading As/Bs
    if (section == 2) {
        QVSECT_TILE(0, 0, c00) QVSECT_TILE(0, 1, c01) QVSECT_TILE(0, 2, c02) QVSECT_TILE(0, 3, c03)
        QVSECT_TILE(1, 0, c10) QVSECT_TILE(1, 1, c11) QVSECT_TILE(1, 2, c12) QVSECT_TILE(1, 3, c13)
        __syncthreads();
        // store: 128 d-rows x 64 contiguous l
        int dr = tid >> 1, hh = tid & 1;
        int h = ((n0 & 1023) >> 6) + (dr >> 6);
        int d = dr & 63;
        int mmb = rt * 64;
        int bb = mmb >> 9, ll0 = mmb & 511;
        unsigned short* orow = vo + (((size_t)bb * NHEADS + h) * HDIM + d) * SEQ + ll0 + hh * 32;
        const unsigned short* csrc = &smemq.Ct[dr * 72 + hh * 32];
        #pragma unroll
        for (int kc = 0; kc < 4; ++kc)
            *(u16x8*)(orow + kc * 8) = *(const u16x8*)(csrc + kc * 8);
        return;
    }

    float inv0 = expf(-0.2878231366f * (float)c);          // 10000^(-c/32)
    float inv1 = expf(-0.2878231366f * (float)(16 + c));
    QROPE_ROW(0, c00, c01, c02, c03)
    QROPE_ROW(1, c10, c11, c12, c13)
    __syncthreads();

    unsigned short* outp = (section == 0) ? qo : ko;
    int rr = tid >> 2;                  // row 0..63
    int ch = (tid >> 1) & 1;            // head-half 0/1
    int sub = tid & 1;                  // 32-short half within head
    int mm = rt * 64 + rr;
    int bb = mm >> 9, ll = mm & 511;
    int h = ((n0 & 1023) >> 6) + ch;
    unsigned short* orow = outp + (((size_t)bb * NHEADS + h) * SEQ + ll) * HDIM + sub * 32;
    const unsigned short* csrc = &smemq.C[rr * CSTR + ch * 64 + sub * 32];
    #pragma unroll
    for (int kc = 0; kc < 4; ++kc)
        *(u16x8*)(orow + kc * 8) = *(const u16x8*)(csrc + kc * 8);
}

// ---------------------------------------------------------------------------
// Projection 1 (MFMA, 64x128 tile, BK=128): t = att @ Wout^T + b_out -> bf16
// grid (8, 64) = 512 blocks
// ---------------------------------------------------------------------------
#define O1_REG(mb, reg, n, Acc)                                                \
    t_bf[(size_t)((mb) + (reg)) * 1024 + (n)] = f2bf(Acc[(reg)] + bo);
#define O1_TILE(i, j, Acc)                                                     \
    {                                                                          \
        int n = ct * 128 + wc * 64 + (j) * 16 + c;                             \
        float bo = b_out[n];                                                   \
        int mb = rt * 64 + wr * 32 + (i) * 16 + quad * 4;                      \
        O1_REG(mb, 0, n, Acc) O1_REG(mb, 1, n, Acc)                            \
        O1_REG(mb, 2, n, Acc) O1_REG(mb, 3, n, Acc)                            \
    }

__global__ __launch_bounds__(256, 1)
void out_gemm1_mfma(const unsigned short* __restrict__ att,
                    const unsigned short* __restrict__ Wob,
                    const float* __restrict__ b_out,
                    unsigned short* __restrict__ t_bf) {
    int ct = blockIdx.x, rt = blockIdx.y;
    __shared__ Smem64B smem2;
    unsigned short* As2 = smem2.A;
    unsigned short* Bs2 = smem2.B;
    int tid = threadIdx.x;

    GEMM_BODY_64B(att, Wob)

    O1_TILE(0, 0, c00) O1_TILE(0, 1, c01) O1_TILE(0, 2, c02) O1_TILE(0, 3, c03)
    O1_TILE(1, 0, c10) O1_TILE(1, 1, c11) O1_TILE(1, 2, c12) O1_TILE(1, 3, c13)
}

// ---------------------------------------------------------------------------
// Projection 2 (MFMA, 64x128 tile, BK=128): gz = t_bf @ Wgate^T + b_gate;
// out = sigmoid(gz)*t + (1-sigmoid)*residual   (t read back as bf16)
// ---------------------------------------------------------------------------
#define O2_REG(mb, reg, n, Acc)                                                \
    {                                                                          \
        float gz = Acc[(reg)] + bg;                                            \
        float g = 1.0f / (1.0f + expf(-gz));                                   \
        size_t idx = (size_t)((mb) + (reg)) * 1024 + (n);                      \
        float tv = bf2f(t_bf[idx]);                                            \
        float rv = residual[idx];                                              \
        out[idx] = g * tv + (1.0f - g) * rv;                                   \
    }
#define O2_TILE(i, j, Acc)                                                     \
    {                                                                          \
        int n = ct * 128 + wc * 64 + (j) * 16 + c;                             \
        float bg = b_gate[n];                                                  \
        int mb = rt * 64 + wr * 32 + (i) * 16 + quad * 4;                      \
        O2_REG(mb, 0, n, Acc) O2_REG(mb, 1, n, Acc)                            \
        O2_REG(mb, 2, n, Acc) O2_REG(mb, 3, n, Acc)                            \
    }

__global__ __launch_bounds__(256, 1)
void out_gemm2_mfma(const unsigned short* __restrict__ t_bf,
                    const unsigned short* __restrict__ Wgb,
                    const float* __restrict__ b_gate,
                    const float* __restrict__ residual,
                    float* __restrict__ out) {
    int ct = blockIdx.x, rt = blockIdx.y;
    __shared__ Smem64B smem2;
    unsigned short* As2 = smem2.A;
    unsigned short* Bs2 = smem2.B;
    int tid = threadIdx.x;

    GEMM_BODY_64B(t_bf, Wgb)

    O2_TILE(0, 0, c00) O2_TILE(0, 1, c01) O2_TILE(0, 2, c02) O2_TILE(0, 3, c03)
    O2_TILE(1, 0, c10) O2_TILE(1, 1, c11) O2_TILE(1, 2, c12) O2_TILE(1, 3, c13)
}

// ---------------------------------------------------------------------------
// Flash attention, bf16 MFMA (16x16x32). 128-row Q tile, 8 waves.
// R12: unnormalized streaming softmax (scores bounded: |s| < ~10).
// R15: K and Vt staged via global_load_lds w/ XOR swizzle (V pre-transposed
// in global by qkv) — no scalar transpose stores, no staging VGPR roundtrip.
// LDS rows 64 shorts, 8 slots; row r slot s holds chunk s^(r&7).
// ---------------------------------------------------------------------------
#define KSTR 72   // Ps stride only

__global__ __launch_bounds__(512)
void attn_kernel(const unsigned short* __restrict__ q,
                 const unsigned short* __restrict__ k,
                 const unsigned short* __restrict__ vt,
                 const float* __restrict__ bias,
                 unsigned short* __restrict__ attended) {
    int qt = blockIdx.x, h = blockIdx.y, b = blockIdx.z;
    __shared__ unsigned short Ks[64 * 64];
    __shared__ unsigned short Vs[64 * 64];
    __shared__ unsigned short Ps[128 * KSTR];
    __shared__ float lf[128];

    int tid = threadIdx.x;
    int wave = tid >> 6, lane = tid & 63;   // wave 0..7
    int quad = lane >> 4, c = lane & 15;
    int wb = wave * 16;                     // wave's q-row base, 0..112
    size_t headbase = (((size_t)b * NHEADS + h) * SEQ) * HDIM;  // == (b*16+h)*32768
    int q0 = qt * 128;

    const unsigned short* qrow = q + headbase + (size_t)(q0 + wb + c) * HDIM;
    bf16x8 aq0 = *(const bf16x8*)(qrow + quad * 8);
    bf16x8 aq1 = *(const bf16x8*)(qrow + 32 + quad * 8);

    // staging: wave w covers rows w*8..w*8+7 (8 rows x 64 shorts = 1 GLOAD16/lane)
    int srow = wave * 8 + (lane >> 3);
    int schunk = (lane & 7) ^ (srow & 7);
    unsigned short* KsW = Ks + wave * 512;
    unsigned short* VsW = Vs + wave * 512;
    const unsigned short* kgb = k + headbase + (size_t)srow * HDIM + schunk * 8;
    const unsigned short* vgb = vt + headbase + (size_t)srow * SEQ + schunk * 8;
    int x7 = c & 7;
    int p0 = (quad ^ x7) * 8;
    int p1 = ((4 + quad) ^ x7) * 8;

    f32x4 oacc[4];
    #pragma unroll
    for (int t = 0; t < 4; ++t) oacc[t] = (f32x4)0.f;
    float lrow[4];
    #pragma unroll
    for (int r = 0; r < 4; ++r) lrow[r] = 0.f;

    for (int kt = 0; kt < 8; ++kt) {
        int kv0 = kt * 64;
        __syncthreads();
        GLOAD16(kgb + (size_t)kv0 * HDIM, KsW);   // K rows kv0+srow
        GLOAD16(vgb + kv0, VsW);                  // Vt rows d=srow, cols kv0+
        __syncthreads();

        f32x4 sacc[4];
        #pragma unroll
        for (int nt = 0; nt < 4; ++nt) {
            const unsigned short* kbase = &Ks[(nt * 16 + c) * 64];
            bf16x8 b0 = *(const bf16x8*)(kbase + p0);
            bf16x8 b1 = *(const bf16x8*)(kbase + p1);
            f32x4 a = (f32x4)0.f;
            a = __builtin_amdgcn_mfma_f32_16x16x32_bf16(aq0, b0, a, 0, 0, 0);
            a = __builtin_amdgcn_mfma_f32_16x16x32_bf16(aq1, b1, a, 0, 0, 0);
            sacc[nt] = a;
        }

        const float* bbase = bias + (size_t)(q0 + wb + quad * 4) * 512 + kv0 + c;
        float tsum[4];
        #pragma unroll
        for (int r = 0; r < 4; ++r) tsum[r] = 0.f;
        #pragma unroll
        for (int nt = 0; nt < 4; ++nt)
            #pragma unroll
            for (int r = 0; r < 4; ++r) {
                float p = __expf(sacc[nt][r] * SCALE + bbase[(size_t)r * 512 + nt * 16]);
                tsum[r] += p;
                Ps[(wb + quad * 4 + r) * KSTR + nt * 16 + c] = f2bf(p);
            }
        #pragma unroll
        for (int r = 0; r < 4; ++r) {
            float t = tsum[r];
            t += __shfl_xor(t, 1);
            t += __shfl_xor(t, 2);
            t += __shfl_xor(t, 4);
            t += __shfl_xor(t, 8);
            lrow[r] += t;
        }

        bf16x8 pb0 = *(const bf16x8*)&Ps[(wb + c) * KSTR + quad * 8];
        bf16x8 pb1 = *(const bf16x8*)&Ps[(wb + c) * KSTR + 32 + quad * 8];
        #pragma unroll
        for (int t = 0; t < 4; ++t) {
            const unsigned short* vbase = &Vs[(t * 16 + c) * 64];
            bf16x8 a0 = *(const bf16x8*)(vbase + p0);
            bf16x8 a1 = *(const bf16x8*)(vbase + p1);
            oacc[t] = __builtin_amdgcn_mfma_f32_16x16x32_bf16(a0, pb0, oacc[t], 0, 0, 0);
            oacc[t] = __builtin_amdgcn_mfma_f32_16x16x32_bf16(a1, pb1, oacc[t], 0, 0, 0);
        }
    }

    if (c == 0) {
        f32x4 lv;
        lv[0] = lrow[0]; lv[1] = lrow[1]; lv[2] = lrow[2]; lv[3] = lrow[3];
        *(f32x4*)&lf[wb + quad * 4] = lv;
    }
    float invl = 1.0f / lf[wb + c];
    unsigned short* drow = attended + ((size_t)b * SEQ + (q0 + wb + c)) * D_MODEL + h * HDIM;
    #pragma unroll
    for (int t = 0; t < 4; ++t) {
        ushort4 o;
        o.x = f2bf(oacc[t][0] * invl);
        o.y = f2bf(oacc[t][1] * invl);
        o.z = f2bf(oacc[t][2] * invl);
        o.w = f2bf(oacc[t][3] * invl);
        *(ushort4*)(drow + t * 16 + quad * 4) = o;
    }
}

extern "C" void kernel_launch(void* const* d_in, const int* in_sizes, int n_in,
                              void* d_out, int out_size, void* d_ws, size_t ws_size,
                              hipStream_t stream) {
    const float* dec    = (const float*)d_in[0];
    const float* enc    = (const float*)d_in[1];
    const float* Wqkv   = (const float*)d_in[2];
    const float* Wout   = (const float*)d_in[3];
    const float* b_out  = (const float*)d_in[4];
    const float* Wgate  = (const float*)d_in[5];
    const float* b_gate = (const float*)d_in[6];
    const float* gamma  = (const float*)d_in[7];
    const float* beta   = (const float*)d_in[8];
    float* out = (float*)d_out;

    char* ws = (char*)d_ws;
    const size_t MB = 1024 * 1024;
    unsigned short* q_ln    = (unsigned short*)(ws + 0 * MB);
    unsigned short* kv_ln   = (unsigned short*)(ws + 8 * MB);
    unsigned short* qb      = (unsigned short*)(ws + 16 * MB);
    unsigned short* kb      = (unsigned short*)(ws + 24 * MB);
    unsigned short* vb      = (unsigned short*)(ws + 32 * MB);   // V^T (B,H,64,L)
    unsigned short* Wqkv_bf = (unsigned short*)(ws + 40 * MB);
    float*          bias    = (float*)(ws + 46 * MB);
    unsigned short* att     = (unsigned short*)(ws + 0 * MB);    // q_ln dead after qkv
    unsigned short* t_bf    = (unsigned short*)(ws + 24 * MB);   // kb dead after attn

    // Hoisted weight-convert needs 4 MB of never-aliased space at 47..51 MB.
    bool hoist = (ws_size >= 51 * MB);
    unsigned short* Wout_bf  = (unsigned short*)(ws + (hoist ? 47 * MB : 32 * MB));
    unsigned short* Wgate_bf = (unsigned short*)(ws + (hoist ? 49 * MB : 34 * MB));

    prep_kernel<<<hoist ? 14336 : 12288, 256, 0, stream>>>(
        dec, enc, gamma, beta, Wqkv, Wout, Wgate,
        q_ln, kv_ln, bias, Wqkv_bf, Wout_bf, Wgate_bf);
    qkv_gemm_mfma<<<1536, 256, 0, stream>>>(q_ln, kv_ln, Wqkv_bf, qb, kb, vb);
    attn_kernel<<<dim3(4, 16, 8), 512, 0, stream>>>(qb, kb, vb, bias, att);
    if (!hoist)
        convert_og<<<2048, 256, 0, stream>>>(Wout, Wgate, Wout_bf, Wgate_bf);
    out_gemm1_mfma<<<dim3(8, 64), 256, 0, stream>>>(att, Wout_bf, b_out, t_bf);
    out_gemm2_mfma<<<dim3(8, 64), 256, 0, stream>>>(t_bf, Wgate_bf, b_gate, dec, out);
}